// Round 2
// baseline (5553.307 us; speedup 1.0000x reference)
//
#include <hip/hip_runtime.h>
#include <hip/hip_bf16.h>
#include <math.h>

// RWKV7 attention, f32 baseline (round 2: fit workspace in 6*NE + 4.25 MiB).
// Pipeline:
//  1. gemm_f32 (mix fused into A-load): R, K0, V0 projections + 4 LoRA stage-1
//  2. activations on LoRA hiddens (tanh / sigmoid)
//  3. gemm_f32 LoRA stage-2 with fused epilogues: EW (sigmoid*e^-0.5), V-lerp (in-place), ya
//  4. ka_epi: a=sigmoid(ya+ab); kk normalize; bv=kk*a; k scale
//  5. rwkv_scan: DPLR recurrence, wave per (b,h,16 v-columns), shfl-only reductions
//     -> output written into d_out (dead before final GEMM overwrites it)
//  6. gn_bonus: GroupNorm + bonus + on-the-fly g (HG . gB row) -> EW
//  7. gemm_f32: output projection Wo -> d_out

#define BM 64
#define BN 64
#define BK 16

// C[M,N] = Amix[M,K] @ W[N,K]^T
// If xx != nullptr: Amix[m,k] = A[m,k] + ((t>0 ? A[m-1,k] : 0) - A[m,k]) * xx[k], t = m % T
// mode 0: C = acc
// mode 1: C = sigmoid(acc + bias[n]) * exp(-0.5)
// mode 2: C = C + sigmoid(acc + bias[n]) * (aux - C)   (in-place lerp toward aux)
__global__ __launch_bounds__(256) void gemm_f32(
    const float* __restrict__ A, const float* __restrict__ xx,
    const float* __restrict__ W, float* __restrict__ C,
    int M, int N, int K, int T, int mode,
    const float* __restrict__ bias, const float* __restrict__ aux)
{
    __shared__ float As[BK][BM + 4];
    __shared__ float Bs[BK][BN + 4];
    const int tid = threadIdx.x;
    const int m0 = blockIdx.x * BM;
    const int n0 = blockIdx.y * BN;
    const int lr = tid >> 2;          // 0..63 : row within tile
    const int lk = (tid & 3) << 2;    // 0,4,8,12 : k within K-step
    const int tx = tid & 15;
    const int ty = tid >> 4;
    const int mrow = m0 + lr;
    const int nrow = n0 + lr;
    float acc[4][4];
    #pragma unroll
    for (int i = 0; i < 4; ++i)
        #pragma unroll
        for (int j = 0; j < 4; ++j) acc[i][j] = 0.f;

    for (int k0 = 0; k0 < K; k0 += BK) {
        const float* ap = A + (size_t)mrow * K + k0 + lk;
        float4 av = *(const float4*)ap;
        if (xx) {
            const int t = mrow % T;
            float4 pv = make_float4(0.f, 0.f, 0.f, 0.f);
            if (t > 0) pv = *(const float4*)(ap - K);
            const float4 xv = *(const float4*)(xx + k0 + lk);
            av.x += (pv.x - av.x) * xv.x;
            av.y += (pv.y - av.y) * xv.y;
            av.z += (pv.z - av.z) * xv.z;
            av.w += (pv.w - av.w) * xv.w;
        }
        float4 bv = make_float4(0.f, 0.f, 0.f, 0.f);
        if (nrow < N) bv = *(const float4*)(W + (size_t)nrow * K + k0 + lk);

        As[lk + 0][lr] = av.x; As[lk + 1][lr] = av.y;
        As[lk + 2][lr] = av.z; As[lk + 3][lr] = av.w;
        Bs[lk + 0][lr] = bv.x; Bs[lk + 1][lr] = bv.y;
        Bs[lk + 2][lr] = bv.z; Bs[lk + 3][lr] = bv.w;
        __syncthreads();

        #pragma unroll
        for (int kk = 0; kk < BK; ++kk) {
            const float4 a4 = *(const float4*)&As[kk][ty << 2];
            const float4 b4 = *(const float4*)&Bs[kk][tx << 2];
            const float a[4] = {a4.x, a4.y, a4.z, a4.w};
            const float b[4] = {b4.x, b4.y, b4.z, b4.w};
            #pragma unroll
            for (int i = 0; i < 4; ++i)
                #pragma unroll
                for (int j = 0; j < 4; ++j)
                    acc[i][j] = fmaf(a[i], b[j], acc[i][j]);
        }
        __syncthreads();
    }
    #pragma unroll
    for (int i = 0; i < 4; ++i) {
        const int m = m0 + (ty << 2) + i;
        #pragma unroll
        for (int j = 0; j < 4; ++j) {
            const int n = n0 + (tx << 2) + j;
            if (n < N) {
                const size_t idx = (size_t)m * N + n;
                float v = acc[i][j];
                if (mode == 1) {
                    v = 0.6065306597126334f / (1.f + expf(-(v + bias[n])));
                } else if (mode == 2) {
                    const float v0 = C[idx];
                    const float sg = 1.f / (1.f + expf(-(v + bias[n])));
                    v = v0 + sg * (aux[idx] - v0);
                }
                C[idx] = v;
            }
        }
    }
}

__global__ void unary_act(float* __restrict__ x, int n, int mode)
{
    int i = blockIdx.x * 256 + threadIdx.x;
    if (i < n) {
        float v = x[i];
        x[i] = (mode == 0) ? tanhf(v) : 1.f / (1.f + expf(-v));
    }
}

// per-(b,t,h) wave: a = sigmoid(ya+ab); kk = normalize(k0*k_k); bv = kk*a;
// kfinal = k0*(1+(a-1)*k_a)
__global__ __launch_bounds__(256) void ka_epi(
    float* __restrict__ Kf, float* __restrict__ A_BV, float* __restrict__ KKo,
    const float* __restrict__ k_k, const float* __restrict__ k_a,
    const float* __restrict__ ab, int total, int H)
{
    int wid = (blockIdx.x << 2) | (threadIdx.x >> 6);
    if (wid >= total) return;
    const int l = threadIdx.x & 63;
    const int h = wid % H;
    const int ch = h * 64 + l;
    const size_t base = (size_t)wid * 64;
    float k0 = Kf[base + l];
    float a = 1.f / (1.f + expf(-(A_BV[base + l] + ab[ch])));
    float kkr = k0 * k_k[ch];
    float ss = kkr * kkr;
    #pragma unroll
    for (int off = 1; off < 64; off <<= 1) ss += __shfl_xor(ss, off, 64);
    float inv = 1.f / fmaxf(sqrtf(ss), 1e-12f);
    float kkn = kkr * inv;
    KKo[base + l] = kkn;
    A_BV[base + l] = kkn * a;
    Kf[base + l] = k0 * fmaf(a - 1.f, k_a[ch], 1.f);
}

// DPLR scan. One wave per (b, h, 16-column slab of v).
// lane l: v = slab*16 + (l&15), owns k in [ (l>>4)*16, +16 ).
// sa and o reductions over k-quarters = shfl_xor(16), shfl_xor(32). No barriers.
__global__ __launch_bounds__(64) void rwkv_scan(
    const float* __restrict__ EW, const float* __restrict__ R,
    const float* __restrict__ Kf, const float* __restrict__ Vf,
    const float* __restrict__ KK, const float* __restrict__ BV,
    float* __restrict__ O, int T, int H)
{
    const int blk = blockIdx.x;
    const int slab = blk & 3;
    const int bh = blk >> 2;
    const int b = bh / H, h = bh % H;
    const int l = threadIdx.x;
    const int v = (slab << 4) | (l & 15);
    const int ko = l & 48;   // k-quarter offset
    const size_t step = (size_t)H * 64;
    const size_t base = ((size_t)b * T * H + h) * 64;

    const float* ewp = EW + base + ko;
    const float* rp  = R  + base + ko;
    const float* kp  = Kf + base + ko;
    const float* kkp = KK + base + ko;
    const float* bvp = BV + base + ko;
    const float* vp  = Vf + base + v;
    float*       op  = O  + base + v;

    float s[16];
    #pragma unroll
    for (int i = 0; i < 16; ++i) s[i] = 0.f;

    for (int t = 0; t < T; ++t) {
        alignas(16) float ew[16], rr[16], kf[16], kkv[16], bb[16];
        #pragma unroll
        for (int j = 0; j < 4; ++j) {
            ((float4*)ew )[j] = ((const float4*)ewp)[j];
            ((float4*)rr )[j] = ((const float4*)rp )[j];
            ((float4*)kf )[j] = ((const float4*)kp )[j];
            ((float4*)kkv)[j] = ((const float4*)kkp)[j];
            ((float4*)bb )[j] = ((const float4*)bvp)[j];
        }
        const float vv = *vp;

        float sa0 = 0.f, sa1 = 0.f, sa2 = 0.f, sa3 = 0.f;
        #pragma unroll
        for (int i = 0; i < 16; i += 4) {
            s[i+0] *= ew[i+0]; s[i+1] *= ew[i+1];
            s[i+2] *= ew[i+2]; s[i+3] *= ew[i+3];
            sa0 = fmaf(kkv[i+0], s[i+0], sa0);
            sa1 = fmaf(kkv[i+1], s[i+1], sa1);
            sa2 = fmaf(kkv[i+2], s[i+2], sa2);
            sa3 = fmaf(kkv[i+3], s[i+3], sa3);
        }
        float sa = -((sa0 + sa1) + (sa2 + sa3));   // a_t = -kk
        sa += __shfl_xor(sa, 16, 64);
        sa += __shfl_xor(sa, 32, 64);

        float o0 = 0.f, o1 = 0.f, o2 = 0.f, o3 = 0.f;
        #pragma unroll
        for (int i = 0; i < 16; i += 4) {
            s[i+0] = fmaf(bb[i+0], sa, fmaf(kf[i+0], vv, s[i+0]));
            s[i+1] = fmaf(bb[i+1], sa, fmaf(kf[i+1], vv, s[i+1]));
            s[i+2] = fmaf(bb[i+2], sa, fmaf(kf[i+2], vv, s[i+2]));
            s[i+3] = fmaf(bb[i+3], sa, fmaf(kf[i+3], vv, s[i+3]));
            o0 = fmaf(rr[i+0], s[i+0], o0);
            o1 = fmaf(rr[i+1], s[i+1], o1);
            o2 = fmaf(rr[i+2], s[i+2], o2);
            o3 = fmaf(rr[i+3], s[i+3], o3);
        }
        float o = (o0 + o1) + (o2 + o3);
        o += __shfl_xor(o, 16, 64);
        o += __shfl_xor(o, 32, 64);
        if (ko == 0) *op = o;

        ewp += step; rp += step; kp += step; kkp += step; bvp += step;
        vp += step; op += step;
    }
}

// GroupNorm over head channels + bonus + on-the-fly g-gate. One wave per (b,t,h).
// g[ch] = dot(HG[m, 0:128], gB[ch, 0:128])  (HG already sigmoid-activated)
__global__ __launch_bounds__(256) void gn_bonus(
    const float* __restrict__ O, const float* __restrict__ R,
    const float* __restrict__ Kf, const float* __restrict__ Vf,
    const float* __restrict__ HG, const float* __restrict__ gB,
    const float* __restrict__ r_k,
    const float* __restrict__ gn_w, const float* __restrict__ gn_b,
    float* __restrict__ ON, int total, int H, float eps)
{
    int wid = (blockIdx.x << 2) | (threadIdx.x >> 6);
    if (wid >= total) return;
    const int l = threadIdx.x & 63;
    const int h = wid % H;
    const int ch = h * 64 + l;
    const int m = wid / H;
    const size_t base = (size_t)wid * 64;

    // g-gate: 128-dot
    const float4* hg4 = (const float4*)(HG + (size_t)m * 128);
    const float4* gb4 = (const float4*)(gB + (size_t)ch * 128);
    float g = 0.f;
    #pragma unroll 8
    for (int j = 0; j < 32; ++j) {
        const float4 a = hg4[j], b = gb4[j];
        g += a.x * b.x + a.y * b.y + a.z * b.z + a.w * b.w;
    }

    float o = O[base + l];
    float sum = o;
    #pragma unroll
    for (int off = 1; off < 64; off <<= 1) sum += __shfl_xor(sum, off, 64);
    float mu = sum * (1.f / 64.f);
    float d = o - mu;
    float ss = d * d;
    #pragma unroll
    for (int off = 1; off < 64; off <<= 1) ss += __shfl_xor(ss, off, 64);
    float inv = 1.f / sqrtf(ss * (1.f / 64.f) + eps);
    float on = d * inv * gn_w[ch] + gn_b[ch];

    float r = R[base + l], k = Kf[base + l], vv = Vf[base + l];
    float p = r * k * r_k[ch];
    #pragma unroll
    for (int off = 1; off < 64; off <<= 1) p += __shfl_xor(p, off, 64);
    on = fmaf(p, vv, on);
    ON[base + l] = on * g;
}

extern "C" void kernel_launch(void* const* d_in, const int* in_sizes, int n_in,
                              void* d_out, int out_size, void* d_ws, size_t ws_size,
                              hipStream_t stream)
{
    const int B = 2, T = 2048, D = 2048, H = 32;
    const int M = B * T;

    const float* hid = (const float*)d_in[0];
    const float* vst = (const float*)d_in[1];
    const float* x_x = (const float*)d_in[2];
    const float* k_k = (const float*)d_in[3];
    const float* k_a = (const float*)d_in[4];
    const float* r_k = (const float*)d_in[5];
    const float* Wr  = (const float*)d_in[6];
    const float* Wk  = (const float*)d_in[7];
    const float* Wv  = (const float*)d_in[8];
    const float* Wo  = (const float*)d_in[9];
    const float* wA  = (const float*)d_in[10];
    const float* wB  = (const float*)d_in[11];
    const float* wb  = (const float*)d_in[12];
    const float* vA  = (const float*)d_in[13];
    const float* vB  = (const float*)d_in[14];
    const float* vb  = (const float*)d_in[15];
    const float* aA  = (const float*)d_in[16];
    const float* aB  = (const float*)d_in[17];
    const float* ab  = (const float*)d_in[18];
    const float* gA  = (const float*)d_in[19];
    const float* gB  = (const float*)d_in[20];
    const float* gnw = (const float*)d_in[21];
    const float* gnb = (const float*)d_in[22];
    float* out = (float*)d_out;

    const size_t NE = (size_t)M * D;  // 8,388,608
    const size_t need = (6 * NE + (size_t)M * (64 + 16 + 64 + 128)) * sizeof(float);  // ~196 MiB
    if (ws_size < need) return;

    float* R_  = (float*)d_ws;
    float* EW  = R_  + NE;     // ew = exp(w); later reused as ON (gn_bonus output)
    float* Kf  = EW  + NE;
    float* Vf  = Kf  + NE;
    float* KK  = Vf  + NE;
    float* ABV = KK  + NE;     // holds ya, then bv = kk*a
    float* HW  = ABV + NE;
    float* HV  = HW + (size_t)M * 64;
    float* HA  = HV + (size_t)M * 16;
    float* HG  = HA + (size_t)M * 64;
    float* O_  = out;          // scan output lives in d_out; dead before final GEMM

    dim3 blk(256);
    dim3 gBig(M / BM, D / BN);
    const float* nf = nullptr;

    // big projections (mix fused)
    hipLaunchKernelGGL(gemm_f32, gBig, blk, 0, stream, hid, x_x + 0 * (size_t)D, Wr, R_, M, D, D, T, 0, nf, nf);
    hipLaunchKernelGGL(gemm_f32, gBig, blk, 0, stream, hid, x_x + 2 * (size_t)D, Wk, Kf, M, D, D, T, 0, nf, nf);
    hipLaunchKernelGGL(gemm_f32, gBig, blk, 0, stream, hid, x_x + 3 * (size_t)D, Wv, Vf, M, D, D, T, 0, nf, nf);
    // LoRA stage-1 (mix fused)
    hipLaunchKernelGGL(gemm_f32, dim3(M / BM, 1), blk, 0, stream, hid, x_x + 1 * (size_t)D, wA, HW, M, 64, D, T, 0, nf, nf);
    hipLaunchKernelGGL(gemm_f32, dim3(M / BM, 1), blk, 0, stream, hid, x_x + 3 * (size_t)D, vA, HV, M, 16, D, T, 0, nf, nf);
    hipLaunchKernelGGL(gemm_f32, dim3(M / BM, 1), blk, 0, stream, hid, x_x + 4 * (size_t)D, aA, HA, M, 64, D, T, 0, nf, nf);
    hipLaunchKernelGGL(gemm_f32, dim3(M / BM, 2), blk, 0, stream, hid, x_x + 5 * (size_t)D, gA, HG, M, 128, D, T, 0, nf, nf);
    // activations on LoRA hiddens
    hipLaunchKernelGGL(unary_act, dim3((M * 64 + 255) / 256), blk, 0, stream, HW, M * 64, 0);
    hipLaunchKernelGGL(unary_act, dim3((M * 128 + 255) / 256), blk, 0, stream, HG, M * 128, 1);
    // LoRA stage-2 with fused epilogues
    hipLaunchKernelGGL(gemm_f32, gBig, blk, 0, stream, HW, nf, wB, EW,  M, D, 64, T, 1, wb, nf);        // ew
    hipLaunchKernelGGL(gemm_f32, gBig, blk, 0, stream, HV, nf, vB, Vf,  M, D, 16, T, 2, vb, vst);       // v lerp (in-place)
    hipLaunchKernelGGL(gemm_f32, gBig, blk, 0, stream, HA, nf, aB, ABV, M, D, 64, T, 0, nf, nf);        // ya
    // a/kk/k epilogue
    const int totalW = M * H;
    hipLaunchKernelGGL(ka_epi, dim3(totalW / 4), blk, 0, stream, Kf, ABV, KK, k_k, k_a, ab, totalW, H);
    // recurrence (output into d_out)
    hipLaunchKernelGGL(rwkv_scan, dim3(B * H * 4), dim3(64), 0, stream, EW, R_, Kf, Vf, KK, ABV, O_, T, H);
    // GroupNorm + bonus + g  (ON reuses EW)
    hipLaunchKernelGGL(gn_bonus, dim3(totalW / 4), blk, 0, stream, O_, R_, Kf, Vf, HG, gB, r_k, gnw, gnb, EW, totalW, H, 64.f * 1e-5f);
    // output projection (overwrites scan output in d_out)
    hipLaunchKernelGGL(gemm_f32, gBig, blk, 0, stream, EW, nf, Wo, out, M, D, D, T, 0, nf, nf);
}

// Round 3
// 4642.299 us; speedup vs baseline: 1.1962x; 1.1962x over previous
//
#include <hip/hip_runtime.h>
#include <hip/hip_bf16.h>
#include <math.h>

// RWKV7 attention, f32 (round 3: software-pipelined DPLR scan).
// Pipeline:
//  1. gemm_f32 (mix fused into A-load): R, K0, V0 projections + 4 LoRA stage-1
//  2. activations on LoRA hiddens (tanh / sigmoid)
//  3. gemm_f32 LoRA stage-2 with fused epilogues: EW (sigmoid*e^-0.5), V-lerp (in-place), ya
//  4. ka_epi: a=sigmoid(ya+ab); kk normalize; bv=kk*a; k scale
//  5. rwkv_scan: DPLR recurrence, wave per (b,h,16 v-columns), shfl-only reductions,
//     depth-1 in-register prefetch (2 named buffers, unroll-by-2)
//  6. gn_bonus: GroupNorm + bonus + on-the-fly g (HG . gB row) -> EW
//  7. gemm_f32: output projection Wo -> d_out

#define BM 64
#define BN 64
#define BK 16

// C[M,N] = Amix[M,K] @ W[N,K]^T
// If xx != nullptr: Amix[m,k] = A[m,k] + ((t>0 ? A[m-1,k] : 0) - A[m,k]) * xx[k], t = m % T
// mode 0: C = acc
// mode 1: C = sigmoid(acc + bias[n]) * exp(-0.5)
// mode 2: C = C + sigmoid(acc + bias[n]) * (aux - C)   (in-place lerp toward aux)
__global__ __launch_bounds__(256) void gemm_f32(
    const float* __restrict__ A, const float* __restrict__ xx,
    const float* __restrict__ W, float* __restrict__ C,
    int M, int N, int K, int T, int mode,
    const float* __restrict__ bias, const float* __restrict__ aux)
{
    __shared__ float As[BK][BM + 4];
    __shared__ float Bs[BK][BN + 4];
    const int tid = threadIdx.x;
    const int m0 = blockIdx.x * BM;
    const int n0 = blockIdx.y * BN;
    const int lr = tid >> 2;          // 0..63 : row within tile
    const int lk = (tid & 3) << 2;    // 0,4,8,12 : k within K-step
    const int tx = tid & 15;
    const int ty = tid >> 4;
    const int mrow = m0 + lr;
    const int nrow = n0 + lr;
    float acc[4][4];
    #pragma unroll
    for (int i = 0; i < 4; ++i)
        #pragma unroll
        for (int j = 0; j < 4; ++j) acc[i][j] = 0.f;

    for (int k0 = 0; k0 < K; k0 += BK) {
        const float* ap = A + (size_t)mrow * K + k0 + lk;
        float4 av = *(const float4*)ap;
        if (xx) {
            const int t = mrow % T;
            float4 pv = make_float4(0.f, 0.f, 0.f, 0.f);
            if (t > 0) pv = *(const float4*)(ap - K);
            const float4 xv = *(const float4*)(xx + k0 + lk);
            av.x += (pv.x - av.x) * xv.x;
            av.y += (pv.y - av.y) * xv.y;
            av.z += (pv.z - av.z) * xv.z;
            av.w += (pv.w - av.w) * xv.w;
        }
        float4 bv = make_float4(0.f, 0.f, 0.f, 0.f);
        if (nrow < N) bv = *(const float4*)(W + (size_t)nrow * K + k0 + lk);

        As[lk + 0][lr] = av.x; As[lk + 1][lr] = av.y;
        As[lk + 2][lr] = av.z; As[lk + 3][lr] = av.w;
        Bs[lk + 0][lr] = bv.x; Bs[lk + 1][lr] = bv.y;
        Bs[lk + 2][lr] = bv.z; Bs[lk + 3][lr] = bv.w;
        __syncthreads();

        #pragma unroll
        for (int kk = 0; kk < BK; ++kk) {
            const float4 a4 = *(const float4*)&As[kk][ty << 2];
            const float4 b4 = *(const float4*)&Bs[kk][tx << 2];
            const float a[4] = {a4.x, a4.y, a4.z, a4.w};
            const float b[4] = {b4.x, b4.y, b4.z, b4.w};
            #pragma unroll
            for (int i = 0; i < 4; ++i)
                #pragma unroll
                for (int j = 0; j < 4; ++j)
                    acc[i][j] = fmaf(a[i], b[j], acc[i][j]);
        }
        __syncthreads();
    }
    #pragma unroll
    for (int i = 0; i < 4; ++i) {
        const int m = m0 + (ty << 2) + i;
        #pragma unroll
        for (int j = 0; j < 4; ++j) {
            const int n = n0 + (tx << 2) + j;
            if (n < N) {
                const size_t idx = (size_t)m * N + n;
                float v = acc[i][j];
                if (mode == 1) {
                    v = 0.6065306597126334f / (1.f + expf(-(v + bias[n])));
                } else if (mode == 2) {
                    const float v0 = C[idx];
                    const float sg = 1.f / (1.f + expf(-(v + bias[n])));
                    v = v0 + sg * (aux[idx] - v0);
                }
                C[idx] = v;
            }
        }
    }
}

__global__ void unary_act(float* __restrict__ x, int n, int mode)
{
    int i = blockIdx.x * 256 + threadIdx.x;
    if (i < n) {
        float v = x[i];
        x[i] = (mode == 0) ? tanhf(v) : 1.f / (1.f + expf(-v));
    }
}

// per-(b,t,h) wave: a = sigmoid(ya+ab); kk = normalize(k0*k_k); bv = kk*a;
// kfinal = k0*(1+(a-1)*k_a)
__global__ __launch_bounds__(256) void ka_epi(
    float* __restrict__ Kf, float* __restrict__ A_BV, float* __restrict__ KKo,
    const float* __restrict__ k_k, const float* __restrict__ k_a,
    const float* __restrict__ ab, int total, int H)
{
    int wid = (blockIdx.x << 2) | (threadIdx.x >> 6);
    if (wid >= total) return;
    const int l = threadIdx.x & 63;
    const int h = wid % H;
    const int ch = h * 64 + l;
    const size_t base = (size_t)wid * 64;
    float k0 = Kf[base + l];
    float a = 1.f / (1.f + expf(-(A_BV[base + l] + ab[ch])));
    float kkr = k0 * k_k[ch];
    float ss = kkr * kkr;
    #pragma unroll
    for (int off = 1; off < 64; off <<= 1) ss += __shfl_xor(ss, off, 64);
    float inv = 1.f / fmaxf(sqrtf(ss), 1e-12f);
    float kkn = kkr * inv;
    KKo[base + l] = kkn;
    A_BV[base + l] = kkn * a;
    Kf[base + l] = k0 * fmaf(a - 1.f, k_a[ch], 1.f);
}

// DPLR scan, software-pipelined (depth-1 prefetch, unroll-by-2).
// One wave per (b, h, 16-column slab of v).
// lane l: v = slab*16 + (l&15), owns k in [ (l>>4)*16, +16 ).
// sa and o reductions over k-quarters = shfl_xor(16), shfl_xor(32). No barriers.
__global__ __launch_bounds__(64) void rwkv_scan(
    const float* __restrict__ EW, const float* __restrict__ R,
    const float* __restrict__ Kf, const float* __restrict__ Vf,
    const float* __restrict__ KK, const float* __restrict__ BV,
    float* __restrict__ O, int T, int H)
{
    const int blk = blockIdx.x;
    const int slab = blk & 3;
    const int bh = blk >> 2;
    const int b = bh / H, h = bh % H;
    const int l = threadIdx.x;
    const int v = (slab << 4) | (l & 15);
    const int ko = l & 48;   // k-quarter offset
    const size_t step = (size_t)H * 64;
    const size_t base0 = ((size_t)b * T * H + h) * 64;

    float s[16];
    #pragma unroll
    for (int i = 0; i < 16; ++i) s[i] = 0.f;

    struct Buf {
        alignas(16) float ew[16];
        alignas(16) float rr[16];
        alignas(16) float kf[16];
        alignas(16) float kv[16];
        alignas(16) float bb[16];
        float vv;
    };
    Buf A, B;

    auto issue = [&](int t, Buf& S) {
        const int tt = (t < T) ? t : (T - 1);          // clamp (harmless reload at tail)
        const size_t o = base0 + (size_t)tt * step;
        const float4* pe = (const float4*)(EW + o + ko);
        const float4* pr = (const float4*)(R  + o + ko);
        const float4* pk = (const float4*)(Kf + o + ko);
        const float4* pq = (const float4*)(KK + o + ko);
        const float4* pb = (const float4*)(BV + o + ko);
        #pragma unroll
        for (int j = 0; j < 4; ++j) {
            ((float4*)S.ew)[j] = pe[j];
            ((float4*)S.rr)[j] = pr[j];
            ((float4*)S.kf)[j] = pk[j];
            ((float4*)S.kv)[j] = pq[j];
            ((float4*)S.bb)[j] = pb[j];
        }
        S.vv = Vf[o + v];
    };

    auto docompute = [&](const Buf& S, int t) {
        float sa0 = 0.f, sa1 = 0.f, sa2 = 0.f, sa3 = 0.f;
        #pragma unroll
        for (int i = 0; i < 16; i += 4) {
            s[i+0] *= S.ew[i+0]; s[i+1] *= S.ew[i+1];
            s[i+2] *= S.ew[i+2]; s[i+3] *= S.ew[i+3];
            sa0 = fmaf(S.kv[i+0], s[i+0], sa0);
            sa1 = fmaf(S.kv[i+1], s[i+1], sa1);
            sa2 = fmaf(S.kv[i+2], s[i+2], sa2);
            sa3 = fmaf(S.kv[i+3], s[i+3], sa3);
        }
        float sa = -((sa0 + sa1) + (sa2 + sa3));   // a_t = -kk
        sa += __shfl_xor(sa, 16, 64);
        sa += __shfl_xor(sa, 32, 64);

        const float vv = S.vv;
        float o0 = 0.f, o1 = 0.f, o2 = 0.f, o3 = 0.f;
        #pragma unroll
        for (int i = 0; i < 16; i += 4) {
            s[i+0] = fmaf(S.bb[i+0], sa, fmaf(S.kf[i+0], vv, s[i+0]));
            s[i+1] = fmaf(S.bb[i+1], sa, fmaf(S.kf[i+1], vv, s[i+1]));
            s[i+2] = fmaf(S.bb[i+2], sa, fmaf(S.kf[i+2], vv, s[i+2]));
            s[i+3] = fmaf(S.bb[i+3], sa, fmaf(S.kf[i+3], vv, s[i+3]));
            o0 = fmaf(S.rr[i+0], s[i+0], o0);
            o1 = fmaf(S.rr[i+1], s[i+1], o1);
            o2 = fmaf(S.rr[i+2], s[i+2], o2);
            o3 = fmaf(S.rr[i+3], s[i+3], o3);
        }
        float oo = (o0 + o1) + (o2 + o3);
        oo += __shfl_xor(oo, 16, 64);
        oo += __shfl_xor(oo, 32, 64);
        if (ko == 0) O[base0 + (size_t)t * step + v] = oo;
    };

    issue(0, A);
    issue(1, B);
    for (int t = 0; t < T; t += 2) {
        docompute(A, t);        // while computing A, B(t+1) loads are in flight
        issue(t + 2, A);        // prefetch t+2 into A
        docompute(B, t + 1);    // while computing B, A(t+2) loads are in flight
        issue(t + 3, B);        // prefetch t+3 into B
    }
}

// GroupNorm over head channels + bonus + on-the-fly g-gate. One wave per (b,t,h).
// g[ch] = dot(HG[m, 0:128], gB[ch, 0:128])  (HG already sigmoid-activated)
__global__ __launch_bounds__(256) void gn_bonus(
    const float* __restrict__ O, const float* __restrict__ R,
    const float* __restrict__ Kf, const float* __restrict__ Vf,
    const float* __restrict__ HG, const float* __restrict__ gB,
    const float* __restrict__ r_k,
    const float* __restrict__ gn_w, const float* __restrict__ gn_b,
    float* __restrict__ ON, int total, int H, float eps)
{
    int wid = (blockIdx.x << 2) | (threadIdx.x >> 6);
    if (wid >= total) return;
    const int l = threadIdx.x & 63;
    const int h = wid % H;
    const int ch = h * 64 + l;
    const int m = wid / H;
    const size_t base = (size_t)wid * 64;

    // g-gate: 128-dot
    const float4* hg4 = (const float4*)(HG + (size_t)m * 128);
    const float4* gb4 = (const float4*)(gB + (size_t)ch * 128);
    float g = 0.f;
    #pragma unroll 8
    for (int j = 0; j < 32; ++j) {
        const float4 a = hg4[j], b = gb4[j];
        g += a.x * b.x + a.y * b.y + a.z * b.z + a.w * b.w;
    }

    float o = O[base + l];
    float sum = o;
    #pragma unroll
    for (int off = 1; off < 64; off <<= 1) sum += __shfl_xor(sum, off, 64);
    float mu = sum * (1.f / 64.f);
    float d = o - mu;
    float ss = d * d;
    #pragma unroll
    for (int off = 1; off < 64; off <<= 1) ss += __shfl_xor(ss, off, 64);
    float inv = 1.f / sqrtf(ss * (1.f / 64.f) + eps);
    float on = d * inv * gn_w[ch] + gn_b[ch];

    float r = R[base + l], k = Kf[base + l], vv = Vf[base + l];
    float p = r * k * r_k[ch];
    #pragma unroll
    for (int off = 1; off < 64; off <<= 1) p += __shfl_xor(p, off, 64);
    on = fmaf(p, vv, on);
    ON[base + l] = on * g;
}

extern "C" void kernel_launch(void* const* d_in, const int* in_sizes, int n_in,
                              void* d_out, int out_size, void* d_ws, size_t ws_size,
                              hipStream_t stream)
{
    const int B = 2, T = 2048, D = 2048, H = 32;
    const int M = B * T;

    const float* hid = (const float*)d_in[0];
    const float* vst = (const float*)d_in[1];
    const float* x_x = (const float*)d_in[2];
    const float* k_k = (const float*)d_in[3];
    const float* k_a = (const float*)d_in[4];
    const float* r_k = (const float*)d_in[5];
    const float* Wr  = (const float*)d_in[6];
    const float* Wk  = (const float*)d_in[7];
    const float* Wv  = (const float*)d_in[8];
    const float* Wo  = (const float*)d_in[9];
    const float* wA  = (const float*)d_in[10];
    const float* wB  = (const float*)d_in[11];
    const float* wb  = (const float*)d_in[12];
    const float* vA  = (const float*)d_in[13];
    const float* vB  = (const float*)d_in[14];
    const float* vb  = (const float*)d_in[15];
    const float* aA  = (const float*)d_in[16];
    const float* aB  = (const float*)d_in[17];
    const float* ab  = (const float*)d_in[18];
    const float* gA  = (const float*)d_in[19];
    const float* gB  = (const float*)d_in[20];
    const float* gnw = (const float*)d_in[21];
    const float* gnb = (const float*)d_in[22];
    float* out = (float*)d_out;

    const size_t NE = (size_t)M * D;  // 8,388,608
    const size_t need = (6 * NE + (size_t)M * (64 + 16 + 64 + 128)) * sizeof(float);  // ~196 MiB
    if (ws_size < need) return;

    float* R_  = (float*)d_ws;
    float* EW  = R_  + NE;     // ew = exp(w); later reused as ON (gn_bonus output)
    float* Kf  = EW  + NE;
    float* Vf  = Kf  + NE;
    float* KK  = Vf  + NE;
    float* ABV = KK  + NE;     // holds ya, then bv = kk*a
    float* HW  = ABV + NE;
    float* HV  = HW + (size_t)M * 64;
    float* HA  = HV + (size_t)M * 16;
    float* HG  = HA + (size_t)M * 64;
    float* O_  = out;          // scan output lives in d_out; dead before final GEMM

    dim3 blk(256);
    dim3 gBig(M / BM, D / BN);
    const float* nf = nullptr;

    // big projections (mix fused)
    hipLaunchKernelGGL(gemm_f32, gBig, blk, 0, stream, hid, x_x + 0 * (size_t)D, Wr, R_, M, D, D, T, 0, nf, nf);
    hipLaunchKernelGGL(gemm_f32, gBig, blk, 0, stream, hid, x_x + 2 * (size_t)D, Wk, Kf, M, D, D, T, 0, nf, nf);
    hipLaunchKernelGGL(gemm_f32, gBig, blk, 0, stream, hid, x_x + 3 * (size_t)D, Wv, Vf, M, D, D, T, 0, nf, nf);
    // LoRA stage-1 (mix fused)
    hipLaunchKernelGGL(gemm_f32, dim3(M / BM, 1), blk, 0, stream, hid, x_x + 1 * (size_t)D, wA, HW, M, 64, D, T, 0, nf, nf);
    hipLaunchKernelGGL(gemm_f32, dim3(M / BM, 1), blk, 0, stream, hid, x_x + 3 * (size_t)D, vA, HV, M, 16, D, T, 0, nf, nf);
    hipLaunchKernelGGL(gemm_f32, dim3(M / BM, 1), blk, 0, stream, hid, x_x + 4 * (size_t)D, aA, HA, M, 64, D, T, 0, nf, nf);
    hipLaunchKernelGGL(gemm_f32, dim3(M / BM, 2), blk, 0, stream, hid, x_x + 5 * (size_t)D, gA, HG, M, 128, D, T, 0, nf, nf);
    // activations on LoRA hiddens
    hipLaunchKernelGGL(unary_act, dim3((M * 64 + 255) / 256), blk, 0, stream, HW, M * 64, 0);
    hipLaunchKernelGGL(unary_act, dim3((M * 128 + 255) / 256), blk, 0, stream, HG, M * 128, 1);
    // LoRA stage-2 with fused epilogues
    hipLaunchKernelGGL(gemm_f32, gBig, blk, 0, stream, HW, nf, wB, EW,  M, D, 64, T, 1, wb, nf);        // ew
    hipLaunchKernelGGL(gemm_f32, gBig, blk, 0, stream, HV, nf, vB, Vf,  M, D, 16, T, 2, vb, vst);       // v lerp (in-place)
    hipLaunchKernelGGL(gemm_f32, gBig, blk, 0, stream, HA, nf, aB, ABV, M, D, 64, T, 0, nf, nf);        // ya
    // a/kk/k epilogue
    const int totalW = M * H;
    hipLaunchKernelGGL(ka_epi, dim3(totalW / 4), blk, 0, stream, Kf, ABV, KK, k_k, k_a, ab, totalW, H);
    // recurrence (output into d_out)
    hipLaunchKernelGGL(rwkv_scan, dim3(B * H * 4), dim3(64), 0, stream, EW, R_, Kf, Vf, KK, ABV, O_, T, H);
    // GroupNorm + bonus + g  (ON reuses EW)
    hipLaunchKernelGGL(gn_bonus, dim3(totalW / 4), blk, 0, stream, O_, R_, Kf, Vf, HG, gB, r_k, gnw, gnb, EW, totalW, H, 64.f * 1e-5f);
    // output projection (overwrites scan output in d_out)
    hipLaunchKernelGGL(gemm_f32, gBig, blk, 0, stream, EW, nf, Wo, out, M, D, D, T, 0, nf, nf);
}

// Round 5
// 2907.286 us; speedup vs baseline: 1.9101x; 1.5968x over previous
//
#include <hip/hip_runtime.h>
#include <hip/hip_bf16.h>
#include <math.h>

// RWKV7 attention, round 5: split-bf16 (hi+lo) MFMA for the five DxD GEMMs,
// all inter-kernel streams f32. Scan: 1024 waves (16 v-slabs), depth-4 prefetch.
//
// Phase order (buffer reuse):
//  1. LoRA stage-1 (f32 SIMD, mix fused) -> HW,HV,HA,HG ; act(HW tanh, HG sigm)
//  2. yv = HV@vB -> ABV (f32)
//  3. R/K/V projections: mixsplit(hid,xx_i) -> hi/lo bf16 in EW window;
//     wsplit(W) -> hi/lo in KK window; gemm_dual (3-term MFMA) -> R_/Kf/Vf f32
//     (V: fused lerp epilogue reading yv=ABV, vb, v_state)
//  4. LoRA stage-2: EW <- ew (mode1) ; ABV <- ya (mode0)
//  5. ka_epi: a=sigm(ya+ab); kk normalize -> KK; bv=kk*a -> ABV; k scale -> Kf
//  6. rwkv_scan (f32): 16 slabs x 64 bh, depth-4 ring -> d_out
//  7. gn_bonus -> ON in EW (f32)
//  8. Wo: mixsplit(EW) -> KK window; wsplit(Wo) -> ABV window; gemm_dual -> d_out

typedef __attribute__((ext_vector_type(8))) unsigned short ushort8;
typedef __attribute__((ext_vector_type(8))) short bf16x8;
typedef __attribute__((ext_vector_type(4))) float f32x4;

__device__ inline float b2f(unsigned short u) {
    union { unsigned int u; float f; } x; x.u = ((unsigned int)u) << 16; return x.f;
}
__device__ inline unsigned short f2b(float f) {
    union { float f; unsigned int u; } x; x.f = f;
    return (unsigned short)((x.u + 0x7FFF + ((x.u >> 16) & 1)) >> 16);
}
__device__ inline float sigm(float x) { return 1.f / (1.f + expf(-x)); }

// ---------------- split pass: out_hi/lo = bf16 split of (optionally mixed) f32 ----------------
// domix: a = in[m,d] + ((t>0 ? in[m-1,d] : 0) - in[m,d]) * xxr[d], t = m % T
__global__ void mixsplit(const float* __restrict__ in, const float* __restrict__ xxr,
                         unsigned short* __restrict__ hi, unsigned short* __restrict__ lo,
                         int T, int D, int total8, int domix)
{
    int i = blockIdx.x * 256 + threadIdx.x;
    if (i >= total8) return;
    const size_t e = (size_t)i * 8;
    float a[8];
    *(float4*)&a[0] = *(const float4*)(in + e);
    *(float4*)&a[4] = *(const float4*)(in + e + 4);
    if (domix) {
        const int m = (int)(e / D);
        const int d = (int)(e % D);
        const int t = m % T;
        float p[8] = {0.f,0.f,0.f,0.f,0.f,0.f,0.f,0.f};
        if (t > 0) {
            *(float4*)&p[0] = *(const float4*)(in + e - D);
            *(float4*)&p[4] = *(const float4*)(in + e - D + 4);
        }
        float xv[8];
        *(float4*)&xv[0] = *(const float4*)(xxr + d);
        *(float4*)&xv[4] = *(const float4*)(xxr + d + 4);
        #pragma unroll
        for (int j = 0; j < 8; ++j) a[j] += (p[j] - a[j]) * xv[j];
    }
    ushort8 h8, l8;
    #pragma unroll
    for (int j = 0; j < 8; ++j) {
        const unsigned short h = f2b(a[j]);
        h8[j] = h;
        l8[j] = f2b(a[j] - b2f(h));
    }
    *(ushort8*)(hi + e) = h8;
    *(ushort8*)(lo + e) = l8;
}

// ---------------- dual (hi+lo) bf16 MFMA GEMM: C[M,N] = A[M,K] @ W[N,K]^T, f32 out --------
// mode 0: C = acc
// mode 2: C = lerp(acc, aux, sigmoid(yv + bias[col]))
#define GBM 128
#define GBN 128
#define LDK 36   // LDS row stride (shorts) for 32-col tile, +4 pad

__global__ __launch_bounds__(256) void gemm_dual(
    const unsigned short* __restrict__ Ahg, const unsigned short* __restrict__ Alg,
    const unsigned short* __restrict__ Bhg, const unsigned short* __restrict__ Blg,
    float* __restrict__ C, int M, int N, int K, int mode,
    const float* __restrict__ yv, const float* __restrict__ bias,
    const float* __restrict__ aux)
{
    __shared__ unsigned short Ah[GBM * LDK], Al[GBM * LDK];
    __shared__ unsigned short Bh[GBN * LDK], Bl[GBN * LDK];
    const int tid = threadIdx.x;
    const int m0 = blockIdx.x * GBM;
    const int n0 = blockIdx.y * GBN;
    const int wave = tid >> 6, lane = tid & 63;
    const int wr = (wave >> 1) * 64, wc = (wave & 1) * 64;
    const int fr = lane & 15, fq = lane >> 4;

    f32x4 acc[4][4];
    #pragma unroll
    for (int i = 0; i < 4; ++i)
        #pragma unroll
        for (int j = 0; j < 4; ++j)
            acc[i][j] = (f32x4){0.f, 0.f, 0.f, 0.f};

    const int srow = tid >> 1;
    const int scol = (tid & 1) << 4;
    const size_t aoff = (size_t)(m0 + srow) * K + scol;
    const size_t boff = (size_t)(n0 + srow) * K + scol;
    unsigned short* lah = &Ah[srow * LDK + scol];
    unsigned short* lal = &Al[srow * LDK + scol];
    unsigned short* lbh = &Bh[srow * LDK + scol];
    unsigned short* lbl = &Bl[srow * LDK + scol];

    for (int k0 = 0; k0 < K; k0 += 32) {
        const ushort8 ah0 = *(const ushort8*)(Ahg + aoff + k0);
        const ushort8 ah1 = *(const ushort8*)(Ahg + aoff + k0 + 8);
        const ushort8 al0 = *(const ushort8*)(Alg + aoff + k0);
        const ushort8 al1 = *(const ushort8*)(Alg + aoff + k0 + 8);
        const ushort8 bh0 = *(const ushort8*)(Bhg + boff + k0);
        const ushort8 bh1 = *(const ushort8*)(Bhg + boff + k0 + 8);
        const ushort8 bl0 = *(const ushort8*)(Blg + boff + k0);
        const ushort8 bl1 = *(const ushort8*)(Blg + boff + k0 + 8);
        *(ushort8*)(lah) = ah0; *(ushort8*)(lah + 8) = ah1;
        *(ushort8*)(lal) = al0; *(ushort8*)(lal + 8) = al1;
        *(ushort8*)(lbh) = bh0; *(ushort8*)(lbh + 8) = bh1;
        *(ushort8*)(lbl) = bl0; *(ushort8*)(lbl + 8) = bl1;
        __syncthreads();

        bf16x8 fah[4], fal[4], fbh[4], fbl[4];
        #pragma unroll
        for (int m = 0; m < 4; ++m) {
            fah[m] = *(const bf16x8*)&Ah[(wr + m * 16 + fr) * LDK + fq * 8];
            fal[m] = *(const bf16x8*)&Al[(wr + m * 16 + fr) * LDK + fq * 8];
        }
        #pragma unroll
        for (int n = 0; n < 4; ++n) {
            fbh[n] = *(const bf16x8*)&Bh[(wc + n * 16 + fr) * LDK + fq * 8];
            fbl[n] = *(const bf16x8*)&Bl[(wc + n * 16 + fr) * LDK + fq * 8];
        }
        #pragma unroll
        for (int m = 0; m < 4; ++m)
            #pragma unroll
            for (int n = 0; n < 4; ++n) {
                acc[m][n] = __builtin_amdgcn_mfma_f32_16x16x32_bf16(fah[m], fbh[n], acc[m][n], 0, 0, 0);
                acc[m][n] = __builtin_amdgcn_mfma_f32_16x16x32_bf16(fah[m], fbl[n], acc[m][n], 0, 0, 0);
                acc[m][n] = __builtin_amdgcn_mfma_f32_16x16x32_bf16(fal[m], fbh[n], acc[m][n], 0, 0, 0);
            }
        __syncthreads();
    }

    #pragma unroll
    for (int m = 0; m < 4; ++m) {
        const int row = m0 + wr + m * 16 + fq * 4;
        #pragma unroll
        for (int n = 0; n < 4; ++n) {
            const int col = n0 + wc + n * 16 + fr;
            #pragma unroll
            for (int j = 0; j < 4; ++j) {
                const size_t idx = (size_t)(row + j) * N + col;
                float v = acc[m][n][j];
                if (mode == 2) {
                    const float sg = sigm(yv[idx] + bias[col]);
                    v = v + sg * (aux[idx] - v);
                }
                C[idx] = v;
            }
        }
    }
}

// ---------------- f32 SIMD GEMM for LoRA ----------------
// If xx != nullptr: Amix[m,k] = A[m,k] + ((t>0 ? A[m-1,k] : 0) - A[m,k]) * xx[k]
// mode 0: C = acc ; mode 1: C = 0.6065*sigmoid(acc + bias[n])
#define BM 64
#define BN 64
#define BK 16
__global__ __launch_bounds__(256) void gemm_f32(
    const float* __restrict__ A, const float* __restrict__ xx,
    const float* __restrict__ W, float* __restrict__ C,
    int M, int N, int K, int T, int mode, const float* __restrict__ bias)
{
    __shared__ float As[BK][BM + 4];
    __shared__ float Bs[BK][BN + 4];
    const int tid = threadIdx.x;
    const int m0 = blockIdx.x * BM;
    const int n0 = blockIdx.y * BN;
    const int lr = tid >> 2;
    const int lk = (tid & 3) << 2;
    const int tx = tid & 15;
    const int ty = tid >> 4;
    const int mrow = m0 + lr;
    const int nrow = n0 + lr;
    float acc[4][4];
    #pragma unroll
    for (int i = 0; i < 4; ++i)
        #pragma unroll
        for (int j = 0; j < 4; ++j) acc[i][j] = 0.f;

    for (int k0 = 0; k0 < K; k0 += BK) {
        const float* ap = A + (size_t)mrow * K + k0 + lk;
        float4 av = *(const float4*)ap;
        if (xx) {
            const int t = mrow % T;
            float4 pv = make_float4(0.f, 0.f, 0.f, 0.f);
            if (t > 0) pv = *(const float4*)(ap - K);
            const float4 xv = *(const float4*)(xx + k0 + lk);
            av.x += (pv.x - av.x) * xv.x;
            av.y += (pv.y - av.y) * xv.y;
            av.z += (pv.z - av.z) * xv.z;
            av.w += (pv.w - av.w) * xv.w;
        }
        float4 bv = make_float4(0.f, 0.f, 0.f, 0.f);
        if (nrow < N) bv = *(const float4*)(W + (size_t)nrow * K + k0 + lk);

        As[lk + 0][lr] = av.x; As[lk + 1][lr] = av.y;
        As[lk + 2][lr] = av.z; As[lk + 3][lr] = av.w;
        Bs[lk + 0][lr] = bv.x; Bs[lk + 1][lr] = bv.y;
        Bs[lk + 2][lr] = bv.z; Bs[lk + 3][lr] = bv.w;
        __syncthreads();

        #pragma unroll
        for (int kk = 0; kk < BK; ++kk) {
            const float4 a4 = *(const float4*)&As[kk][ty << 2];
            const float4 b4 = *(const float4*)&Bs[kk][tx << 2];
            const float a[4] = {a4.x, a4.y, a4.z, a4.w};
            const float b[4] = {b4.x, b4.y, b4.z, b4.w};
            #pragma unroll
            for (int i = 0; i < 4; ++i)
                #pragma unroll
                for (int j = 0; j < 4; ++j)
                    acc[i][j] = fmaf(a[i], b[j], acc[i][j]);
        }
        __syncthreads();
    }
    #pragma unroll
    for (int i = 0; i < 4; ++i) {
        const int m = m0 + (ty << 2) + i;
        #pragma unroll
        for (int j = 0; j < 4; ++j) {
            const int n = n0 + (tx << 2) + j;
            if (n < N) {
                const size_t idx = (size_t)m * N + n;
                float v = acc[i][j];
                if (mode == 1) v = 0.6065306597126334f * sigm(v + bias[n]);
                C[idx] = v;
            }
        }
    }
}

__global__ void unary_act(float* __restrict__ x, int n, int mode)
{
    int i = blockIdx.x * 256 + threadIdx.x;
    if (i < n) {
        float v = x[i];
        x[i] = (mode == 0) ? tanhf(v) : sigm(v);
    }
}

// per-(b,t,h) wave: a = sigmoid(ya+ab); kk = normalize(k0*k_k); bv = kk*a;
// kfinal = k0*(1+(a-1)*k_a)
__global__ __launch_bounds__(256) void ka_epi(
    float* __restrict__ Kf, float* __restrict__ A_BV, float* __restrict__ KKo,
    const float* __restrict__ k_k, const float* __restrict__ k_a,
    const float* __restrict__ ab, int total, int H)
{
    int wid = (blockIdx.x << 2) | (threadIdx.x >> 6);
    if (wid >= total) return;
    const int l = threadIdx.x & 63;
    const int h = wid % H;
    const int ch = h * 64 + l;
    const size_t base = (size_t)wid * 64;
    float k0 = Kf[base + l];
    float a = sigm(A_BV[base + l] + ab[ch]);
    float kkr = k0 * k_k[ch];
    float ss = kkr * kkr;
    #pragma unroll
    for (int off = 1; off < 64; off <<= 1) ss += __shfl_xor(ss, off, 64);
    float inv = 1.f / fmaxf(sqrtf(ss), 1e-12f);
    float kkn = kkr * inv;
    KKo[base + l] = kkn;
    A_BV[base + l] = kkn * a;
    Kf[base + l] = k0 * fmaf(a - 1.f, k_a[ch], 1.f);
}

// DPLR scan, f32 streams. 1024 waves: 16 v-slabs (4 cols each) x 64 (b,h).
// bh = blk & 63 so all 16 slabs of one (b,h) share blk%8 (same XCD L2).
// lane l: vcol = slab*4 + (l&3), owns k in [ (l>>2)*4, +4 ). Depth-4 prefetch ring.
__global__ __launch_bounds__(64) void rwkv_scan(
    const float* __restrict__ EW, const float* __restrict__ R,
    const float* __restrict__ Kf, const float* __restrict__ Vf,
    const float* __restrict__ KK, const float* __restrict__ BV,
    float* __restrict__ O, int T, int H)
{
    const int blk = blockIdx.x;
    const int bh = blk & 63;
    const int slab = blk >> 6;
    const int b = bh >> 5, h = bh & 31;
    const int l = threadIdx.x;
    const int vc = (slab << 2) | (l & 3);
    const int kb = (l >> 2) << 2;
    const size_t step = (size_t)H * 64;
    const size_t base0 = ((size_t)b * T * H + h) * 64;

    float s0 = 0.f, s1 = 0.f, s2 = 0.f, s3 = 0.f;

    struct Buf { float4 ew, rr, kf, kv, bb; float vv; };
    Buf Ab, Bb, Cb, Db;

    auto issue = [&](int t, Buf& S) {
        const int tt = (t < T) ? t : (T - 1);
        const size_t o = base0 + (size_t)tt * step;
        S.ew = *(const float4*)(EW + o + kb);
        S.rr = *(const float4*)(R  + o + kb);
        S.kf = *(const float4*)(Kf + o + kb);
        S.kv = *(const float4*)(KK + o + kb);
        S.bb = *(const float4*)(BV + o + kb);
        S.vv = Vf[o + vc];
    };

    auto comp = [&](const Buf& S, int t) {
        s0 *= S.ew.x; s1 *= S.ew.y; s2 *= S.ew.z; s3 *= S.ew.w;
        float p = fmaf(S.kv.x, s0, fmaf(S.kv.y, s1, fmaf(S.kv.z, s2, S.kv.w * s3)));
        p = -p;
        p += __shfl_xor(p, 4, 64);
        p += __shfl_xor(p, 8, 64);
        p += __shfl_xor(p, 16, 64);
        p += __shfl_xor(p, 32, 64);
        const float vv = S.vv;
        s0 = fmaf(S.bb.x, p, fmaf(S.kf.x, vv, s0));
        s1 = fmaf(S.bb.y, p, fmaf(S.kf.y, vv, s1));
        s2 = fmaf(S.bb.z, p, fmaf(S.kf.z, vv, s2));
        s3 = fmaf(S.bb.w, p, fmaf(S.kf.w, vv, s3));
        float oo = fmaf(S.rr.x, s0, fmaf(S.rr.y, s1, fmaf(S.rr.z, s2, S.rr.w * s3)));
        oo += __shfl_xor(oo, 4, 64);
        oo += __shfl_xor(oo, 8, 64);
        oo += __shfl_xor(oo, 16, 64);
        oo += __shfl_xor(oo, 32, 64);
        if ((l >> 2) == 0) O[base0 + (size_t)t * step + vc] = oo;
    };

    issue(0, Ab); issue(1, Bb); issue(2, Cb); issue(3, Db);
    for (int t = 0; t < T; t += 4) {
        comp(Ab, t);     issue(t + 4, Ab);
        comp(Bb, t + 1); issue(t + 5, Bb);
        comp(Cb, t + 2); issue(t + 6, Cb);
        comp(Db, t + 3); issue(t + 7, Db);
    }
}

// GroupNorm + bonus + on-the-fly g (HG[m,:128] . gB[ch,:128]); f32 ON out.
__global__ __launch_bounds__(256) void gn_bonus(
    const float* __restrict__ O, const float* __restrict__ R,
    const float* __restrict__ Kf, const float* __restrict__ Vf,
    const float* __restrict__ HG, const float* __restrict__ gB,
    const float* __restrict__ r_k,
    const float* __restrict__ gn_w, const float* __restrict__ gn_b,
    float* __restrict__ ON, int total, int H, float eps)
{
    int wid = (blockIdx.x << 2) | (threadIdx.x >> 6);
    if (wid >= total) return;
    const int l = threadIdx.x & 63;
    const int h = wid % H;
    const int ch = h * 64 + l;
    const int m = wid / H;
    const size_t base = (size_t)wid * 64;

    const float4* hg4 = (const float4*)(HG + (size_t)m * 128);
    const float4* gb4 = (const float4*)(gB + (size_t)ch * 128);
    float g = 0.f;
    #pragma unroll 8
    for (int j = 0; j < 32; ++j) {
        const float4 a = hg4[j], b = gb4[j];
        g += a.x * b.x + a.y * b.y + a.z * b.z + a.w * b.w;
    }

    const float o = O[base + l];
    float sum = o;
    #pragma unroll
    for (int off = 1; off < 64; off <<= 1) sum += __shfl_xor(sum, off, 64);
    const float mu = sum * (1.f / 64.f);
    const float d = o - mu;
    float ss = d * d;
    #pragma unroll
    for (int off = 1; off < 64; off <<= 1) ss += __shfl_xor(ss, off, 64);
    const float inv = 1.f / sqrtf(ss * (1.f / 64.f) + eps);
    float on = d * inv * gn_w[ch] + gn_b[ch];

    const float r = R[base + l], k = Kf[base + l], vv = Vf[base + l];
    float p = r * k * r_k[ch];
    #pragma unroll
    for (int off = 1; off < 64; off <<= 1) p += __shfl_xor(p, off, 64);
    on = fmaf(p, vv, on);
    ON[base + l] = on * g;
}

extern "C" void kernel_launch(void* const* d_in, const int* in_sizes, int n_in,
                              void* d_out, int out_size, void* d_ws, size_t ws_size,
                              hipStream_t stream)
{
    const int B = 2, T = 2048, D = 2048, H = 32;
    const int M = B * T;

    const float* hid = (const float*)d_in[0];
    const float* vst = (const float*)d_in[1];
    const float* x_x = (const float*)d_in[2];
    const float* k_k = (const float*)d_in[3];
    const float* k_a = (const float*)d_in[4];
    const float* r_k = (const float*)d_in[5];
    const float* Wr  = (const float*)d_in[6];
    const float* Wk  = (const float*)d_in[7];
    const float* Wv  = (const float*)d_in[8];
    const float* Wo  = (const float*)d_in[9];
    const float* wA  = (const float*)d_in[10];
    const float* wB  = (const float*)d_in[11];
    const float* wb  = (const float*)d_in[12];
    const float* vA  = (const float*)d_in[13];
    const float* vB  = (const float*)d_in[14];
    const float* vb  = (const float*)d_in[15];
    const float* aA  = (const float*)d_in[16];
    const float* aB  = (const float*)d_in[17];
    const float* ab  = (const float*)d_in[18];
    const float* gA  = (const float*)d_in[19];
    const float* gB  = (const float*)d_in[20];
    const float* gnw = (const float*)d_in[21];
    const float* gnb = (const float*)d_in[22];
    float* out = (float*)d_out;

    const size_t NE = (size_t)M * D;   // 8,388,608
    const size_t DD = (size_t)D * D;   // 4,194,304
    const size_t need = (6 * NE + (size_t)M * 272) * sizeof(float);  // ~196 MiB (proven)
    if (ws_size < need) return;

    float* R_  = (float*)d_ws;
    float* EW  = R_  + NE;   // phase3: X hi/lo staging (ushort); then ew; then ON
    float* Kf  = EW  + NE;
    float* Vf  = Kf  + NE;
    float* KK  = Vf  + NE;   // phase3: W hi/lo staging; then kk; phase8: X hi/lo staging
    float* ABV = KK  + NE;   // yv, then ya, then bv; phase8: W hi/lo staging
    float* HW  = ABV + NE;
    float* HV  = HW + (size_t)M * 64;
    float* HA  = HV + (size_t)M * 16;
    float* HG  = HA + (size_t)M * 64;

    dim3 blk(256);
    dim3 gDual(M / GBM, D / GBN);
    const int nMix = (int)(NE / 8);     // 1,048,576 -> 4096 blocks
    const int nW   = (int)(DD / 8);     // 524,288 -> 2048 blocks
    const float* nf = nullptr;

    unsigned short* XHi = (unsigned short*)EW;   // NE shorts
    unsigned short* XLo = XHi + NE;
    unsigned short* WHi = (unsigned short*)KK;   // DD shorts
    unsigned short* WLo = WHi + DD;

    // ---- phase 1: LoRA stage-1 + activations ----
    hipLaunchKernelGGL(gemm_f32, dim3(M / BM, 1), blk, 0, stream, hid, x_x + 1 * (size_t)D, wA, HW, M, 64,  D, T, 0, nf);
    hipLaunchKernelGGL(gemm_f32, dim3(M / BM, 1), blk, 0, stream, hid, x_x + 3 * (size_t)D, vA, HV, M, 16,  D, T, 0, nf);
    hipLaunchKernelGGL(gemm_f32, dim3(M / BM, 1), blk, 0, stream, hid, x_x + 4 * (size_t)D, aA, HA, M, 64,  D, T, 0, nf);
    hipLaunchKernelGGL(gemm_f32, dim3(M / BM, 2), blk, 0, stream, hid, x_x + 5 * (size_t)D, gA, HG, M, 128, D, T, 0, nf);
    hipLaunchKernelGGL(unary_act, dim3((M * 64  + 255) / 256), blk, 0, stream, HW, M * 64, 0);
    hipLaunchKernelGGL(unary_act, dim3((M * 128 + 255) / 256), blk, 0, stream, HG, M * 128, 1);

    // ---- phase 2: yv -> ABV ----
    hipLaunchKernelGGL(gemm_f32, dim3(M / BM, D / BN), blk, 0, stream, HV, nf, vB, ABV, M, D, 16, T, 0, nf);

    // ---- phase 3: R/K/V projections via split MFMA ----
    hipLaunchKernelGGL(mixsplit, dim3(nMix / 256), blk, 0, stream, hid, x_x + 0 * (size_t)D, XHi, XLo, T, D, nMix, 1);
    hipLaunchKernelGGL(mixsplit, dim3(nW / 256), blk, 0, stream, Wr, nf, WHi, WLo, T, D, nW, 0);
    hipLaunchKernelGGL(gemm_dual, gDual, blk, 0, stream, XHi, XLo, WHi, WLo, R_, M, D, D, 0, nf, nf, nf);

    hipLaunchKernelGGL(mixsplit, dim3(nMix / 256), blk, 0, stream, hid, x_x + 2 * (size_t)D, XHi, XLo, T, D, nMix, 1);
    hipLaunchKernelGGL(mixsplit, dim3(nW / 256), blk, 0, stream, Wk, nf, WHi, WLo, T, D, nW, 0);
    hipLaunchKernelGGL(gemm_dual, gDual, blk, 0, stream, XHi, XLo, WHi, WLo, Kf, M, D, D, 0, nf, nf, nf);

    hipLaunchKernelGGL(mixsplit, dim3(nMix / 256), blk, 0, stream, hid, x_x + 3 * (size_t)D, XHi, XLo, T, D, nMix, 1);
    hipLaunchKernelGGL(mixsplit, dim3(nW / 256), blk, 0, stream, Wv, nf, WHi, WLo, T, D, nW, 0);
    hipLaunchKernelGGL(gemm_dual, gDual, blk, 0, stream, XHi, XLo, WHi, WLo, Vf, M, D, D, 2, ABV, vb, vst);

    // ---- phase 4: LoRA stage-2 ----
    hipLaunchKernelGGL(gemm_f32, dim3(M / BM, D / BN), blk, 0, stream, HW, nf, wB, EW,  M, D, 64, T, 1, wb);
    hipLaunchKernelGGL(gemm_f32, dim3(M / BM, D / BN), blk, 0, stream, HA, nf, aB, ABV, M, D, 64, T, 0, nf);

    // ---- phase 5: ka epilogue ----
    const int totalW = M * H;
    hipLaunchKernelGGL(ka_epi, dim3(totalW / 4), blk, 0, stream, Kf, ABV, KK, k_k, k_a, ab, totalW, H);

    // ---- phase 6: scan -> d_out ----
    hipLaunchKernelGGL(rwkv_scan, dim3(B * H * 16), dim3(64), 0, stream, EW, R_, Kf, Vf, KK, ABV, out, T, H);

    // ---- phase 7: GroupNorm + bonus + g -> EW ----
    hipLaunchKernelGGL(gn_bonus, dim3(totalW / 4), blk, 0, stream, out, R_, Kf, Vf, HG, gB, r_k, gnw, gnb, EW, totalW, H, 64.f * 1e-5f);

    // ---- phase 8: Wo projection -> d_out ----
    unsigned short* XHi2 = (unsigned short*)KK;
    unsigned short* XLo2 = XHi2 + NE;
    unsigned short* WHi2 = (unsigned short*)ABV;
    unsigned short* WLo2 = WHi2 + DD;
    hipLaunchKernelGGL(mixsplit, dim3(nMix / 256), blk, 0, stream, EW, nf, XHi2, XLo2, T, D, nMix, 0);
    hipLaunchKernelGGL(mixsplit, dim3(nW / 256), blk, 0, stream, Wo, nf, WHi2, WLo2, T, D, nW, 0);
    hipLaunchKernelGGL(gemm_dual, gDual, blk, 0, stream, XHi2, XLo2, WHi2, WLo2, out, M, D, D, 0, nf, nf, nf);
}

// Round 6
// 2868.272 us; speedup vs baseline: 1.9361x; 1.0136x over previous
//
#include <hip/hip_runtime.h>
#include <hip/hip_bf16.h>
#include <math.h>

// RWKV7 attention, round 6: chunk-staged LDS pipeline for the scan.
// (All non-scan kernels identical to round 5.)
//
// Phase order (buffer reuse):
//  1. LoRA stage-1 (f32 SIMD, mix fused) -> HW,HV,HA,HG ; act(HW tanh, HG sigm)
//  2. yv = HV@vB -> ABV (f32)
//  3. R/K/V projections: mixsplit -> hi/lo bf16; gemm_dual (3-term MFMA) -> f32
//  4. LoRA stage-2: EW <- ew ; ABV <- ya
//  5. ka_epi: a=sigm(ya+ab); kk normalize -> KK; bv=kk*a -> ABV; k scale -> Kf
//  6. rwkv_scan: 256 blocks (4 waves, 16 v-cols each), 16-step LDS chunks,
//     global->reg issued under compute, reg->LDS after barrier -> d_out
//  7. gn_bonus -> ON in EW (f32)
//  8. Wo: mixsplit -> staging windows; gemm_dual -> d_out

typedef __attribute__((ext_vector_type(8))) unsigned short ushort8;
typedef __attribute__((ext_vector_type(8))) short bf16x8;
typedef __attribute__((ext_vector_type(4))) float f32x4;

__device__ inline float b2f(unsigned short u) {
    union { unsigned int u; float f; } x; x.u = ((unsigned int)u) << 16; return x.f;
}
__device__ inline unsigned short f2b(float f) {
    union { float f; unsigned int u; } x; x.f = f;
    return (unsigned short)((x.u + 0x7FFF + ((x.u >> 16) & 1)) >> 16);
}
__device__ inline float sigm(float x) { return 1.f / (1.f + expf(-x)); }

// ---------------- split pass: out_hi/lo = bf16 split of (optionally mixed) f32 ----------------
__global__ void mixsplit(const float* __restrict__ in, const float* __restrict__ xxr,
                         unsigned short* __restrict__ hi, unsigned short* __restrict__ lo,
                         int T, int D, int total8, int domix)
{
    int i = blockIdx.x * 256 + threadIdx.x;
    if (i >= total8) return;
    const size_t e = (size_t)i * 8;
    float a[8];
    *(float4*)&a[0] = *(const float4*)(in + e);
    *(float4*)&a[4] = *(const float4*)(in + e + 4);
    if (domix) {
        const int m = (int)(e / D);
        const int d = (int)(e % D);
        const int t = m % T;
        float p[8] = {0.f,0.f,0.f,0.f,0.f,0.f,0.f,0.f};
        if (t > 0) {
            *(float4*)&p[0] = *(const float4*)(in + e - D);
            *(float4*)&p[4] = *(const float4*)(in + e - D + 4);
        }
        float xv[8];
        *(float4*)&xv[0] = *(const float4*)(xxr + d);
        *(float4*)&xv[4] = *(const float4*)(xxr + d + 4);
        #pragma unroll
        for (int j = 0; j < 8; ++j) a[j] += (p[j] - a[j]) * xv[j];
    }
    ushort8 h8, l8;
    #pragma unroll
    for (int j = 0; j < 8; ++j) {
        const unsigned short h = f2b(a[j]);
        h8[j] = h;
        l8[j] = f2b(a[j] - b2f(h));
    }
    *(ushort8*)(hi + e) = h8;
    *(ushort8*)(lo + e) = l8;
}

// ---------------- dual (hi+lo) bf16 MFMA GEMM: C[M,N] = A[M,K] @ W[N,K]^T, f32 out --------
#define GBM 128
#define GBN 128
#define LDK 36

__global__ __launch_bounds__(256) void gemm_dual(
    const unsigned short* __restrict__ Ahg, const unsigned short* __restrict__ Alg,
    const unsigned short* __restrict__ Bhg, const unsigned short* __restrict__ Blg,
    float* __restrict__ C, int M, int N, int K, int mode,
    const float* __restrict__ yv, const float* __restrict__ bias,
    const float* __restrict__ aux)
{
    __shared__ unsigned short Ah[GBM * LDK], Al[GBM * LDK];
    __shared__ unsigned short Bh[GBN * LDK], Bl[GBN * LDK];
    const int tid = threadIdx.x;
    const int m0 = blockIdx.x * GBM;
    const int n0 = blockIdx.y * GBN;
    const int wave = tid >> 6, lane = tid & 63;
    const int wr = (wave >> 1) * 64, wc = (wave & 1) * 64;
    const int fr = lane & 15, fq = lane >> 4;

    f32x4 acc[4][4];
    #pragma unroll
    for (int i = 0; i < 4; ++i)
        #pragma unroll
        for (int j = 0; j < 4; ++j)
            acc[i][j] = (f32x4){0.f, 0.f, 0.f, 0.f};

    const int srow = tid >> 1;
    const int scol = (tid & 1) << 4;
    const size_t aoff = (size_t)(m0 + srow) * K + scol;
    const size_t boff = (size_t)(n0 + srow) * K + scol;
    unsigned short* lah = &Ah[srow * LDK + scol];
    unsigned short* lal = &Al[srow * LDK + scol];
    unsigned short* lbh = &Bh[srow * LDK + scol];
    unsigned short* lbl = &Bl[srow * LDK + scol];

    for (int k0 = 0; k0 < K; k0 += 32) {
        const ushort8 ah0 = *(const ushort8*)(Ahg + aoff + k0);
        const ushort8 ah1 = *(const ushort8*)(Ahg + aoff + k0 + 8);
        const ushort8 al0 = *(const ushort8*)(Alg + aoff + k0);
        const ushort8 al1 = *(const ushort8*)(Alg + aoff + k0 + 8);
        const ushort8 bh0 = *(const ushort8*)(Bhg + boff + k0);
        const ushort8 bh1 = *(const ushort8*)(Bhg + boff + k0 + 8);
        const ushort8 bl0 = *(const ushort8*)(Blg + boff + k0);
        const ushort8 bl1 = *(const ushort8*)(Blg + boff + k0 + 8);
        *(ushort8*)(lah) = ah0; *(ushort8*)(lah + 8) = ah1;
        *(ushort8*)(lal) = al0; *(ushort8*)(lal + 8) = al1;
        *(ushort8*)(lbh) = bh0; *(ushort8*)(lbh + 8) = bh1;
        *(ushort8*)(lbl) = bl0; *(ushort8*)(lbl + 8) = bl1;
        __syncthreads();

        bf16x8 fah[4], fal[4], fbh[4], fbl[4];
        #pragma unroll
        for (int m = 0; m < 4; ++m) {
            fah[m] = *(const bf16x8*)&Ah[(wr + m * 16 + fr) * LDK + fq * 8];
            fal[m] = *(const bf16x8*)&Al[(wr + m * 16 + fr) * LDK + fq * 8];
        }
        #pragma unroll
        for (int n = 0; n < 4; ++n) {
            fbh[n] = *(const bf16x8*)&Bh[(wc + n * 16 + fr) * LDK + fq * 8];
            fbl[n] = *(const bf16x8*)&Bl[(wc + n * 16 + fr) * LDK + fq * 8];
        }
        #pragma unroll
        for (int m = 0; m < 4; ++m)
            #pragma unroll
            for (int n = 0; n < 4; ++n) {
                acc[m][n] = __builtin_amdgcn_mfma_f32_16x16x32_bf16(fah[m], fbh[n], acc[m][n], 0, 0, 0);
                acc[m][n] = __builtin_amdgcn_mfma_f32_16x16x32_bf16(fah[m], fbl[n], acc[m][n], 0, 0, 0);
                acc[m][n] = __builtin_amdgcn_mfma_f32_16x16x32_bf16(fal[m], fbh[n], acc[m][n], 0, 0, 0);
            }
        __syncthreads();
    }

    #pragma unroll
    for (int m = 0; m < 4; ++m) {
        const int row = m0 + wr + m * 16 + fq * 4;
        #pragma unroll
        for (int n = 0; n < 4; ++n) {
            const int col = n0 + wc + n * 16 + fr;
            #pragma unroll
            for (int j = 0; j < 4; ++j) {
                const size_t idx = (size_t)(row + j) * N + col;
                float v = acc[m][n][j];
                if (mode == 2) {
                    const float sg = sigm(yv[idx] + bias[col]);
                    v = v + sg * (aux[idx] - v);
                }
                C[idx] = v;
            }
        }
    }
}

// ---------------- f32 SIMD GEMM for LoRA ----------------
#define BM 64
#define BN 64
#define BK 16
__global__ __launch_bounds__(256) void gemm_f32(
    const float* __restrict__ A, const float* __restrict__ xx,
    const float* __restrict__ W, float* __restrict__ C,
    int M, int N, int K, int T, int mode, const float* __restrict__ bias)
{
    __shared__ float As[BK][BM + 4];
    __shared__ float Bs[BK][BN + 4];
    const int tid = threadIdx.x;
    const int m0 = blockIdx.x * BM;
    const int n0 = blockIdx.y * BN;
    const int lr = tid >> 2;
    const int lk = (tid & 3) << 2;
    const int tx = tid & 15;
    const int ty = tid >> 4;
    const int mrow = m0 + lr;
    const int nrow = n0 + lr;
    float acc[4][4];
    #pragma unroll
    for (int i = 0; i < 4; ++i)
        #pragma unroll
        for (int j = 0; j < 4; ++j) acc[i][j] = 0.f;

    for (int k0 = 0; k0 < K; k0 += BK) {
        const float* ap = A + (size_t)mrow * K + k0 + lk;
        float4 av = *(const float4*)ap;
        if (xx) {
            const int t = mrow % T;
            float4 pv = make_float4(0.f, 0.f, 0.f, 0.f);
            if (t > 0) pv = *(const float4*)(ap - K);
            const float4 xv = *(const float4*)(xx + k0 + lk);
            av.x += (pv.x - av.x) * xv.x;
            av.y += (pv.y - av.y) * xv.y;
            av.z += (pv.z - av.z) * xv.z;
            av.w += (pv.w - av.w) * xv.w;
        }
        float4 bv = make_float4(0.f, 0.f, 0.f, 0.f);
        if (nrow < N) bv = *(const float4*)(W + (size_t)nrow * K + k0 + lk);

        As[lk + 0][lr] = av.x; As[lk + 1][lr] = av.y;
        As[lk + 2][lr] = av.z; As[lk + 3][lr] = av.w;
        Bs[lk + 0][lr] = bv.x; Bs[lk + 1][lr] = bv.y;
        Bs[lk + 2][lr] = bv.z; Bs[lk + 3][lr] = bv.w;
        __syncthreads();

        #pragma unroll
        for (int kk = 0; kk < BK; ++kk) {
            const float4 a4 = *(const float4*)&As[kk][ty << 2];
            const float4 b4 = *(const float4*)&Bs[kk][tx << 2];
            const float a[4] = {a4.x, a4.y, a4.z, a4.w};
            const float b[4] = {b4.x, b4.y, b4.z, b4.w};
            #pragma unroll
            for (int i = 0; i < 4; ++i)
                #pragma unroll
                for (int j = 0; j < 4; ++j)
                    acc[i][j] = fmaf(a[i], b[j], acc[i][j]);
        }
        __syncthreads();
    }
    #pragma unroll
    for (int i = 0; i < 4; ++i) {
        const int m = m0 + (ty << 2) + i;
        #pragma unroll
        for (int j = 0; j < 4; ++j) {
            const int n = n0 + (tx << 2) + j;
            if (n < N) {
                const size_t idx = (size_t)m * N + n;
                float v = acc[i][j];
                if (mode == 1) v = 0.6065306597126334f * sigm(v + bias[n]);
                C[idx] = v;
            }
        }
    }
}

__global__ void unary_act(float* __restrict__ x, int n, int mode)
{
    int i = blockIdx.x * 256 + threadIdx.x;
    if (i < n) {
        float v = x[i];
        x[i] = (mode == 0) ? tanhf(v) : sigm(v);
    }
}

// per-(b,t,h) wave: a = sigmoid(ya+ab); kk = normalize(k0*k_k); bv = kk*a;
// kfinal = k0*(1+(a-1)*k_a)
__global__ __launch_bounds__(256) void ka_epi(
    float* __restrict__ Kf, float* __restrict__ A_BV, float* __restrict__ KKo,
    const float* __restrict__ k_k, const float* __restrict__ k_a,
    const float* __restrict__ ab, int total, int H)
{
    int wid = (blockIdx.x << 2) | (threadIdx.x >> 6);
    if (wid >= total) return;
    const int l = threadIdx.x & 63;
    const int h = wid % H;
    const int ch = h * 64 + l;
    const size_t base = (size_t)wid * 64;
    float k0 = Kf[base + l];
    float a = sigm(A_BV[base + l] + ab[ch]);
    float kkr = k0 * k_k[ch];
    float ss = kkr * kkr;
    #pragma unroll
    for (int off = 1; off < 64; off <<= 1) ss += __shfl_xor(ss, off, 64);
    float inv = 1.f / fmaxf(sqrtf(ss), 1e-12f);
    float kkn = kkr * inv;
    KKo[base + l] = kkn;
    A_BV[base + l] = kkn * a;
    Kf[base + l] = k0 * fmaf(a - 1.f, k_a[ch], 1.f);
}

// DPLR scan, chunk-staged LDS pipeline.
// Block = 256 threads (4 waves) = one (b,h) x one 16-v-col slab. Grid = B*H*4 = 256.
// Wave w handles v-cols slab*16 + w*4 .. +3; lane l: vcl=(w<<2)|(l&3), k in [kb,kb+4), kb=(l>>2)*4.
// Per CH=16-step chunk: global->reg loads issued at chunk start (in flight under
// compute of current chunk), reg->LDS after post-compute barrier (T14 split).
// LDS per buffer: 5 streams [16][64] + V [16][16] = 5376 floats; double-buffered (43KB).
#define CH 16
__global__ __launch_bounds__(256) void rwkv_scan(
    const float* __restrict__ EW, const float* __restrict__ R,
    const float* __restrict__ Kf, const float* __restrict__ Vf,
    const float* __restrict__ KK, const float* __restrict__ BV,
    float* __restrict__ O, int T, int H)
{
    __shared__ float lds[2][5 * CH * 64 + CH * 16];

    const int blk = blockIdx.x;
    const int bh = blk & 63;
    const int slab = blk >> 6;            // 0..3
    const int b = bh >> 5, h = bh & 31;
    const int tid = threadIdx.x;
    const int w = tid >> 6;
    const int l = tid & 63;
    const int vcl = (w << 2) | (l & 3);   // 0..15 within slab
    const int kb = (l >> 2) << 2;         // 0..60
    const size_t step = (size_t)H * 64;
    const size_t base0 = ((size_t)b * T * H + h) * 64;

    // wave w's "own" stream (0:EW 1:R 2:Kf 3:KK); BV split across waves; V by wave 0
    const float* sp = (w == 0) ? EW : (w == 1) ? R : (w == 2) ? Kf : KK;
    const int lrow = l >> 4;              // 0..3 (row within a 4-row block)
    const int lcol = (l & 15) << 2;       // 0..60 (float col)

    float4 r0, r1, r2, r3, r4, r5;

    auto load_chunk = [&](int c) {
        const size_t t0 = (size_t)c * CH;
        const float* own = sp + base0 + (t0 + lrow) * step + lcol;
        r0 = *(const float4*)(own);
        r1 = *(const float4*)(own + 4 * step);
        r2 = *(const float4*)(own + 8 * step);
        r3 = *(const float4*)(own + 12 * step);
        r4 = *(const float4*)(BV + base0 + (t0 + w * 4 + lrow) * step + lcol);
        if (w == 0)
            r5 = *(const float4*)(Vf + base0 + (t0 + (l >> 2)) * step + (slab << 4) + ((l & 3) << 2));
    };

    auto write_chunk = [&](int buf) {
        float* L = lds[buf];
        float* ownL = L + w * (CH * 64) + lrow * 64 + lcol;
        *(float4*)(ownL)            = r0;
        *(float4*)(ownL + 4 * 64)   = r1;
        *(float4*)(ownL + 8 * 64)   = r2;
        *(float4*)(ownL + 12 * 64)  = r3;
        *(float4*)(L + 4 * (CH * 64) + (w * 4 + lrow) * 64 + lcol) = r4;
        if (w == 0)
            *(float4*)(L + 5 * (CH * 64) + (l >> 2) * 16 + ((l & 3) << 2)) = r5;
    };

    float s0 = 0.f, s1 = 0.f, s2 = 0.f, s3 = 0.f;
    const int NCH = T / CH;

    load_chunk(0);
    write_chunk(0);
    __syncthreads();

    for (int c = 0; c < NCH; ++c) {
        if (c + 1 < NCH) load_chunk(c + 1);     // in flight during compute

        const float* L = lds[c & 1];
        const size_t tbase = base0 + (size_t)c * CH * step;
        #pragma unroll
        for (int tt = 0; tt < CH; ++tt) {
            const float4 ew = *(const float4*)(L + 0 * (CH * 64) + tt * 64 + kb);
            const float4 rr = *(const float4*)(L + 1 * (CH * 64) + tt * 64 + kb);
            const float4 kf = *(const float4*)(L + 2 * (CH * 64) + tt * 64 + kb);
            const float4 kv = *(const float4*)(L + 3 * (CH * 64) + tt * 64 + kb);
            const float4 bb = *(const float4*)(L + 4 * (CH * 64) + tt * 64 + kb);
            const float  vv = L[5 * (CH * 64) + tt * 16 + vcl];

            s0 *= ew.x; s1 *= ew.y; s2 *= ew.z; s3 *= ew.w;
            float p = fmaf(kv.x, s0, fmaf(kv.y, s1, fmaf(kv.z, s2, kv.w * s3)));
            p = -p;
            p += __shfl_xor(p, 4, 64);
            p += __shfl_xor(p, 8, 64);
            p += __shfl_xor(p, 16, 64);
            p += __shfl_xor(p, 32, 64);
            s0 = fmaf(bb.x, p, fmaf(kf.x, vv, s0));
            s1 = fmaf(bb.y, p, fmaf(kf.y, vv, s1));
            s2 = fmaf(bb.z, p, fmaf(kf.z, vv, s2));
            s3 = fmaf(bb.w, p, fmaf(kf.w, vv, s3));
            float oo = fmaf(rr.x, s0, fmaf(rr.y, s1, fmaf(rr.z, s2, rr.w * s3)));
            oo += __shfl_xor(oo, 4, 64);
            oo += __shfl_xor(oo, 8, 64);
            oo += __shfl_xor(oo, 16, 64);
            oo += __shfl_xor(oo, 32, 64);
            if ((l >> 2) == 0)
                O[tbase + (size_t)tt * step + (slab << 4) + vcl] = oo;
        }
        __syncthreads();                         // everyone done reading lds[c&1]
        if (c + 1 < NCH) {
            write_chunk((c + 1) & 1);
            __syncthreads();
        }
    }
}

// GroupNorm + bonus + on-the-fly g (HG[m,:128] . gB[ch,:128]); f32 ON out.
__global__ __launch_bounds__(256) void gn_bonus(
    const float* __restrict__ O, const float* __restrict__ R,
    const float* __restrict__ Kf, const float* __restrict__ Vf,
    const float* __restrict__ HG, const float* __restrict__ gB,
    const float* __restrict__ r_k,
    const float* __restrict__ gn_w, const float* __restrict__ gn_b,
    float* __restrict__ ON, int total, int H, float eps)
{
    int wid = (blockIdx.x << 2) | (threadIdx.x >> 6);
    if (wid >= total) return;
    const int l = threadIdx.x & 63;
    const int h = wid % H;
    const int ch = h * 64 + l;
    const int m = wid / H;
    const size_t base = (size_t)wid * 64;

    const float4* hg4 = (const float4*)(HG + (size_t)m * 128);
    const float4* gb4 = (const float4*)(gB + (size_t)ch * 128);
    float g = 0.f;
    #pragma unroll 8
    for (int j = 0; j < 32; ++j) {
        const float4 a = hg4[j], b = gb4[j];
        g += a.x * b.x + a.y * b.y + a.z * b.z + a.w * b.w;
    }

    const float o = O[base + l];
    float sum = o;
    #pragma unroll
    for (int off = 1; off < 64; off <<= 1) sum += __shfl_xor(sum, off, 64);
    const float mu = sum * (1.f / 64.f);
    const float d = o - mu;
    float ss = d * d;
    #pragma unroll
    for (int off = 1; off < 64; off <<= 1) ss += __shfl_xor(ss, off, 64);
    const float inv = 1.f / sqrtf(ss * (1.f / 64.f) + eps);
    float on = d * inv * gn_w[ch] + gn_b[ch];

    const float r = R[base + l], k = Kf[base + l], vv = Vf[base + l];
    float p = r * k * r_k[ch];
    #pragma unroll
    for (int off = 1; off < 64; off <<= 1) p += __shfl_xor(p, off, 64);
    on = fmaf(p, vv, on);
    ON[base + l] = on * g;
}

extern "C" void kernel_launch(void* const* d_in, const int* in_sizes, int n_in,
                              void* d_out, int out_size, void* d_ws, size_t ws_size,
                              hipStream_t stream)
{
    const int B = 2, T = 2048, D = 2048, H = 32;
    const int M = B * T;

    const float* hid = (const float*)d_in[0];
    const float* vst = (const float*)d_in[1];
    const float* x_x = (const float*)d_in[2];
    const float* k_k = (const float*)d_in[3];
    const float* k_a = (const float*)d_in[4];
    const float* r_k = (const float*)d_in[5];
    const float* Wr  = (const float*)d_in[6];
    const float* Wk  = (const float*)d_in[7];
    const float* Wv  = (const float*)d_in[8];
    const float* Wo  = (const float*)d_in[9];
    const float* wA  = (const float*)d_in[10];
    const float* wB  = (const float*)d_in[11];
    const float* wb  = (const float*)d_in[12];
    const float* vA  = (const float*)d_in[13];
    const float* vB  = (const float*)d_in[14];
    const float* vb  = (const float*)d_in[15];
    const float* aA  = (const float*)d_in[16];
    const float* aB  = (const float*)d_in[17];
    const float* ab  = (const float*)d_in[18];
    const float* gA  = (const float*)d_in[19];
    const float* gB  = (const float*)d_in[20];
    const float* gnw = (const float*)d_in[21];
    const float* gnb = (const float*)d_in[22];
    float* out = (float*)d_out;

    const size_t NE = (size_t)M * D;   // 8,388,608
    const size_t DD = (size_t)D * D;   // 4,194,304
    const size_t need = (6 * NE + (size_t)M * 272) * sizeof(float);  // ~196 MiB (proven)
    if (ws_size < need) return;

    float* R_  = (float*)d_ws;
    float* EW  = R_  + NE;
    float* Kf  = EW  + NE;
    float* Vf  = Kf  + NE;
    float* KK  = Vf  + NE;
    float* ABV = KK  + NE;
    float* HW  = ABV + NE;
    float* HV  = HW + (size_t)M * 64;
    float* HA  = HV + (size_t)M * 16;
    float* HG  = HA + (size_t)M * 64;

    dim3 blk(256);
    dim3 gDual(M / GBM, D / GBN);
    const int nMix = (int)(NE / 8);
    const int nW   = (int)(DD / 8);
    const float* nf = nullptr;

    unsigned short* XHi = (unsigned short*)EW;
    unsigned short* XLo = XHi + NE;
    unsigned short* WHi = (unsigned short*)KK;
    unsigned short* WLo = WHi + DD;

    // ---- phase 1: LoRA stage-1 + activations ----
    hipLaunchKernelGGL(gemm_f32, dim3(M / BM, 1), blk, 0, stream, hid, x_x + 1 * (size_t)D, wA, HW, M, 64,  D, T, 0, nf);
    hipLaunchKernelGGL(gemm_f32, dim3(M / BM, 1), blk, 0, stream, hid, x_x + 3 * (size_t)D, vA, HV, M, 16,  D, T, 0, nf);
    hipLaunchKernelGGL(gemm_f32, dim3(M / BM, 1), blk, 0, stream, hid, x_x + 4 * (size_t)D, aA, HA, M, 64,  D, T, 0, nf);
    hipLaunchKernelGGL(gemm_f32, dim3(M / BM, 2), blk, 0, stream, hid, x_x + 5 * (size_t)D, gA, HG, M, 128, D, T, 0, nf);
    hipLaunchKernelGGL(unary_act, dim3((M * 64  + 255) / 256), blk, 0, stream, HW, M * 64, 0);
    hipLaunchKernelGGL(unary_act, dim3((M * 128 + 255) / 256), blk, 0, stream, HG, M * 128, 1);

    // ---- phase 2: yv -> ABV ----
    hipLaunchKernelGGL(gemm_f32, dim3(M / BM, D / BN), blk, 0, stream, HV, nf, vB, ABV, M, D, 16, T, 0, nf);

    // ---- phase 3: R/K/V projections via split MFMA ----
    hipLaunchKernelGGL(mixsplit, dim3(nMix / 256), blk, 0, stream, hid, x_x + 0 * (size_t)D, XHi, XLo, T, D, nMix, 1);
    hipLaunchKernelGGL(mixsplit, dim3(nW / 256), blk, 0, stream, Wr, nf, WHi, WLo, T, D, nW, 0);
    hipLaunchKernelGGL(gemm_dual, gDual, blk, 0, stream, XHi, XLo, WHi, WLo, R_, M, D, D, 0, nf, nf, nf);

    hipLaunchKernelGGL(mixsplit, dim3(nMix / 256), blk, 0, stream, hid, x_x + 2 * (size_t)D, XHi, XLo, T, D, nMix, 1);
    hipLaunchKernelGGL(mixsplit, dim3(nW / 256), blk, 0, stream, Wk, nf, WHi, WLo, T, D, nW, 0);
    hipLaunchKernelGGL(gemm_dual, gDual, blk, 0, stream, XHi, XLo, WHi, WLo, Kf, M, D, D, 0, nf, nf, nf);

    hipLaunchKernelGGL(mixsplit, dim3(nMix / 256), blk, 0, stream, hid, x_x + 3 * (size_t)D, XHi, XLo, T, D, nMix, 1);
    hipLaunchKernelGGL(mixsplit, dim3(nW / 256), blk, 0, stream, Wv, nf, WHi, WLo, T, D, nW, 0);
    hipLaunchKernelGGL(gemm_dual, gDual, blk, 0, stream, XHi, XLo, WHi, WLo, Vf, M, D, D, 2, ABV, vb, vst);

    // ---- phase 4: LoRA stage-2 ----
    hipLaunchKernelGGL(gemm_f32, dim3(M / BM, D / BN), blk, 0, stream, HW, nf, wB, EW,  M, D, 64, T, 1, wb);
    hipLaunchKernelGGL(gemm_f32, dim3(M / BM, D / BN), blk, 0, stream, HA, nf, aB, ABV, M, D, 64, T, 0, nf);

    // ---- phase 5: ka epilogue ----
    const int totalW = M * H;
    hipLaunchKernelGGL(ka_epi, dim3(totalW / 4), blk, 0, stream, Kf, ABV, KK, k_k, k_a, ab, totalW, H);

    // ---- phase 6: scan -> d_out ----
    hipLaunchKernelGGL(rwkv_scan, dim3(B * H * 4), blk, 0, stream, EW, R_, Kf, Vf, KK, ABV, out, T, H);

    // ---- phase 7: GroupNorm + bonus + g -> EW ----
    hipLaunchKernelGGL(gn_bonus, dim3(totalW / 4), blk, 0, stream, out, R_, Kf, Vf, HG, gB, r_k, gnw, gnb, EW, totalW, H, 64.f * 1e-5f);

    // ---- phase 8: Wo projection -> d_out ----
    unsigned short* XHi2 = (unsigned short*)KK;
    unsigned short* XLo2 = XHi2 + NE;
    unsigned short* WHi2 = (unsigned short*)ABV;
    unsigned short* WLo2 = WHi2 + DD;
    hipLaunchKernelGGL(mixsplit, dim3(nMix / 256), blk, 0, stream, EW, nf, XHi2, XLo2, T, D, nMix, 0);
    hipLaunchKernelGGL(mixsplit, dim3(nW / 256), blk, 0, stream, Wo, nf, WHi2, WLo2, T, D, nW, 0);
    hipLaunchKernelGGL(gemm_dual, gDual, blk, 0, stream, XHi2, XLo2, WHi2, WLo2, out, M, D, D, 0, nf, nf, nf);
}

// Round 7
// 2762.913 us; speedup vs baseline: 2.0099x; 1.0381x over previous
//
#include <hip/hip_runtime.h>
#include <hip/hip_bf16.h>
#include <math.h>

// RWKV7 attention, round 7: scan with 16-k-per-lane mapping (2 shfls on the
// carried chain) + deferred o-reduction via LDS partials. Non-scan kernels
// identical to round 6.
//
// Phase order (buffer reuse):
//  1. LoRA stage-1 (f32 SIMD, mix fused) -> HW,HV,HA,HG ; act(HW tanh, HG sigm)
//  2. yv = HV@vB -> ABV (f32)
//  3. R/K/V projections: mixsplit -> hi/lo bf16; gemm_dual (3-term MFMA) -> f32
//  4. LoRA stage-2: EW <- ew ; ABV <- ya
//  5. ka_epi: a=sigm(ya+ab); kk normalize -> KK; bv=kk*a -> ABV; k scale -> Kf
//  6. rwkv_scan: 64 blocks (one head each; 4 waves x 16 v-cols), 16-step LDS
//     chunks, in-chunk depth-1 reg prefetch, deferred o-reduce -> d_out
//  7. gn_bonus -> ON in EW (f32)
//  8. Wo: mixsplit -> staging windows; gemm_dual -> d_out

typedef __attribute__((ext_vector_type(8))) unsigned short ushort8;
typedef __attribute__((ext_vector_type(8))) short bf16x8;
typedef __attribute__((ext_vector_type(4))) float f32x4;

__device__ inline float b2f(unsigned short u) {
    union { unsigned int u; float f; } x; x.u = ((unsigned int)u) << 16; return x.f;
}
__device__ inline unsigned short f2b(float f) {
    union { float f; unsigned int u; } x; x.f = f;
    return (unsigned short)((x.u + 0x7FFF + ((x.u >> 16) & 1)) >> 16);
}
__device__ inline float sigm(float x) { return 1.f / (1.f + expf(-x)); }

// ---------------- split pass: out_hi/lo = bf16 split of (optionally mixed) f32 ----------------
__global__ void mixsplit(const float* __restrict__ in, const float* __restrict__ xxr,
                         unsigned short* __restrict__ hi, unsigned short* __restrict__ lo,
                         int T, int D, int total8, int domix)
{
    int i = blockIdx.x * 256 + threadIdx.x;
    if (i >= total8) return;
    const size_t e = (size_t)i * 8;
    float a[8];
    *(float4*)&a[0] = *(const float4*)(in + e);
    *(float4*)&a[4] = *(const float4*)(in + e + 4);
    if (domix) {
        const int m = (int)(e / D);
        const int d = (int)(e % D);
        const int t = m % T;
        float p[8] = {0.f,0.f,0.f,0.f,0.f,0.f,0.f,0.f};
        if (t > 0) {
            *(float4*)&p[0] = *(const float4*)(in + e - D);
            *(float4*)&p[4] = *(const float4*)(in + e - D + 4);
        }
        float xv[8];
        *(float4*)&xv[0] = *(const float4*)(xxr + d);
        *(float4*)&xv[4] = *(const float4*)(xxr + d + 4);
        #pragma unroll
        for (int j = 0; j < 8; ++j) a[j] += (p[j] - a[j]) * xv[j];
    }
    ushort8 h8, l8;
    #pragma unroll
    for (int j = 0; j < 8; ++j) {
        const unsigned short h = f2b(a[j]);
        h8[j] = h;
        l8[j] = f2b(a[j] - b2f(h));
    }
    *(ushort8*)(hi + e) = h8;
    *(ushort8*)(lo + e) = l8;
}

// ---------------- dual (hi+lo) bf16 MFMA GEMM: C[M,N] = A[M,K] @ W[N,K]^T, f32 out --------
#define GBM 128
#define GBN 128
#define LDK 36

__global__ __launch_bounds__(256) void gemm_dual(
    const unsigned short* __restrict__ Ahg, const unsigned short* __restrict__ Alg,
    const unsigned short* __restrict__ Bhg, const unsigned short* __restrict__ Blg,
    float* __restrict__ C, int M, int N, int K, int mode,
    const float* __restrict__ yv, const float* __restrict__ bias,
    const float* __restrict__ aux)
{
    __shared__ unsigned short Ah[GBM * LDK], Al[GBM * LDK];
    __shared__ unsigned short Bh[GBN * LDK], Bl[GBN * LDK];
    const int tid = threadIdx.x;
    const int m0 = blockIdx.x * GBM;
    const int n0 = blockIdx.y * GBN;
    const int wave = tid >> 6, lane = tid & 63;
    const int wr = (wave >> 1) * 64, wc = (wave & 1) * 64;
    const int fr = lane & 15, fq = lane >> 4;

    f32x4 acc[4][4];
    #pragma unroll
    for (int i = 0; i < 4; ++i)
        #pragma unroll
        for (int j = 0; j < 4; ++j)
            acc[i][j] = (f32x4){0.f, 0.f, 0.f, 0.f};

    const int srow = tid >> 1;
    const int scol = (tid & 1) << 4;
    const size_t aoff = (size_t)(m0 + srow) * K + scol;
    const size_t boff = (size_t)(n0 + srow) * K + scol;
    unsigned short* lah = &Ah[srow * LDK + scol];
    unsigned short* lal = &Al[srow * LDK + scol];
    unsigned short* lbh = &Bh[srow * LDK + scol];
    unsigned short* lbl = &Bl[srow * LDK + scol];

    for (int k0 = 0; k0 < K; k0 += 32) {
        const ushort8 ah0 = *(const ushort8*)(Ahg + aoff + k0);
        const ushort8 ah1 = *(const ushort8*)(Ahg + aoff + k0 + 8);
        const ushort8 al0 = *(const ushort8*)(Alg + aoff + k0);
        const ushort8 al1 = *(const ushort8*)(Alg + aoff + k0 + 8);
        const ushort8 bh0 = *(const ushort8*)(Bhg + boff + k0);
        const ushort8 bh1 = *(const ushort8*)(Bhg + boff + k0 + 8);
        const ushort8 bl0 = *(const ushort8*)(Blg + boff + k0);
        const ushort8 bl1 = *(const ushort8*)(Blg + boff + k0 + 8);
        *(ushort8*)(lah) = ah0; *(ushort8*)(lah + 8) = ah1;
        *(ushort8*)(lal) = al0; *(ushort8*)(lal + 8) = al1;
        *(ushort8*)(lbh) = bh0; *(ushort8*)(lbh + 8) = bh1;
        *(ushort8*)(lbl) = bl0; *(ushort8*)(lbl + 8) = bl1;
        __syncthreads();

        bf16x8 fah[4], fal[4], fbh[4], fbl[4];
        #pragma unroll
        for (int m = 0; m < 4; ++m) {
            fah[m] = *(const bf16x8*)&Ah[(wr + m * 16 + fr) * LDK + fq * 8];
            fal[m] = *(const bf16x8*)&Al[(wr + m * 16 + fr) * LDK + fq * 8];
        }
        #pragma unroll
        for (int n = 0; n < 4; ++n) {
            fbh[n] = *(const bf16x8*)&Bh[(wc + n * 16 + fr) * LDK + fq * 8];
            fbl[n] = *(const bf16x8*)&Bl[(wc + n * 16 + fr) * LDK + fq * 8];
        }
        #pragma unroll
        for (int m = 0; m < 4; ++m)
            #pragma unroll
            for (int n = 0; n < 4; ++n) {
                acc[m][n] = __builtin_amdgcn_mfma_f32_16x16x32_bf16(fah[m], fbh[n], acc[m][n], 0, 0, 0);
                acc[m][n] = __builtin_amdgcn_mfma_f32_16x16x32_bf16(fah[m], fbl[n], acc[m][n], 0, 0, 0);
                acc[m][n] = __builtin_amdgcn_mfma_f32_16x16x32_bf16(fal[m], fbh[n], acc[m][n], 0, 0, 0);
            }
        __syncthreads();
    }

    #pragma unroll
    for (int m = 0; m < 4; ++m) {
        const int row = m0 + wr + m * 16 + fq * 4;
        #pragma unroll
        for (int n = 0; n < 4; ++n) {
            const int col = n0 + wc + n * 16 + fr;
            #pragma unroll
            for (int j = 0; j < 4; ++j) {
                const size_t idx = (size_t)(row + j) * N + col;
                float v = acc[m][n][j];
                if (mode == 2) {
                    const float sg = sigm(yv[idx] + bias[col]);
                    v = v + sg * (aux[idx] - v);
                }
                C[idx] = v;
            }
        }
    }
}

// ---------------- f32 SIMD GEMM for LoRA ----------------
#define BM 64
#define BN 64
#define BK 16
__global__ __launch_bounds__(256) void gemm_f32(
    const float* __restrict__ A, const float* __restrict__ xx,
    const float* __restrict__ W, float* __restrict__ C,
    int M, int N, int K, int T, int mode, const float* __restrict__ bias)
{
    __shared__ float As[BK][BM + 4];
    __shared__ float Bs[BK][BN + 4];
    const int tid = threadIdx.x;
    const int m0 = blockIdx.x * BM;
    const int n0 = blockIdx.y * BN;
    const int lr = tid >> 2;
    const int lk = (tid & 3) << 2;
    const int tx = tid & 15;
    const int ty = tid >> 4;
    const int mrow = m0 + lr;
    const int nrow = n0 + lr;
    float acc[4][4];
    #pragma unroll
    for (int i = 0; i < 4; ++i)
        #pragma unroll
        for (int j = 0; j < 4; ++j) acc[i][j] = 0.f;

    for (int k0 = 0; k0 < K; k0 += BK) {
        const float* ap = A + (size_t)mrow * K + k0 + lk;
        float4 av = *(const float4*)ap;
        if (xx) {
            const int t = mrow % T;
            float4 pv = make_float4(0.f, 0.f, 0.f, 0.f);
            if (t > 0) pv = *(const float4*)(ap - K);
            const float4 xv = *(const float4*)(xx + k0 + lk);
            av.x += (pv.x - av.x) * xv.x;
            av.y += (pv.y - av.y) * xv.y;
            av.z += (pv.z - av.z) * xv.z;
            av.w += (pv.w - av.w) * xv.w;
        }
        float4 bv = make_float4(0.f, 0.f, 0.f, 0.f);
        if (nrow < N) bv = *(const float4*)(W + (size_t)nrow * K + k0 + lk);

        As[lk + 0][lr] = av.x; As[lk + 1][lr] = av.y;
        As[lk + 2][lr] = av.z; As[lk + 3][lr] = av.w;
        Bs[lk + 0][lr] = bv.x; Bs[lk + 1][lr] = bv.y;
        Bs[lk + 2][lr] = bv.z; Bs[lk + 3][lr] = bv.w;
        __syncthreads();

        #pragma unroll
        for (int kk = 0; kk < BK; ++kk) {
            const float4 a4 = *(const float4*)&As[kk][ty << 2];
            const float4 b4 = *(const float4*)&Bs[kk][tx << 2];
            const float a[4] = {a4.x, a4.y, a4.z, a4.w};
            const float b[4] = {b4.x, b4.y, b4.z, b4.w};
            #pragma unroll
            for (int i = 0; i < 4; ++i)
                #pragma unroll
                for (int j = 0; j < 4; ++j)
                    acc[i][j] = fmaf(a[i], b[j], acc[i][j]);
        }
        __syncthreads();
    }
    #pragma unroll
    for (int i = 0; i < 4; ++i) {
        const int m = m0 + (ty << 2) + i;
        #pragma unroll
        for (int j = 0; j < 4; ++j) {
            const int n = n0 + (tx << 2) + j;
            if (n < N) {
                const size_t idx = (size_t)m * N + n;
                float v = acc[i][j];
                if (mode == 1) v = 0.6065306597126334f * sigm(v + bias[n]);
                C[idx] = v;
            }
        }
    }
}

__global__ void unary_act(float* __restrict__ x, int n, int mode)
{
    int i = blockIdx.x * 256 + threadIdx.x;
    if (i < n) {
        float v = x[i];
        x[i] = (mode == 0) ? tanhf(v) : sigm(v);
    }
}

// per-(b,t,h) wave: a = sigmoid(ya+ab); kk = normalize(k0*k_k); bv = kk*a;
// kfinal = k0*(1+(a-1)*k_a)
__global__ __launch_bounds__(256) void ka_epi(
    float* __restrict__ Kf, float* __restrict__ A_BV, float* __restrict__ KKo,
    const float* __restrict__ k_k, const float* __restrict__ k_a,
    const float* __restrict__ ab, int total, int H)
{
    int wid = (blockIdx.x << 2) | (threadIdx.x >> 6);
    if (wid >= total) return;
    const int l = threadIdx.x & 63;
    const int h = wid % H;
    const int ch = h * 64 + l;
    const size_t base = (size_t)wid * 64;
    float k0 = Kf[base + l];
    float a = sigm(A_BV[base + l] + ab[ch]);
    float kkr = k0 * k_k[ch];
    float ss = kkr * kkr;
    #pragma unroll
    for (int off = 1; off < 64; off <<= 1) ss += __shfl_xor(ss, off, 64);
    float inv = 1.f / fmaxf(sqrtf(ss), 1e-12f);
    float kkn = kkr * inv;
    KKo[base + l] = kkn;
    A_BV[base + l] = kkn * a;
    Kf[base + l] = k0 * fmaf(a - 1.f, k_a[ch], 1.f);
}

// DPLR scan v3. Block = 256 thr (4 waves) = ONE head (b,h). Grid = B*H = 64.
// Wave w: v-cols [w*16, w*16+16). Lane l: vc = l&15 (v-col), g = l>>4 (k-group),
// owns k in [g*16, g*16+16) -> state s[16] in regs.
// Per step: sa reduce = 2 shfl_xor (16,32). o-partials go to LDS (off the
// carried chain); per-chunk parallel pass sums 4 partials -> global.
// Chunk staging: global->reg at chunk start (in flight under compute),
// reg->LDS after barrier. In-chunk depth-1 LDS->reg prefetch (PA/PB).
#define CH 16
__global__ __launch_bounds__(256) void rwkv_scan(
    const float* __restrict__ EW, const float* __restrict__ R,
    const float* __restrict__ Kf, const float* __restrict__ Vf,
    const float* __restrict__ KK, const float* __restrict__ BV,
    float* __restrict__ O, int T, int H)
{
    // LDS: 2 buffers x 6 streams x [CH][64]  +  po[4 waves][CH][16 vc][4 g]
    __shared__ float lds[2 * 6 * CH * 64 + 4 * CH * 64];

    const int bh = blockIdx.x;
    const int b = bh >> 5, h = bh & 31;
    const int tid = threadIdx.x;
    const int w = tid >> 6;
    const int l = tid & 63;
    const int vc = l & 15;
    const int g  = l >> 4;
    const int kb = g << 4;             // k-offset of this lane's 16 k-values
    const size_t step = (size_t)H * 64;
    const size_t base0 = ((size_t)b * T * H + h) * 64;

    // staging: thread tid covers (t = tid>>4, dcol = (tid&15)*4) of each stream
    const int st = tid >> 4;
    const int sd = (tid & 15) << 2;
    float4 g0, g1, g2, g3, g4, g5;

    auto load_chunk = [&](int c) {
        const size_t o = base0 + (size_t)(c * CH + st) * step + sd;
        g0 = *(const float4*)(EW + o);
        g1 = *(const float4*)(R  + o);
        g2 = *(const float4*)(Kf + o);
        g3 = *(const float4*)(KK + o);
        g4 = *(const float4*)(BV + o);
        g5 = *(const float4*)(Vf + o);
    };
    auto write_chunk = [&](int buf) {
        float* L = lds + buf * (6 * CH * 64);
        const int o = st * 64 + sd;
        *(float4*)(L + 0 * CH * 64 + o) = g0;
        *(float4*)(L + 1 * CH * 64 + o) = g1;
        *(float4*)(L + 2 * CH * 64 + o) = g2;
        *(float4*)(L + 3 * CH * 64 + o) = g3;
        *(float4*)(L + 4 * CH * 64 + o) = g4;
        *(float4*)(L + 5 * CH * 64 + o) = g5;
    };

    float s[16];
    #pragma unroll
    for (int i = 0; i < 16; ++i) s[i] = 0.f;

    float* po = lds + 2 * 6 * CH * 64 + w * (CH * 64);
    const int NCH = T / CH;

    struct P { float4 e[4], r[4], k[4], q[4], bb[4]; float vv; };
    P PA, PB;

    load_chunk(0);
    write_chunk(0);
    __syncthreads();

    for (int c = 0; c < NCH; ++c) {
        if (c + 1 < NCH) load_chunk(c + 1);   // global->reg, in flight under compute

        const float* L  = lds + (c & 1) * (6 * CH * 64);
        const float* Le = L;
        const float* Lr = L + 1 * CH * 64;
        const float* Lk = L + 2 * CH * 64;
        const float* Lq = L + 3 * CH * 64;
        const float* Lb = L + 4 * CH * 64;
        const float* Lv = L + 5 * CH * 64;

        auto PRE = [&](P& pp, int tt) {
            const int o = tt * 64 + kb;
            #pragma unroll
            for (int j = 0; j < 4; ++j) {
                pp.e[j]  = *(const float4*)(Le + o + j * 4);
                pp.r[j]  = *(const float4*)(Lr + o + j * 4);
                pp.k[j]  = *(const float4*)(Lk + o + j * 4);
                pp.q[j]  = *(const float4*)(Lq + o + j * 4);
                pp.bb[j] = *(const float4*)(Lb + o + j * 4);
            }
            pp.vv = Lv[tt * 64 + (w << 4) + vc];
        };
        auto COMP = [&](const P& pp, int tt) {
            float a0 = 0.f, a1 = 0.f, a2 = 0.f, a3 = 0.f;
            #pragma unroll
            for (int j = 0; j < 4; ++j) {
                s[4*j+0] *= pp.e[j].x; s[4*j+1] *= pp.e[j].y;
                s[4*j+2] *= pp.e[j].z; s[4*j+3] *= pp.e[j].w;
                a0 = fmaf(pp.q[j].x, s[4*j+0], a0);
                a1 = fmaf(pp.q[j].y, s[4*j+1], a1);
                a2 = fmaf(pp.q[j].z, s[4*j+2], a2);
                a3 = fmaf(pp.q[j].w, s[4*j+3], a3);
            }
            float p = -((a0 + a1) + (a2 + a3));
            p += __shfl_xor(p, 16, 64);
            p += __shfl_xor(p, 32, 64);
            const float vv = pp.vv;
            float o0 = 0.f, o1 = 0.f, o2 = 0.f, o3 = 0.f;
            #pragma unroll
            for (int j = 0; j < 4; ++j) {
                s[4*j+0] = fmaf(pp.bb[j].x, p, fmaf(pp.k[j].x, vv, s[4*j+0]));
                s[4*j+1] = fmaf(pp.bb[j].y, p, fmaf(pp.k[j].y, vv, s[4*j+1]));
                s[4*j+2] = fmaf(pp.bb[j].z, p, fmaf(pp.k[j].z, vv, s[4*j+2]));
                s[4*j+3] = fmaf(pp.bb[j].w, p, fmaf(pp.k[j].w, vv, s[4*j+3]));
                o0 = fmaf(pp.r[j].x, s[4*j+0], o0);
                o1 = fmaf(pp.r[j].y, s[4*j+1], o1);
                o2 = fmaf(pp.r[j].z, s[4*j+2], o2);
                o3 = fmaf(pp.r[j].w, s[4*j+3], o3);
            }
            po[tt * 64 + (vc << 2) + g] = (o0 + o1) + (o2 + o3);  // off-chain partial
        };

        PRE(PA, 0);
        PRE(PB, 1);
        #pragma unroll
        for (int tt = 0; tt < CH - 2; tt += 2) {
            COMP(PA, tt);     PRE(PA, tt + 2);
            COMP(PB, tt + 1); PRE(PB, tt + 3);
        }
        COMP(PA, CH - 2);
        COMP(PB, CH - 1);

        // deferred o-reduction: sum 4 group-partials, fully parallel
        #pragma unroll
        for (int ppi = 0; ppi < 4; ++ppi) {
            const int tt = (ppi << 2) + g;
            const float4 q = *(const float4*)(po + tt * 64 + (vc << 2));
            O[base0 + (size_t)(c * CH + tt) * step + (w << 4) + vc] = (q.x + q.y) + (q.z + q.w);
        }

        __syncthreads();                       // all waves done reading lds[c&1]
        if (c + 1 < NCH) {
            write_chunk((c + 1) & 1);
            __syncthreads();
        }
    }
}

// GroupNorm + bonus + on-the-fly g (HG[m,:128] . gB[ch,:128]); f32 ON out.
__global__ __launch_bounds__(256) void gn_bonus(
    const float* __restrict__ O, const float* __restrict__ R,
    const float* __restrict__ Kf, const float* __restrict__ Vf,
    const float* __restrict__ HG, const float* __restrict__ gB,
    const float* __restrict__ r_k,
    const float* __restrict__ gn_w, const float* __restrict__ gn_b,
    float* __restrict__ ON, int total, int H, float eps)
{
    int wid = (blockIdx.x << 2) | (threadIdx.x >> 6);
    if (wid >= total) return;
    const int l = threadIdx.x & 63;
    const int h = wid % H;
    const int ch = h * 64 + l;
    const int m = wid / H;
    const size_t base = (size_t)wid * 64;

    const float4* hg4 = (const float4*)(HG + (size_t)m * 128);
    const float4* gb4 = (const float4*)(gB + (size_t)ch * 128);
    float g = 0.f;
    #pragma unroll 8
    for (int j = 0; j < 32; ++j) {
        const float4 a = hg4[j], b = gb4[j];
        g += a.x * b.x + a.y * b.y + a.z * b.z + a.w * b.w;
    }

    const float o = O[base + l];
    float sum = o;
    #pragma unroll
    for (int off = 1; off < 64; off <<= 1) sum += __shfl_xor(sum, off, 64);
    const float mu = sum * (1.f / 64.f);
    const float d = o - mu;
    float ss = d * d;
    #pragma unroll
    for (int off = 1; off < 64; off <<= 1) ss += __shfl_xor(ss, off, 64);
    const float inv = 1.f / sqrtf(ss * (1.f / 64.f) + eps);
    float on = d * inv * gn_w[ch] + gn_b[ch];

    const float r = R[base + l], k = Kf[base + l], vv = Vf[base + l];
    float p = r * k * r_k[ch];
    #pragma unroll
    for (int off = 1; off < 64; off <<= 1) p += __shfl_xor(p, off, 64);
    on = fmaf(p, vv, on);
    ON[base + l] = on * g;
}

extern "C" void kernel_launch(void* const* d_in, const int* in_sizes, int n_in,
                              void* d_out, int out_size, void* d_ws, size_t ws_size,
                              hipStream_t stream)
{
    const int B = 2, T = 2048, D = 2048, H = 32;
    const int M = B * T;

    const float* hid = (const float*)d_in[0];
    const float* vst = (const float*)d_in[1];
    const float* x_x = (const float*)d_in[2];
    const float* k_k = (const float*)d_in[3];
    const float* k_a = (const float*)d_in[4];
    const float* r_k = (const float*)d_in[5];
    const float* Wr  = (const float*)d_in[6];
    const float* Wk  = (const float*)d_in[7];
    const float* Wv  = (const float*)d_in[8];
    const float* Wo  = (const float*)d_in[9];
    const float* wA  = (const float*)d_in[10];
    const float* wB  = (const float*)d_in[11];
    const float* wb  = (const float*)d_in[12];
    const float* vA  = (const float*)d_in[13];
    const float* vB  = (const float*)d_in[14];
    const float* vb  = (const float*)d_in[15];
    const float* aA  = (const float*)d_in[16];
    const float* aB  = (const float*)d_in[17];
    const float* ab  = (const float*)d_in[18];
    const float* gA  = (const float*)d_in[19];
    const float* gB  = (const float*)d_in[20];
    const float* gnw = (const float*)d_in[21];
    const float* gnb = (const float*)d_in[22];
    float* out = (float*)d_out;

    const size_t NE = (size_t)M * D;   // 8,388,608
    const size_t DD = (size_t)D * D;   // 4,194,304
    const size_t need = (6 * NE + (size_t)M * 272) * sizeof(float);  // ~196 MiB (proven)
    if (ws_size < need) return;

    float* R_  = (float*)d_ws;
    float* EW  = R_  + NE;
    float* Kf  = EW  + NE;
    float* Vf  = Kf  + NE;
    float* KK  = Vf  + NE;
    float* ABV = KK  + NE;
    float* HW  = ABV + NE;
    float* HV  = HW + (size_t)M * 64;
    float* HA  = HV + (size_t)M * 16;
    float* HG  = HA + (size_t)M * 64;

    dim3 blk(256);
    dim3 gDual(M / GBM, D / GBN);
    const int nMix = (int)(NE / 8);
    const int nW   = (int)(DD / 8);
    const float* nf = nullptr;

    unsigned short* XHi = (unsigned short*)EW;
    unsigned short* XLo = XHi + NE;
    unsigned short* WHi = (unsigned short*)KK;
    unsigned short* WLo = WHi + DD;

    // ---- phase 1: LoRA stage-1 + activations ----
    hipLaunchKernelGGL(gemm_f32, dim3(M / BM, 1), blk, 0, stream, hid, x_x + 1 * (size_t)D, wA, HW, M, 64,  D, T, 0, nf);
    hipLaunchKernelGGL(gemm_f32, dim3(M / BM, 1), blk, 0, stream, hid, x_x + 3 * (size_t)D, vA, HV, M, 16,  D, T, 0, nf);
    hipLaunchKernelGGL(gemm_f32, dim3(M / BM, 1), blk, 0, stream, hid, x_x + 4 * (size_t)D, aA, HA, M, 64,  D, T, 0, nf);
    hipLaunchKernelGGL(gemm_f32, dim3(M / BM, 2), blk, 0, stream, hid, x_x + 5 * (size_t)D, gA, HG, M, 128, D, T, 0, nf);
    hipLaunchKernelGGL(unary_act, dim3((M * 64  + 255) / 256), blk, 0, stream, HW, M * 64, 0);
    hipLaunchKernelGGL(unary_act, dim3((M * 128 + 255) / 256), blk, 0, stream, HG, M * 128, 1);

    // ---- phase 2: yv -> ABV ----
    hipLaunchKernelGGL(gemm_f32, dim3(M / BM, D / BN), blk, 0, stream, HV, nf, vB, ABV, M, D, 16, T, 0, nf);

    // ---- phase 3: R/K/V projections via split MFMA ----
    hipLaunchKernelGGL(mixsplit, dim3(nMix / 256), blk, 0, stream, hid, x_x + 0 * (size_t)D, XHi, XLo, T, D, nMix, 1);
    hipLaunchKernelGGL(mixsplit, dim3(nW / 256), blk, 0, stream, Wr, nf, WHi, WLo, T, D, nW, 0);
    hipLaunchKernelGGL(gemm_dual, gDual, blk, 0, stream, XHi, XLo, WHi, WLo, R_, M, D, D, 0, nf, nf, nf);

    hipLaunchKernelGGL(mixsplit, dim3(nMix / 256), blk, 0, stream, hid, x_x + 2 * (size_t)D, XHi, XLo, T, D, nMix, 1);
    hipLaunchKernelGGL(mixsplit, dim3(nW / 256), blk, 0, stream, Wk, nf, WHi, WLo, T, D, nW, 0);
    hipLaunchKernelGGL(gemm_dual, gDual, blk, 0, stream, XHi, XLo, WHi, WLo, Kf, M, D, D, 0, nf, nf, nf);

    hipLaunchKernelGGL(mixsplit, dim3(nMix / 256), blk, 0, stream, hid, x_x + 3 * (size_t)D, XHi, XLo, T, D, nMix, 1);
    hipLaunchKernelGGL(mixsplit, dim3(nW / 256), blk, 0, stream, Wv, nf, WHi, WLo, T, D, nW, 0);
    hipLaunchKernelGGL(gemm_dual, gDual, blk, 0, stream, XHi, XLo, WHi, WLo, Vf, M, D, D, 2, ABV, vb, vst);

    // ---- phase 4: LoRA stage-2 ----
    hipLaunchKernelGGL(gemm_f32, dim3(M / BM, D / BN), blk, 0, stream, HW, nf, wB, EW,  M, D, 64, T, 1, wb);
    hipLaunchKernelGGL(gemm_f32, dim3(M / BM, D / BN), blk, 0, stream, HA, nf, aB, ABV, M, D, 64, T, 0, nf);

    // ---- phase 5: ka epilogue ----
    const int totalW = M * H;
    hipLaunchKernelGGL(ka_epi, dim3(totalW / 4), blk, 0, stream, Kf, ABV, KK, k_k, k_a, ab, totalW, H);

    // ---- phase 6: scan -> d_out (64 blocks, one head each) ----
    hipLaunchKernelGGL(rwkv_scan, dim3(B * H), blk, 0, stream, EW, R_, Kf, Vf, KK, ABV, out, T, H);

    // ---- phase 7: GroupNorm + bonus + g -> EW ----
    hipLaunchKernelGGL(gn_bonus, dim3(totalW / 4), blk, 0, stream, out, R_, Kf, Vf, HG, gB, r_k, gnw, gnb, EW, totalW, H, 64.f * 1e-5f);

    // ---- phase 8: Wo projection -> d_out ----
    unsigned short* XHi2 = (unsigned short*)KK;
    unsigned short* XLo2 = XHi2 + NE;
    unsigned short* WHi2 = (unsigned short*)ABV;
    unsigned short* WLo2 = WHi2 + DD;
    hipLaunchKernelGGL(mixsplit, dim3(nMix / 256), blk, 0, stream, EW, nf, XHi2, XLo2, T, D, nMix, 0);
    hipLaunchKernelGGL(mixsplit, dim3(nW / 256), blk, 0, stream, Wo, nf, WHi2, WLo2, T, D, nW, 0);
    hipLaunchKernelGGL(gemm_dual, gDual, blk, 0, stream, XHi2, XLo2, WHi2, WLo2, out, M, D, D, 0, nf, nf, nf);
}

// Round 8
// 2435.156 us; speedup vs baseline: 2.2805x; 1.1346x over previous
//
#include <hip/hip_runtime.h>
#include <hip/hip_bf16.h>
#include <math.h>

// RWKV7 attention, round 8:
//  - rwkv_scan: 1 wave/block, grid 256 (all CUs), chunks staged global->LDS via
//    global_load_lds (no barriers), f32x2 packed math, 2-shfl sa reduce.
//  - gemm_dual: m97-style staging (BK=32 linear LDS, global_load_lds width 16,
//    wave-per-buffer). MFMA math unchanged.
// Other kernels identical to round 7.

typedef __attribute__((ext_vector_type(8))) unsigned short ushort8;
typedef __attribute__((ext_vector_type(8))) short bf16x8;
typedef __attribute__((ext_vector_type(4))) float f32x4;
typedef __attribute__((ext_vector_type(2))) float f32x2;

__device__ inline float b2f(unsigned short u) {
    union { unsigned int u; float f; } x; x.u = ((unsigned int)u) << 16; return x.f;
}
__device__ inline unsigned short f2b(float f) {
    union { float f; unsigned int u; } x; x.f = f;
    return (unsigned short)((x.u + 0x7FFF + ((x.u >> 16) & 1)) >> 16);
}
__device__ inline float sigm(float x) { return 1.f / (1.f + expf(-x)); }

// async global -> LDS, 16 bytes per lane. LDS dest = uniform base + lane*16.
__device__ __forceinline__ void gld16(void* lds, const void* g)
{
    __builtin_amdgcn_global_load_lds(
        (const __attribute__((address_space(1))) void*)g,
        (__attribute__((address_space(3))) void*)lds, 16, 0, 0);
}

// ---------------- split pass: out_hi/lo = bf16 split of (optionally mixed) f32 ----------------
__global__ void mixsplit(const float* __restrict__ in, const float* __restrict__ xxr,
                         unsigned short* __restrict__ hi, unsigned short* __restrict__ lo,
                         int T, int D, int total8, int domix)
{
    int i = blockIdx.x * 256 + threadIdx.x;
    if (i >= total8) return;
    const size_t e = (size_t)i * 8;
    float a[8];
    *(float4*)&a[0] = *(const float4*)(in + e);
    *(float4*)&a[4] = *(const float4*)(in + e + 4);
    if (domix) {
        const int m = (int)(e / D);
        const int d = (int)(e % D);
        const int t = m % T;
        float p[8] = {0.f,0.f,0.f,0.f,0.f,0.f,0.f,0.f};
        if (t > 0) {
            *(float4*)&p[0] = *(const float4*)(in + e - D);
            *(float4*)&p[4] = *(const float4*)(in + e - D + 4);
        }
        float xv[8];
        *(float4*)&xv[0] = *(const float4*)(xxr + d);
        *(float4*)&xv[4] = *(const float4*)(xxr + d + 4);
        #pragma unroll
        for (int j = 0; j < 8; ++j) a[j] += (p[j] - a[j]) * xv[j];
    }
    ushort8 h8, l8;
    #pragma unroll
    for (int j = 0; j < 8; ++j) {
        const unsigned short h = f2b(a[j]);
        h8[j] = h;
        l8[j] = f2b(a[j] - b2f(h));
    }
    *(ushort8*)(hi + e) = h8;
    *(ushort8*)(lo + e) = l8;
}

// ---------------- dual (hi+lo) bf16 MFMA GEMM: C[M,N] = A[M,K] @ W[N,K]^T, f32 out --------
// m97-style staging: linear LDS [128][32] shorts, global_load_lds width 16,
// wave w stages buffer w (Ah/Al/Bh/Bl). mode 0: C=acc ; mode 2: fused V-lerp.
#define GBM 128
#define GBN 128

__global__ __launch_bounds__(256) void gemm_dual(
    const unsigned short* __restrict__ Ahg, const unsigned short* __restrict__ Alg,
    const unsigned short* __restrict__ Bhg, const unsigned short* __restrict__ Blg,
    float* __restrict__ C, int M, int N, int K, int mode,
    const float* __restrict__ yv, const float* __restrict__ bias,
    const float* __restrict__ aux)
{
    __shared__ unsigned short Ah[GBM * 32], Al[GBM * 32];
    __shared__ unsigned short Bh[GBN * 32], Bl[GBN * 32];
    const int tid = threadIdx.x;
    const int m0 = blockIdx.x * GBM;
    const int n0 = blockIdx.y * GBN;
    const int wave = tid >> 6, lane = tid & 63;
    const int wr = (wave >> 1) * 64, wc = (wave & 1) * 64;
    const int fr = lane & 15, fq = lane >> 4;

    f32x4 acc[4][4];
    #pragma unroll
    for (int i = 0; i < 4; ++i)
        #pragma unroll
        for (int j = 0; j < 4; ++j)
            acc[i][j] = (f32x4){0.f, 0.f, 0.f, 0.f};

    // staging role: wave w owns one buffer; lane covers (row = j*16 + lane/4, 16B chunk = lane%4)
    const unsigned short* gsrc = (wave == 0) ? Ahg : (wave == 1) ? Alg : (wave == 2) ? Bhg : Blg;
    unsigned short* lbuf = (wave == 0) ? Ah : (wave == 1) ? Al : (wave == 2) ? Bh : Bl;
    const int tile0 = (wave < 2) ? m0 : n0;
    const unsigned short* gbase = gsrc + (size_t)(tile0 + (lane >> 2)) * K + ((lane & 3) << 3);

    for (int k0 = 0; k0 < K; k0 += 32) {
        #pragma unroll
        for (int j = 0; j < 8; ++j)
            gld16(lbuf + j * 16 * 32, gbase + (size_t)(j * 16) * K + k0);
        __syncthreads();   // compiler drains vmcnt before barrier -> staged data visible

        bf16x8 fah[4], fal[4], fbh[4], fbl[4];
        #pragma unroll
        for (int m = 0; m < 4; ++m) {
            fah[m] = *(const bf16x8*)&Ah[(wr + m * 16 + fr) * 32 + fq * 8];
            fal[m] = *(const bf16x8*)&Al[(wr + m * 16 + fr) * 32 + fq * 8];
        }
        #pragma unroll
        for (int n = 0; n < 4; ++n) {
            fbh[n] = *(const bf16x8*)&Bh[(wc + n * 16 + fr) * 32 + fq * 8];
            fbl[n] = *(const bf16x8*)&Bl[(wc + n * 16 + fr) * 32 + fq * 8];
        }
        #pragma unroll
        for (int m = 0; m < 4; ++m)
            #pragma unroll
            for (int n = 0; n < 4; ++n) {
                acc[m][n] = __builtin_amdgcn_mfma_f32_16x16x32_bf16(fah[m], fbh[n], acc[m][n], 0, 0, 0);
                acc[m][n] = __builtin_amdgcn_mfma_f32_16x16x32_bf16(fah[m], fbl[n], acc[m][n], 0, 0, 0);
                acc[m][n] = __builtin_amdgcn_mfma_f32_16x16x32_bf16(fal[m], fbh[n], acc[m][n], 0, 0, 0);
            }
        __syncthreads();
    }

    #pragma unroll
    for (int m = 0; m < 4; ++m) {
        const int row = m0 + wr + m * 16 + fq * 4;
        #pragma unroll
        for (int n = 0; n < 4; ++n) {
            const int col = n0 + wc + n * 16 + fr;
            #pragma unroll
            for (int j = 0; j < 4; ++j) {
                const size_t idx = (size_t)(row + j) * N + col;
                float v = acc[m][n][j];
                if (mode == 2) {
                    const float sg = sigm(yv[idx] + bias[col]);
                    v = v + sg * (aux[idx] - v);
                }
                C[idx] = v;
            }
        }
    }
}

// ---------------- f32 SIMD GEMM for LoRA ----------------
#define BM 64
#define BN 64
#define BK 16
__global__ __launch_bounds__(256) void gemm_f32(
    const float* __restrict__ A, const float* __restrict__ xx,
    const float* __restrict__ W, float* __restrict__ C,
    int M, int N, int K, int T, int mode, const float* __restrict__ bias)
{
    __shared__ float As[BK][BM + 4];
    __shared__ float Bs[BK][BN + 4];
    const int tid = threadIdx.x;
    const int m0 = blockIdx.x * BM;
    const int n0 = blockIdx.y * BN;
    const int lr = tid >> 2;
    const int lk = (tid & 3) << 2;
    const int tx = tid & 15;
    const int ty = tid >> 4;
    const int mrow = m0 + lr;
    const int nrow = n0 + lr;
    float acc[4][4];
    #pragma unroll
    for (int i = 0; i < 4; ++i)
        #pragma unroll
        for (int j = 0; j < 4; ++j) acc[i][j] = 0.f;

    for (int k0 = 0; k0 < K; k0 += BK) {
        const float* ap = A + (size_t)mrow * K + k0 + lk;
        float4 av = *(const float4*)ap;
        if (xx) {
            const int t = mrow % T;
            float4 pv = make_float4(0.f, 0.f, 0.f, 0.f);
            if (t > 0) pv = *(const float4*)(ap - K);
            const float4 xv = *(const float4*)(xx + k0 + lk);
            av.x += (pv.x - av.x) * xv.x;
            av.y += (pv.y - av.y) * xv.y;
            av.z += (pv.z - av.z) * xv.z;
            av.w += (pv.w - av.w) * xv.w;
        }
        float4 bv = make_float4(0.f, 0.f, 0.f, 0.f);
        if (nrow < N) bv = *(const float4*)(W + (size_t)nrow * K + k0 + lk);

        As[lk + 0][lr] = av.x; As[lk + 1][lr] = av.y;
        As[lk + 2][lr] = av.z; As[lk + 3][lr] = av.w;
        Bs[lk + 0][lr] = bv.x; Bs[lk + 1][lr] = bv.y;
        Bs[lk + 2][lr] = bv.z; Bs[lk + 3][lr] = bv.w;
        __syncthreads();

        #pragma unroll
        for (int kk = 0; kk < BK; ++kk) {
            const float4 a4 = *(const float4*)&As[kk][ty << 2];
            const float4 b4 = *(const float4*)&Bs[kk][tx << 2];
            const float a[4] = {a4.x, a4.y, a4.z, a4.w};
            const float b[4] = {b4.x, b4.y, b4.z, b4.w};
            #pragma unroll
            for (int i = 0; i < 4; ++i)
                #pragma unroll
                for (int j = 0; j < 4; ++j)
                    acc[i][j] = fmaf(a[i], b[j], acc[i][j]);
        }
        __syncthreads();
    }
    #pragma unroll
    for (int i = 0; i < 4; ++i) {
        const int m = m0 + (ty << 2) + i;
        #pragma unroll
        for (int j = 0; j < 4; ++j) {
            const int n = n0 + (tx << 2) + j;
            if (n < N) {
                const size_t idx = (size_t)m * N + n;
                float v = acc[i][j];
                if (mode == 1) v = 0.6065306597126334f * sigm(v + bias[n]);
                C[idx] = v;
            }
        }
    }
}

__global__ void unary_act(float* __restrict__ x, int n, int mode)
{
    int i = blockIdx.x * 256 + threadIdx.x;
    if (i < n) {
        float v = x[i];
        x[i] = (mode == 0) ? tanhf(v) : sigm(v);
    }
}

// per-(b,t,h) wave: a = sigmoid(ya+ab); kk = normalize(k0*k_k); bv = kk*a;
// kfinal = k0*(1+(a-1)*k_a)
__global__ __launch_bounds__(256) void ka_epi(
    float* __restrict__ Kf, float* __restrict__ A_BV, float* __restrict__ KKo,
    const float* __restrict__ k_k, const float* __restrict__ k_a,
    const float* __restrict__ ab, int total, int H)
{
    int wid = (blockIdx.x << 2) | (threadIdx.x >> 6);
    if (wid >= total) return;
    const int l = threadIdx.x & 63;
    const int h = wid % H;
    const int ch = h * 64 + l;
    const size_t base = (size_t)wid * 64;
    float k0 = Kf[base + l];
    float a = sigm(A_BV[base + l] + ab[ch]);
    float kkr = k0 * k_k[ch];
    float ss = kkr * kkr;
    #pragma unroll
    for (int off = 1; off < 64; off <<= 1) ss += __shfl_xor(ss, off, 64);
    float inv = 1.f / fmaxf(sqrtf(ss), 1e-12f);
    float kkn = kkr * inv;
    KKo[base + l] = kkn;
    A_BV[base + l] = kkn * a;
    Kf[base + l] = k0 * fmaf(a - 1.f, k_a[ch], 1.f);
}

// DPLR scan v4. ONE wave per block; grid = B*H*4 = 256 (1 block/CU).
// Block (b,h,slab): 16 v-cols [slab*16, +16). Lane l: vc = l&15, g = l>>4,
// owns k in [g*16, +16) -> state s2[8] (f32x2) in regs.
// Chunks of SCH=16 steps staged global->LDS via global_load_lds (21 instrs/chunk,
// no ds_writes, no barriers); explicit vmcnt(0) before buffer swap.
// Per step: 20 ds_read_b128 + 1 b32 + 2 shfl (sa, on chain) + 2 shfl (o, off chain).
#define SCH 16
__global__ __launch_bounds__(64) void rwkv_scan(
    const float* __restrict__ EW, const float* __restrict__ R,
    const float* __restrict__ Kf, const float* __restrict__ Vf,
    const float* __restrict__ KK, const float* __restrict__ BV,
    float* __restrict__ O, int T, int H)
{
    __shared__ float lds[2][5 * SCH * 64 + SCH * 16];

    const int blk = blockIdx.x;
    const int bh = blk & 63;               // 4 slabs of one head are 64 apart -> same XCD
    const int slab = blk >> 6;
    const int b = bh >> 5, h = bh & 31;
    const int l = threadIdx.x;
    const int vc = l & 15;
    const int g  = l >> 4;
    const int kb = g << 4;
    const int vb0 = slab << 4;
    const size_t step = (size_t)H * 64;
    const size_t base0 = ((size_t)b * T * H + h) * 64;

    // staging: 5 big streams (4 gld16 each: lane -> row t0+j*4+(l>>4), 16B chunk l&15)
    //          + V slab (1 gld16: lane -> row t0+(l>>2), 16B chunk l&3 of 16-float row)
    auto stage = [&](int c, int buf) {
        float* L = &lds[buf][0];
        const size_t t0 = (size_t)c * SCH;
        const float* gs[5] = {EW, R, Kf, KK, BV};
        #pragma unroll
        for (int s = 0; s < 5; ++s) {
            const float* gp = gs[s];
            #pragma unroll
            for (int j = 0; j < 4; ++j)
                gld16(L + s * SCH * 64 + j * 4 * 64,
                      gp + base0 + (t0 + j * 4 + (l >> 4)) * step + ((l & 15) << 2));
        }
        gld16(L + 5 * SCH * 64,
              Vf + base0 + (t0 + (l >> 2)) * step + vb0 + ((l & 3) << 2));
    };

    f32x2 s2[8];
    #pragma unroll
    for (int i = 0; i < 8; ++i) s2[i] = (f32x2){0.f, 0.f};

    struct P { f32x4 e[4], r[4], k[4], q[4], bb[4]; float vv; };
    P PA, PB;
    const int NCH = T / SCH;

    stage(0, 0);
    asm volatile("s_waitcnt vmcnt(0)" ::: "memory");
    __builtin_amdgcn_sched_barrier(0);

    for (int c = 0; c < NCH; ++c) {
        if (c + 1 < NCH) stage(c + 1, (c + 1) & 1);   // loads fly under compute

        const float* L = &lds[c & 1][0];
        auto PRE = [&](P& pp, int tt) {
            const int o = tt * 64 + kb;
            #pragma unroll
            for (int j = 0; j < 4; ++j) {
                pp.e[j]  = *(const f32x4*)(L + 0 * SCH * 64 + o + j * 4);
                pp.r[j]  = *(const f32x4*)(L + 1 * SCH * 64 + o + j * 4);
                pp.k[j]  = *(const f32x4*)(L + 2 * SCH * 64 + o + j * 4);
                pp.q[j]  = *(const f32x4*)(L + 3 * SCH * 64 + o + j * 4);
                pp.bb[j] = *(const f32x4*)(L + 4 * SCH * 64 + o + j * 4);
            }
            pp.vv = L[5 * SCH * 64 + tt * 16 + vc];
        };
        auto COMP = [&](const P& pp, int tt) {
            f32x2 sa0 = (f32x2){0.f, 0.f}, sa1 = (f32x2){0.f, 0.f};
            #pragma unroll
            for (int j = 0; j < 4; ++j) {
                const f32x2 elo = __builtin_shufflevector(pp.e[j], pp.e[j], 0, 1);
                const f32x2 ehi = __builtin_shufflevector(pp.e[j], pp.e[j], 2, 3);
                const f32x2 qlo = __builtin_shufflevector(pp.q[j], pp.q[j], 0, 1);
                const f32x2 qhi = __builtin_shufflevector(pp.q[j], pp.q[j], 2, 3);
                s2[2*j]   *= elo;
                s2[2*j+1] *= ehi;
                sa0 += qlo * s2[2*j];
                sa1 += qhi * s2[2*j+1];
            }
            const f32x2 sas = sa0 + sa1;
            float p = -(sas.x + sas.y);
            p += __shfl_xor(p, 16, 64);
            p += __shfl_xor(p, 32, 64);
            const f32x2 p2 = (f32x2){p, p};
            const f32x2 v2 = (f32x2){pp.vv, pp.vv};
            f32x2 o0 = (f32x2){0.f, 0.f}, o1 = (f32x2){0.f, 0.f};
            #pragma unroll
            for (int j = 0; j < 4; ++j) {
                const f32x2 klo = __builtin_shufflevector(pp.k[j], pp.k[j], 0, 1);
                const f32x2 khi = __builtin_shufflevector(pp.k[j], pp.k[j], 2, 3);
                const f32x2 blo = __builtin_shufflevector(pp.bb[j], pp.bb[j], 0, 1);
                const f32x2 bhi = __builtin_shufflevector(pp.bb[j], pp.bb[j], 2, 3);
                const f32x2 rlo = __builtin_shufflevector(pp.r[j], pp.r[j], 0, 1);
                const f32x2 rhi = __builtin_shufflevector(pp.r[j], pp.r[j], 2, 3);
                s2[2*j]   = blo * p2 + (klo * v2 + s2[2*j]);
                s2[2*j+1] = bhi * p2 + (khi * v2 + s2[2*j+1]);
                o0 += rlo * s2[2*j];
                o1 += rhi * s2[2*j+1];
            }
            const f32x2 os = o0 + o1;
            float oo = os.x + os.y;
            oo += __shfl_xor(oo, 16, 64);
            oo += __shfl_xor(oo, 32, 64);
            if (g == 0)
                O[base0 + (size_t)(c * SCH + tt) * step + vb0 + vc] = oo;
        };

        PRE(PA, 0);
        PRE(PB, 1);
        #pragma unroll
        for (int tt = 0; tt < SCH - 2; tt += 2) {
            COMP(PA, tt);     PRE(PA, tt + 2);
            COMP(PB, tt + 1); PRE(PB, tt + 3);
        }
        COMP(PA, SCH - 2);
        COMP(PB, SCH - 1);

        // staged loads for chunk c+1 must have landed before reading that buffer
        asm volatile("s_waitcnt vmcnt(0)" ::: "memory");
        __builtin_amdgcn_sched_barrier(0);
    }
}

// GroupNorm + bonus + on-the-fly g (HG[m,:128] . gB[ch,:128]); f32 ON out.
__global__ __launch_bounds__(256) void gn_bonus(
    const float* __restrict__ O, const float* __restrict__ R,
    const float* __restrict__ Kf, const float* __restrict__ Vf,
    const float* __restrict__ HG, const float* __restrict__ gB,
    const float* __restrict__ r_k,
    const float* __restrict__ gn_w, const float* __restrict__ gn_b,
    float* __restrict__ ON, int total, int H, float eps)
{
    int wid = (blockIdx.x << 2) | (threadIdx.x >> 6);
    if (wid >= total) return;
    const int l = threadIdx.x & 63;
    const int h = wid % H;
    const int ch = h * 64 + l;
    const int m = wid / H;
    const size_t base = (size_t)wid * 64;

    const float4* hg4 = (const float4*)(HG + (size_t)m * 128);
    const float4* gb4 = (const float4*)(gB + (size_t)ch * 128);
    float g = 0.f;
    #pragma unroll 8
    for (int j = 0; j < 32; ++j) {
        const float4 a = hg4[j], b = gb4[j];
        g += a.x * b.x + a.y * b.y + a.z * b.z + a.w * b.w;
    }

    const float o = O[base + l];
    float sum = o;
    #pragma unroll
    for (int off = 1; off < 64; off <<= 1) sum += __shfl_xor(sum, off, 64);
    const float mu = sum * (1.f / 64.f);
    const float d = o - mu;
    float ss = d * d;
    #pragma unroll
    for (int off = 1; off < 64; off <<= 1) ss += __shfl_xor(ss, off, 64);
    const float inv = 1.f / sqrtf(ss * (1.f / 64.f) + eps);
    float on = d * inv * gn_w[ch] + gn_b[ch];

    const float r = R[base + l], k = Kf[base + l], vv = Vf[base + l];
    float p = r * k * r_k[ch];
    #pragma unroll
    for (int off = 1; off < 64; off <<= 1) p += __shfl_xor(p, off, 64);
    on = fmaf(p, vv, on);
    ON[base + l] = on * g;
}

extern "C" void kernel_launch(void* const* d_in, const int* in_sizes, int n_in,
                              void* d_out, int out_size, void* d_ws, size_t ws_size,
                              hipStream_t stream)
{
    const int B = 2, T = 2048, D = 2048, H = 32;
    const int M = B * T;

    const float* hid = (const float*)d_in[0];
    const float* vst = (const float*)d_in[1];
    const float* x_x = (const float*)d_in[2];
    const float* k_k = (const float*)d_in[3];
    const float* k_a = (const float*)d_in[4];
    const float* r_k = (const float*)d_in[5];
    const float* Wr  = (const float*)d_in[6];
    const float* Wk  = (const float*)d_in[7];
    const float* Wv  = (const float*)d_in[8];
    const float* Wo  = (const float*)d_in[9];
    const float* wA  = (const float*)d_in[10];
    const float* wB  = (const float*)d_in[11];
    const float* wb  = (const float*)d_in[12];
    const float* vA  = (const float*)d_in[13];
    const float* vB  = (const float*)d_in[14];
    const float* vb  = (const float*)d_in[15];
    const float* aA  = (const float*)d_in[16];
    const float* aB  = (const float*)d_in[17];
    const float* ab  = (const float*)d_in[18];
    const float* gA  = (const float*)d_in[19];
    const float* gB  = (const float*)d_in[20];
    const float* gnw = (const float*)d_in[21];
    const float* gnb = (const float*)d_in[22];
    float* out = (float*)d_out;

    const size_t NE = (size_t)M * D;   // 8,388,608
    const size_t DD = (size_t)D * D;   // 4,194,304
    const size_t need = (6 * NE + (size_t)M * 272) * sizeof(float);  // ~196 MiB (proven)
    if (ws_size < need) return;

    float* R_  = (float*)d_ws;
    float* EW  = R_  + NE;
    float* Kf  = EW  + NE;
    float* Vf  = Kf  + NE;
    float* KK  = Vf  + NE;
    float* ABV = KK  + NE;
    float* HW  = ABV + NE;
    float* HV  = HW + (size_t)M * 64;
    float* HA  = HV + (size_t)M * 16;
    float* HG  = HA + (size_t)M * 64;

    dim3 blk(256);
    dim3 gDual(M / GBM, D / GBN);
    const int nMix = (int)(NE / 8);
    const int nW   = (int)(DD / 8);
    const float* nf = nullptr;

    unsigned short* XHi = (unsigned short*)EW;
    unsigned short* XLo = XHi + NE;
    unsigned short* WHi = (unsigned short*)KK;
    unsigned short* WLo = WHi + DD;

    // ---- phase 1: LoRA stage-1 + activations ----
    hipLaunchKernelGGL(gemm_f32, dim3(M / BM, 1), blk, 0, stream, hid, x_x + 1 * (size_t)D, wA, HW, M, 64,  D, T, 0, nf);
    hipLaunchKernelGGL(gemm_f32, dim3(M / BM, 1), blk, 0, stream, hid, x_x + 3 * (size_t)D, vA, HV, M, 16,  D, T, 0, nf);
    hipLaunchKernelGGL(gemm_f32, dim3(M / BM, 1), blk, 0, stream, hid, x_x + 4 * (size_t)D, aA, HA, M, 64,  D, T, 0, nf);
    hipLaunchKernelGGL(gemm_f32, dim3(M / BM, 2), blk, 0, stream, hid, x_x + 5 * (size_t)D, gA, HG, M, 128, D, T, 0, nf);
    hipLaunchKernelGGL(unary_act, dim3((M * 64  + 255) / 256), blk, 0, stream, HW, M * 64, 0);
    hipLaunchKernelGGL(unary_act, dim3((M * 128 + 255) / 256), blk, 0, stream, HG, M * 128, 1);

    // ---- phase 2: yv -> ABV ----
    hipLaunchKernelGGL(gemm_f32, dim3(M / BM, D / BN), blk, 0, stream, HV, nf, vB, ABV, M, D, 16, T, 0, nf);

    // ---- phase 3: R/K/V projections via split MFMA ----
    hipLaunchKernelGGL(mixsplit, dim3(nMix / 256), blk, 0, stream, hid, x_x + 0 * (size_t)D, XHi, XLo, T, D, nMix, 1);
    hipLaunchKernelGGL(mixsplit, dim3(nW / 256), blk, 0, stream, Wr, nf, WHi, WLo, T, D, nW, 0);
    hipLaunchKernelGGL(gemm_dual, gDual, blk, 0, stream, XHi, XLo, WHi, WLo, R_, M, D, D, 0, nf, nf, nf);

    hipLaunchKernelGGL(mixsplit, dim3(nMix / 256), blk, 0, stream, hid, x_x + 2 * (size_t)D, XHi, XLo, T, D, nMix, 1);
    hipLaunchKernelGGL(mixsplit, dim3(nW / 256), blk, 0, stream, Wk, nf, WHi, WLo, T, D, nW, 0);
    hipLaunchKernelGGL(gemm_dual, gDual, blk, 0, stream, XHi, XLo, WHi, WLo, Kf, M, D, D, 0, nf, nf, nf);

    hipLaunchKernelGGL(mixsplit, dim3(nMix / 256), blk, 0, stream, hid, x_x + 3 * (size_t)D, XHi, XLo, T, D, nMix, 1);
    hipLaunchKernelGGL(mixsplit, dim3(nW / 256), blk, 0, stream, Wv, nf, WHi, WLo, T, D, nW, 0);
    hipLaunchKernelGGL(gemm_dual, gDual, blk, 0, stream, XHi, XLo, WHi, WLo, Vf, M, D, D, 2, ABV, vb, vst);

    // ---- phase 4: LoRA stage-2 ----
    hipLaunchKernelGGL(gemm_f32, dim3(M / BM, D / BN), blk, 0, stream, HW, nf, wB, EW,  M, D, 64, T, 1, wb);
    hipLaunchKernelGGL(gemm_f32, dim3(M / BM, D / BN), blk, 0, stream, HA, nf, aB, ABV, M, D, 64, T, 0, nf);

    // ---- phase 5: ka epilogue ----
    const int totalW = M * H;
    hipLaunchKernelGGL(ka_epi, dim3(totalW / 4), blk, 0, stream, Kf, ABV, KK, k_k, k_a, ab, totalW, H);

    // ---- phase 6: scan -> d_out (256 single-wave blocks) ----
    hipLaunchKernelGGL(rwkv_scan, dim3(B * H * 4), dim3(64), 0, stream, EW, R_, Kf, Vf, KK, ABV, out, T, H);

    // ---- phase 7: GroupNorm + bonus + g -> EW ----
    hipLaunchKernelGGL(gn_bonus, dim3(totalW / 4), blk, 0, stream, out, R_, Kf, Vf, HG, gB, r_k, gnw, gnb, EW, totalW, H, 64.f * 1e-5f);

    // ---- phase 8: Wo projection -> d_out ----
    unsigned short* XHi2 = (unsigned short*)KK;
    unsigned short* XLo2 = XHi2 + NE;
    unsigned short* WHi2 = (unsigned short*)ABV;
    unsigned short* WLo2 = WHi2 + DD;
    hipLaunchKernelGGL(mixsplit, dim3(nMix / 256), blk, 0, stream, EW, nf, XHi2, XLo2, T, D, nMix, 0);
    hipLaunchKernelGGL(mixsplit, dim3(nW / 256), blk, 0, stream, Wo, nf, WHi2, WLo2, T, D, nW, 0);
    hipLaunchKernelGGL(gemm_dual, gDual, blk, 0, stream, XHi2, XLo2, WHi2, WLo2, out, M, D, D, 0, nf, nf, nf);
}

// Round 10
// 1826.518 us; speedup vs baseline: 3.0404x; 1.3332x over previous
//
#include <hip/hip_runtime.h>
#include <hip/hip_bf16.h>
#include <math.h>

// RWKV7 attention, round 10:
//  - rwkv_scan: cross-lane reductions via v_permlane16/32_swap_b32 (VALU).
//    FIX vs r9: opaque copy forces a/b into DISTINCT registers (r9 aliased both
//    asm operands to one vreg -> swap(v0,v0) -> 2*x_partner instead of x+x_partner).
//  - lora1: four LoRA stage-1 GEMMs fused (grid 64x5), acts in epilogue.
// Other kernels identical to round 8.

typedef __attribute__((ext_vector_type(8))) unsigned short ushort8;
typedef __attribute__((ext_vector_type(8))) short bf16x8;
typedef __attribute__((ext_vector_type(4))) float f32x4;
typedef __attribute__((ext_vector_type(2))) float f32x2;

__device__ inline float b2f(unsigned short u) {
    union { unsigned int u; float f; } x; x.u = ((unsigned int)u) << 16; return x.f;
}
__device__ inline unsigned short f2b(float f) {
    union { float f; unsigned int u; } x; x.f = f;
    return (unsigned short)((x.u + 0x7FFF + ((x.u >> 16) & 1)) >> 16);
}
__device__ inline float sigm(float x) { return 1.f / (1.f + expf(-x)); }

// VALU cross-lane reductions (gfx950 permlane swaps). After swap(a, b) with
// a=x and b=opaque_copy(x), every lane holds {x_l, x_{l^16 or ^32}} across a,b.
// The empty asm makes b a distinct live value -> guaranteed distinct register.
__device__ __forceinline__ float red16(float x) {
    float b = x;
    asm("" : "+v"(b));          // opaque copy: distinct vreg from a
    float a = x;
    asm("v_permlane16_swap_b32 %0, %1" : "+v"(a), "+v"(b));
    return a + b;
}
__device__ __forceinline__ float red32(float x) {
    float b = x;
    asm("" : "+v"(b));
    float a = x;
    asm("v_permlane32_swap_b32 %0, %1" : "+v"(a), "+v"(b));
    return a + b;
}

// async global -> LDS, 16 bytes per lane. LDS dest = uniform base + lane*16.
__device__ __forceinline__ void gld16(void* lds, const void* g)
{
    __builtin_amdgcn_global_load_lds(
        (const __attribute__((address_space(1))) void*)g,
        (__attribute__((address_space(3))) void*)lds, 16, 0, 0);
}

// ---------------- split pass: out_hi/lo = bf16 split of (optionally mixed) f32 ----------------
__global__ void mixsplit(const float* __restrict__ in, const float* __restrict__ xxr,
                         unsigned short* __restrict__ hi, unsigned short* __restrict__ lo,
                         int T, int D, int total8, int domix)
{
    int i = blockIdx.x * 256 + threadIdx.x;
    if (i >= total8) return;
    const size_t e = (size_t)i * 8;
    float a[8];
    *(float4*)&a[0] = *(const float4*)(in + e);
    *(float4*)&a[4] = *(const float4*)(in + e + 4);
    if (domix) {
        const int m = (int)(e / D);
        const int d = (int)(e % D);
        const int t = m % T;
        float p[8] = {0.f,0.f,0.f,0.f,0.f,0.f,0.f,0.f};
        if (t > 0) {
            *(float4*)&p[0] = *(const float4*)(in + e - D);
            *(float4*)&p[4] = *(const float4*)(in + e - D + 4);
        }
        float xv[8];
        *(float4*)&xv[0] = *(const float4*)(xxr + d);
        *(float4*)&xv[4] = *(const float4*)(xxr + d + 4);
        #pragma unroll
        for (int j = 0; j < 8; ++j) a[j] += (p[j] - a[j]) * xv[j];
    }
    ushort8 h8, l8;
    #pragma unroll
    for (int j = 0; j < 8; ++j) {
        const unsigned short h = f2b(a[j]);
        h8[j] = h;
        l8[j] = f2b(a[j] - b2f(h));
    }
    *(ushort8*)(hi + e) = h8;
    *(ushort8*)(lo + e) = l8;
}

// ---------------- dual (hi+lo) bf16 MFMA GEMM: C[M,N] = A[M,K] @ W[N,K]^T, f32 out --------
#define GBM 128
#define GBN 128

__global__ __launch_bounds__(256) void gemm_dual(
    const unsigned short* __restrict__ Ahg, const unsigned short* __restrict__ Alg,
    const unsigned short* __restrict__ Bhg, const unsigned short* __restrict__ Blg,
    float* __restrict__ C, int M, int N, int K, int mode,
    const float* __restrict__ yv, const float* __restrict__ bias,
    const float* __restrict__ aux)
{
    __shared__ unsigned short Ah[GBM * 32], Al[GBM * 32];
    __shared__ unsigned short Bh[GBN * 32], Bl[GBN * 32];
    const int tid = threadIdx.x;
    const int m0 = blockIdx.x * GBM;
    const int n0 = blockIdx.y * GBN;
    const int wave = tid >> 6, lane = tid & 63;
    const int wr = (wave >> 1) * 64, wc = (wave & 1) * 64;
    const int fr = lane & 15, fq = lane >> 4;

    f32x4 acc[4][4];
    #pragma unroll
    for (int i = 0; i < 4; ++i)
        #pragma unroll
        for (int j = 0; j < 4; ++j)
            acc[i][j] = (f32x4){0.f, 0.f, 0.f, 0.f};

    const unsigned short* gsrc = (wave == 0) ? Ahg : (wave == 1) ? Alg : (wave == 2) ? Bhg : Blg;
    unsigned short* lbuf = (wave == 0) ? Ah : (wave == 1) ? Al : (wave == 2) ? Bh : Bl;
    const int tile0 = (wave < 2) ? m0 : n0;
    const unsigned short* gbase = gsrc + (size_t)(tile0 + (lane >> 2)) * K + ((lane & 3) << 3);

    for (int k0 = 0; k0 < K; k0 += 32) {
        #pragma unroll
        for (int j = 0; j < 8; ++j)
            gld16(lbuf + j * 16 * 32, gbase + (size_t)(j * 16) * K + k0);
        __syncthreads();

        bf16x8 fah[4], fal[4], fbh[4], fbl[4];
        #pragma unroll
        for (int m = 0; m < 4; ++m) {
            fah[m] = *(const bf16x8*)&Ah[(wr + m * 16 + fr) * 32 + fq * 8];
            fal[m] = *(const bf16x8*)&Al[(wr + m * 16 + fr) * 32 + fq * 8];
        }
        #pragma unroll
        for (int n = 0; n < 4; ++n) {
            fbh[n] = *(const bf16x8*)&Bh[(wc + n * 16 + fr) * 32 + fq * 8];
            fbl[n] = *(const bf16x8*)&Bl[(wc + n * 16 + fr) * 32 + fq * 8];
        }
        #pragma unroll
        for (int m = 0; m < 4; ++m)
            #pragma unroll
            for (int n = 0; n < 4; ++n) {
                acc[m][n] = __builtin_amdgcn_mfma_f32_16x16x32_bf16(fah[m], fbh[n], acc[m][n], 0, 0, 0);
                acc[m][n] = __builtin_amdgcn_mfma_f32_16x16x32_bf16(fah[m], fbl[n], acc[m][n], 0, 0, 0);
                acc[m][n] = __builtin_amdgcn_mfma_f32_16x16x32_bf16(fal[m], fbh[n], acc[m][n], 0, 0, 0);
            }
        __syncthreads();
    }

    #pragma unroll
    for (int m = 0; m < 4; ++m) {
        const int row = m0 + wr + m * 16 + fq * 4;
        #pragma unroll
        for (int n = 0; n < 4; ++n) {
            const int col = n0 + wc + n * 16 + fr;
            #pragma unroll
            for (int j = 0; j < 4; ++j) {
                const size_t idx = (size_t)(row + j) * N + col;
                float v = acc[m][n][j];
                if (mode == 2) {
                    const float sg = sigm(yv[idx] + bias[col]);
                    v = v + sg * (aux[idx] - v);
                }
                C[idx] = v;
            }
        }
    }
}

// ---------------- f32 SIMD GEMM (LoRA stage-2) ----------------
#define BM 64
#define BN 64
#define BK 16
__global__ __launch_bounds__(256) void gemm_f32(
    const float* __restrict__ A, const float* __restrict__ xx,
    const float* __restrict__ W, float* __restrict__ C,
    int M, int N, int K, int T, int mode, const float* __restrict__ bias)
{
    __shared__ float As[BK][BM + 4];
    __shared__ float Bs[BK][BN + 4];
    const int tid = threadIdx.x;
    const int m0 = blockIdx.x * BM;
    const int n0 = blockIdx.y * BN;
    const int lr = tid >> 2;
    const int lk = (tid & 3) << 2;
    const int tx = tid & 15;
    const int ty = tid >> 4;
    const int mrow = m0 + lr;
    const int nrow = n0 + lr;
    float acc[4][4];
    #pragma unroll
    for (int i = 0; i < 4; ++i)
        #pragma unroll
        for (int j = 0; j < 4; ++j) acc[i][j] = 0.f;

    for (int k0 = 0; k0 < K; k0 += BK) {
        const float* ap = A + (size_t)mrow * K + k0 + lk;
        float4 av = *(const float4*)ap;
        if (xx) {
            const int t = mrow % T;
            float4 pv = make_float4(0.f, 0.f, 0.f, 0.f);
            if (t > 0) pv = *(const float4*)(ap - K);
            const float4 xv = *(const float4*)(xx + k0 + lk);
            av.x += (pv.x - av.x) * xv.x;
            av.y += (pv.y - av.y) * xv.y;
            av.z += (pv.z - av.z) * xv.z;
            av.w += (pv.w - av.w) * xv.w;
        }
        float4 bv = make_float4(0.f, 0.f, 0.f, 0.f);
        if (nrow < N) bv = *(const float4*)(W + (size_t)nrow * K + k0 + lk);

        As[lk + 0][lr] = av.x; As[lk + 1][lr] = av.y;
        As[lk + 2][lr] = av.z; As[lk + 3][lr] = av.w;
        Bs[lk + 0][lr] = bv.x; Bs[lk + 1][lr] = bv.y;
        Bs[lk + 2][lr] = bv.z; Bs[lk + 3][lr] = bv.w;
        __syncthreads();

        #pragma unroll
        for (int kk = 0; kk < BK; ++kk) {
            const float4 a4 = *(const float4*)&As[kk][ty << 2];
            const float4 b4 = *(const float4*)&Bs[kk][tx << 2];
            const float a[4] = {a4.x, a4.y, a4.z, a4.w};
            const float b[4] = {b4.x, b4.y, b4.z, b4.w};
            #pragma unroll
            for (int i = 0; i < 4; ++i)
                #pragma unroll
                for (int j = 0; j < 4; ++j)
                    acc[i][j] = fmaf(a[i], b[j], acc[i][j]);
        }
        __syncthreads();
    }
    #pragma unroll
    for (int i = 0; i < 4; ++i) {
        const int m = m0 + (ty << 2) + i;
        #pragma unroll
        for (int j = 0; j < 4; ++j) {
            const int n = n0 + (tx << 2) + j;
            if (n < N) {
                const size_t idx = (size_t)m * N + n;
                float v = acc[i][j];
                if (mode == 1) v = 0.6065306597126334f * sigm(v + bias[n]);
                C[idx] = v;
            }
        }
    }
}

// ---------------- fused LoRA stage-1: 4 GEMMs in one launch, act in epilogue ------------
// blockIdx.y: 0 -> HW = tanh(mix1 @ wA^T)   [M,64]
//             1 -> HV = mix3 @ vA^T         [M,16]
//             2 -> HA = mix4 @ aA^T         [M,64]
//             3,4 -> HG[:, y64] = sigm(mix5 @ gA^T)  [M,128]
__global__ __launch_bounds__(256) void lora1(
    const float* __restrict__ hid, const float* __restrict__ x_x,
    const float* __restrict__ wA, const float* __restrict__ vA,
    const float* __restrict__ aA, const float* __restrict__ gA,
    float* __restrict__ HW, float* __restrict__ HV,
    float* __restrict__ HA, float* __restrict__ HG,
    int M, int K, int T)
{
    __shared__ float As[BK][BM + 4];
    __shared__ float Bs[BK][BN + 4];
    const int y = blockIdx.y;
    const float* W; const float* xx; float* C; int NL, act, nofs, nvalid;
    if (y == 0)      { W = wA; xx = x_x + 1 * (size_t)K; C = HW; NL = 64;  act = 1; nofs = 0;  nvalid = 64; }
    else if (y == 1) { W = vA; xx = x_x + 3 * (size_t)K; C = HV; NL = 16;  act = 0; nofs = 0;  nvalid = 16; }
    else if (y == 2) { W = aA; xx = x_x + 4 * (size_t)K; C = HA; NL = 64;  act = 0; nofs = 0;  nvalid = 64; }
    else             { W = gA + (size_t)(y - 3) * 64 * K; xx = x_x + 5 * (size_t)K; C = HG; NL = 128; act = 2; nofs = (y - 3) * 64; nvalid = 64; }

    const int tid = threadIdx.x;
    const int m0 = blockIdx.x * BM;
    const int lr = tid >> 2;
    const int lk = (tid & 3) << 2;
    const int tx = tid & 15;
    const int ty = tid >> 4;
    const int mrow = m0 + lr;
    float acc[4][4];
    #pragma unroll
    for (int i = 0; i < 4; ++i)
        #pragma unroll
        for (int j = 0; j < 4; ++j) acc[i][j] = 0.f;

    for (int k0 = 0; k0 < K; k0 += BK) {
        const float* ap = hid + (size_t)mrow * K + k0 + lk;
        float4 av = *(const float4*)ap;
        {
            const int t = mrow % T;
            float4 pv = make_float4(0.f, 0.f, 0.f, 0.f);
            if (t > 0) pv = *(const float4*)(ap - K);
            const float4 xv = *(const float4*)(xx + k0 + lk);
            av.x += (pv.x - av.x) * xv.x;
            av.y += (pv.y - av.y) * xv.y;
            av.z += (pv.z - av.z) * xv.z;
            av.w += (pv.w - av.w) * xv.w;
        }
        float4 bv = make_float4(0.f, 0.f, 0.f, 0.f);
        if (lr < nvalid) bv = *(const float4*)(W + (size_t)lr * K + k0 + lk);

        As[lk + 0][lr] = av.x; As[lk + 1][lr] = av.y;
        As[lk + 2][lr] = av.z; As[lk + 3][lr] = av.w;
        Bs[lk + 0][lr] = bv.x; Bs[lk + 1][lr] = bv.y;
        Bs[lk + 2][lr] = bv.z; Bs[lk + 3][lr] = bv.w;
        __syncthreads();

        #pragma unroll
        for (int kk = 0; kk < BK; ++kk) {
            const float4 a4 = *(const float4*)&As[kk][ty << 2];
            const float4 b4 = *(const float4*)&Bs[kk][tx << 2];
            const float a[4] = {a4.x, a4.y, a4.z, a4.w};
            const float b[4] = {b4.x, b4.y, b4.z, b4.w};
            #pragma unroll
            for (int i = 0; i < 4; ++i)
                #pragma unroll
                for (int j = 0; j < 4; ++j)
                    acc[i][j] = fmaf(a[i], b[j], acc[i][j]);
        }
        __syncthreads();
    }
    #pragma unroll
    for (int i = 0; i < 4; ++i) {
        const int m = m0 + (ty << 2) + i;
        #pragma unroll
        for (int j = 0; j < 4; ++j) {
            const int n = (tx << 2) + j;
            if (n < nvalid) {
                float v = acc[i][j];
                if (act == 1) v = tanhf(v);
                else if (act == 2) v = sigm(v);
                C[(size_t)m * NL + nofs + n] = v;
            }
        }
    }
}

// per-(b,t,h) wave: a = sigmoid(ya+ab); kk = normalize(k0*k_k); bv = kk*a;
// kfinal = k0*(1+(a-1)*k_a)
__global__ __launch_bounds__(256) void ka_epi(
    float* __restrict__ Kf, float* __restrict__ A_BV, float* __restrict__ KKo,
    const float* __restrict__ k_k, const float* __restrict__ k_a,
    const float* __restrict__ ab, int total, int H)
{
    int wid = (blockIdx.x << 2) | (threadIdx.x >> 6);
    if (wid >= total) return;
    const int l = threadIdx.x & 63;
    const int h = wid % H;
    const int ch = h * 64 + l;
    const size_t base = (size_t)wid * 64;
    float k0 = Kf[base + l];
    float a = sigm(A_BV[base + l] + ab[ch]);
    float kkr = k0 * k_k[ch];
    float ss = kkr * kkr;
    #pragma unroll
    for (int off = 1; off < 64; off <<= 1) ss += __shfl_xor(ss, off, 64);
    float inv = 1.f / fmaxf(sqrtf(ss), 1e-12f);
    float kkn = kkr * inv;
    KKo[base + l] = kkn;
    A_BV[base + l] = kkn * a;
    Kf[base + l] = k0 * fmaf(a - 1.f, k_a[ch], 1.f);
}

// DPLR scan v5. ONE wave per block; grid = B*H*4 = 256 (1 block/CU).
// Lane l: vc = l&15, g = l>>4, owns k in [g*16,+16). Chunks staged via
// global_load_lds; reductions via permlane swaps (VALU) -> no lgkm on chain.
#define SCH 16
__global__ __launch_bounds__(64) void rwkv_scan(
    const float* __restrict__ EW, const float* __restrict__ R,
    const float* __restrict__ Kf, const float* __restrict__ Vf,
    const float* __restrict__ KK, const float* __restrict__ BV,
    float* __restrict__ O, int T, int H)
{
    __shared__ float lds[2][5 * SCH * 64 + SCH * 16];

    const int blk = blockIdx.x;
    const int bh = blk & 63;
    const int slab = blk >> 6;
    const int b = bh >> 5, h = bh & 31;
    const int l = threadIdx.x;
    const int vc = l & 15;
    const int g  = l >> 4;
    const int kb = g << 4;
    const int vb0 = slab << 4;
    const size_t step = (size_t)H * 64;
    const size_t base0 = ((size_t)b * T * H + h) * 64;

    auto stage = [&](int c, int buf) {
        float* L = &lds[buf][0];
        const size_t t0 = (size_t)c * SCH;
        const float* gs[5] = {EW, R, Kf, KK, BV};
        #pragma unroll
        for (int s = 0; s < 5; ++s) {
            const float* gp = gs[s];
            #pragma unroll
            for (int j = 0; j < 4; ++j)
                gld16(L + s * SCH * 64 + j * 4 * 64,
                      gp + base0 + (t0 + j * 4 + (l >> 4)) * step + ((l & 15) << 2));
        }
        gld16(L + 5 * SCH * 64,
              Vf + base0 + (t0 + (l >> 2)) * step + vb0 + ((l & 3) << 2));
    };

    f32x2 s2[8];
    #pragma unroll
    for (int i = 0; i < 8; ++i) s2[i] = (f32x2){0.f, 0.f};

    struct P { f32x4 e[4], r[4], k[4], q[4], bb[4]; float vv; };
    P PA, PB;
    const int NCH = T / SCH;

    stage(0, 0);
    asm volatile("s_waitcnt vmcnt(0)" ::: "memory");
    __builtin_amdgcn_sched_barrier(0);

    for (int c = 0; c < NCH; ++c) {
        if (c + 1 < NCH) stage(c + 1, (c + 1) & 1);

        const float* L = &lds[c & 1][0];
        auto PRE = [&](P& pp, int tt) {
            const int o = tt * 64 + kb;
            #pragma unroll
            for (int j = 0; j < 4; ++j) {
                pp.e[j]  = *(const f32x4*)(L + 0 * SCH * 64 + o + j * 4);
                pp.r[j]  = *(const f32x4*)(L + 1 * SCH * 64 + o + j * 4);
                pp.k[j]  = *(const f32x4*)(L + 2 * SCH * 64 + o + j * 4);
                pp.q[j]  = *(const f32x4*)(L + 3 * SCH * 64 + o + j * 4);
                pp.bb[j] = *(const f32x4*)(L + 4 * SCH * 64 + o + j * 4);
            }
            pp.vv = L[5 * SCH * 64 + tt * 16 + vc];
        };
        auto COMP = [&](const P& pp, int tt) {
            f32x2 sa0 = (f32x2){0.f, 0.f}, sa1 = (f32x2){0.f, 0.f};
            #pragma unroll
            for (int j = 0; j < 4; ++j) {
                const f32x2 elo = __builtin_shufflevector(pp.e[j], pp.e[j], 0, 1);
                const f32x2 ehi = __builtin_shufflevector(pp.e[j], pp.e[j], 2, 3);
                const f32x2 qlo = __builtin_shufflevector(pp.q[j], pp.q[j], 0, 1);
                const f32x2 qhi = __builtin_shufflevector(pp.q[j], pp.q[j], 2, 3);
                s2[2*j]   *= elo;
                s2[2*j+1] *= ehi;
                sa0 += qlo * s2[2*j];
                sa1 += qhi * s2[2*j+1];
            }
            const f32x2 sas = sa0 + sa1;
            float p = -(sas.x + sas.y);
            p = red32(red16(p));                    // VALU reduction, no DS wait
            const f32x2 p2 = (f32x2){p, p};
            const f32x2 v2 = (f32x2){pp.vv, pp.vv};
            f32x2 o0 = (f32x2){0.f, 0.f}, o1 = (f32x2){0.f, 0.f};
            #pragma unroll
            for (int j = 0; j < 4; ++j) {
                const f32x2 klo = __builtin_shufflevector(pp.k[j], pp.k[j], 0, 1);
                const f32x2 khi = __builtin_shufflevector(pp.k[j], pp.k[j], 2, 3);
                const f32x2 blo = __builtin_shufflevector(pp.bb[j], pp.bb[j], 0, 1);
                const f32x2 bhi = __builtin_shufflevector(pp.bb[j], pp.bb[j], 2, 3);
                const f32x2 rlo = __builtin_shufflevector(pp.r[j], pp.r[j], 0, 1);
                const f32x2 rhi = __builtin_shufflevector(pp.r[j], pp.r[j], 2, 3);
                s2[2*j]   = blo * p2 + (klo * v2 + s2[2*j]);
                s2[2*j+1] = bhi * p2 + (khi * v2 + s2[2*j+1]);
                o0 += rlo * s2[2*j];
                o1 += rhi * s2[2*j+1];
            }
            const f32x2 os = o0 + o1;
            float oo = os.x + os.y;
            oo = red32(red16(oo));                  // VALU reduction
            if (g == 0)
                O[base0 + (size_t)(c * SCH + tt) * step + vb0 + vc] = oo;
        };

        PRE(PA, 0);
        PRE(PB, 1);
        #pragma unroll
        for (int tt = 0; tt < SCH - 2; tt += 2) {
            COMP(PA, tt);     PRE(PA, tt + 2);
            COMP(PB, tt + 1); PRE(PB, tt + 3);
        }
        COMP(PA, SCH - 2);
        COMP(PB, SCH - 1);

        asm volatile("s_waitcnt vmcnt(0)" ::: "memory");
        __builtin_amdgcn_sched_barrier(0);
    }
}

// GroupNorm + bonus + on-the-fly g (HG[m,:128] . gB[ch,:128]); f32 ON out.
__global__ __launch_bounds__(256) void gn_bonus(
    const float* __restrict__ O, const float* __restrict__ R,
    const float* __restrict__ Kf, const float* __restrict__ Vf,
    const float* __restrict__ HG, const float* __restrict__ gB,
    const float* __restrict__ r_k,
    const float* __restrict__ gn_w, const float* __restrict__ gn_b,
    float* __restrict__ ON, int total, int H, float eps)
{
    int wid = (blockIdx.x << 2) | (threadIdx.x >> 6);
    if (wid >= total) return;
    const int l = threadIdx.x & 63;
    const int h = wid % H;
    const int ch = h * 64 + l;
    const int m = wid / H;
    const size_t base = (size_t)wid * 64;

    const float4* hg4 = (const float4*)(HG + (size_t)m * 128);
    const float4* gb4 = (const float4*)(gB + (size_t)ch * 128);
    float g = 0.f;
    #pragma unroll 8
    for (int j = 0; j < 32; ++j) {
        const float4 a = hg4[j], b = gb4[j];
        g += a.x * b.x + a.y * b.y + a.z * b.z + a.w * b.w;
    }

    const float o = O[base + l];
    float sum = o;
    #pragma unroll
    for (int off = 1; off < 64; off <<= 1) sum += __shfl_xor(sum, off, 64);
    const float mu = sum * (1.f / 64.f);
    const float d = o - mu;
    float ss = d * d;
    #pragma unroll
    for (int off = 1; off < 64; off <<= 1) ss += __shfl_xor(ss, off, 64);
    const float inv = 1.f / sqrtf(ss * (1.f / 64.f) + eps);
    float on = d * inv * gn_w[ch] + gn_b[ch];

    const float r = R[base + l], k = Kf[base + l], vv = Vf[base + l];
    float p = r * k * r_k[ch];
    #pragma unroll
    for (int off = 1; off < 64; off <<= 1) p += __shfl_xor(p, off, 64);
    on = fmaf(p, vv, on);
    ON[base + l] = on * g;
}

extern "C" void kernel_launch(void* const* d_in, const int* in_sizes, int n_in,
                              void* d_out, int out_size, void* d_ws, size_t ws_size,
                              hipStream_t stream)
{
    const int B = 2, T = 2048, D = 2048, H = 32;
    const int M = B * T;

    const float* hid = (const float*)d_in[0];
    const float* vst = (const float*)d_in[1];
    const float* x_x = (const float*)d_in[2];
    const float* k_k = (const float*)d_in[3];
    const float* k_a = (const float*)d_in[4];
    const float* r_k = (const float*)d_in[5];
    const float* Wr  = (const float*)d_in[6];
    const float* Wk  = (const float*)d_in[7];
    const float* Wv  = (const float*)d_in[8];
    const float* Wo  = (const float*)d_in[9];
    const float* wA  = (const float*)d_in[10];
    const float* wB  = (const float*)d_in[11];
    const float* wb  = (const float*)d_in[12];
    const float* vA  = (const float*)d_in[13];
    const float* vB  = (const float*)d_in[14];
    const float* vb  = (const float*)d_in[15];
    const float* aA  = (const float*)d_in[16];
    const float* aB  = (const float*)d_in[17];
    const float* ab  = (const float*)d_in[18];
    const float* gA  = (const float*)d_in[19];
    const float* gB  = (const float*)d_in[20];
    const float* gnw = (const float*)d_in[21];
    const float* gnb = (const float*)d_in[22];
    float* out = (float*)d_out;

    const size_t NE = (size_t)M * D;   // 8,388,608
    const size_t DD = (size_t)D * D;   // 4,194,304
    const size_t need = (6 * NE + (size_t)M * 272) * sizeof(float);  // ~196 MiB (proven)
    if (ws_size < need) return;

    float* R_  = (float*)d_ws;
    float* EW  = R_  + NE;
    float* Kf  = EW  + NE;
    float* Vf  = Kf  + NE;
    float* KK  = Vf  + NE;
    float* ABV = KK  + NE;
    float* HW  = ABV + NE;
    float* HV  = HW + (size_t)M * 64;
    float* HA  = HV + (size_t)M * 16;
    float* HG  = HA + (size_t)M * 64;

    dim3 blk(256);
    dim3 gDual(M / GBM, D / GBN);
    const int nMix = (int)(NE / 8);
    const int nW   = (int)(DD / 8);
    const float* nf = nullptr;

    unsigned short* XHi = (unsigned short*)EW;
    unsigned short* XLo = XHi + NE;
    unsigned short* WHi = (unsigned short*)KK;
    unsigned short* WLo = WHi + DD;

    // ---- phase 1: fused LoRA stage-1 (acts in epilogue) ----
    hipLaunchKernelGGL(lora1, dim3(M / BM, 5), blk, 0, stream,
                       hid, x_x, wA, vA, aA, gA, HW, HV, HA, HG, M, D, T);

    // ---- phase 2: yv -> ABV ----
    hipLaunchKernelGGL(gemm_f32, dim3(M / BM, D / BN), blk, 0, stream, HV, nf, vB, ABV, M, D, 16, T, 0, nf);

    // ---- phase 3: R/K/V projections via split MFMA ----
    hipLaunchKernelGGL(mixsplit, dim3(nMix / 256), blk, 0, stream, hid, x_x + 0 * (size_t)D, XHi, XLo, T, D, nMix, 1);
    hipLaunchKernelGGL(mixsplit, dim3(nW / 256), blk, 0, stream, Wr, nf, WHi, WLo, T, D, nW, 0);
    hipLaunchKernelGGL(gemm_dual, gDual, blk, 0, stream, XHi, XLo, WHi, WLo, R_, M, D, D, 0, nf, nf, nf);

    hipLaunchKernelGGL(mixsplit, dim3(nMix / 256), blk, 0, stream, hid, x_x + 2 * (size_t)D, XHi, XLo, T, D, nMix, 1);
    hipLaunchKernelGGL(mixsplit, dim3(nW / 256), blk, 0, stream, Wk, nf, WHi, WLo, T, D, nW, 0);
    hipLaunchKernelGGL(gemm_dual, gDual, blk, 0, stream, XHi, XLo, WHi, WLo, Kf, M, D, D, 0, nf, nf, nf);

    hipLaunchKernelGGL(mixsplit, dim3(nMix / 256), blk, 0, stream, hid, x_x + 3 * (size_t)D, XHi, XLo, T, D, nMix, 1);
    hipLaunchKernelGGL(mixsplit, dim3(nW / 256), blk, 0, stream, Wv, nf, WHi, WLo, T, D, nW, 0);
    hipLaunchKernelGGL(gemm_dual, gDual, blk, 0, stream, XHi, XLo, WHi, WLo, Vf, M, D, D, 2, ABV, vb, vst);

    // ---- phase 4: LoRA stage-2 ----
    hipLaunchKernelGGL(gemm_f32, dim3(M / BM, D / BN), blk, 0, stream, HW, nf, wB, EW,  M, D, 64, T, 1, wb);
    hipLaunchKernelGGL(gemm_f32, dim3(M / BM, D / BN), blk, 0, stream, HA, nf, aB, ABV, M, D, 64, T, 0, nf);

    // ---- phase 5: ka epilogue ----
    const int totalW = M * H;
    hipLaunchKernelGGL(ka_epi, dim3(totalW / 4), blk, 0, stream, Kf, ABV, KK, k_k, k_a, ab, totalW, H);

    // ---- phase 6: scan -> d_out (256 single-wave blocks) ----
    hipLaunchKernelGGL(rwkv_scan, dim3(B * H * 4), dim3(64), 0, stream, EW, R_, Kf, Vf, KK, ABV, out, T, H);

    // ---- phase 7: GroupNorm + bonus + g -> EW ----
    hipLaunchKernelGGL(gn_bonus, dim3(totalW / 4), blk, 0, stream, out, R_, Kf, Vf, HG, gB, r_k, gnw, gnb, EW, totalW, H, 64.f * 1e-5f);

    // ---- phase 8: Wo projection -> d_out ----
    unsigned short* XHi2 = (unsigned short*)KK;
    unsigned short* XLo2 = XHi2 + NE;
    unsigned short* WHi2 = (unsigned short*)ABV;
    unsigned short* WLo2 = WHi2 + DD;
    hipLaunchKernelGGL(mixsplit, dim3(nMix / 256), blk, 0, stream, EW, nf, XHi2, XLo2, T, D, nMix, 0);
    hipLaunchKernelGGL(mixsplit, dim3(nW / 256), blk, 0, stream, Wo, nf, WHi2, WLo2, T, D, nW, 0);
    hipLaunchKernelGGL(gemm_dual, gDual, blk, 0, stream, XHi2, XLo2, WHi2, WLo2, out, M, D, D, 0, nf, nf, nf);
}

// Round 11
// 1303.491 us; speedup vs baseline: 4.2603x; 1.4013x over previous
//
#include <hip/hip_runtime.h>
#include <hip/hip_bf16.h>
#include <math.h>

// RWKV7 attention, round 11:
//  - g-gate materialized: G = HG @ gB^T via coalesced gemm_f32 into the dead KK
//    window (post-scan); gn_bonus reads G coalesced instead of the per-lane
//    uncoalesced 128-dot (the r10 profile's 614 us hotspot).
// Other kernels identical to round 10.

typedef __attribute__((ext_vector_type(8))) unsigned short ushort8;
typedef __attribute__((ext_vector_type(8))) short bf16x8;
typedef __attribute__((ext_vector_type(4))) float f32x4;
typedef __attribute__((ext_vector_type(2))) float f32x2;

__device__ inline float b2f(unsigned short u) {
    union { unsigned int u; float f; } x; x.u = ((unsigned int)u) << 16; return x.f;
}
__device__ inline unsigned short f2b(float f) {
    union { float f; unsigned int u; } x; x.f = f;
    return (unsigned short)((x.u + 0x7FFF + ((x.u >> 16) & 1)) >> 16);
}
__device__ inline float sigm(float x) { return 1.f / (1.f + expf(-x)); }

// VALU cross-lane reductions (gfx950 permlane swaps); opaque copy keeps a/b in
// distinct registers (r9 lesson: aliased operands -> swap(v0,v0) miscompile).
__device__ __forceinline__ float red16(float x) {
    float b = x;
    asm("" : "+v"(b));
    float a = x;
    asm("v_permlane16_swap_b32 %0, %1" : "+v"(a), "+v"(b));
    return a + b;
}
__device__ __forceinline__ float red32(float x) {
    float b = x;
    asm("" : "+v"(b));
    float a = x;
    asm("v_permlane32_swap_b32 %0, %1" : "+v"(a), "+v"(b));
    return a + b;
}

// async global -> LDS, 16 bytes per lane. LDS dest = uniform base + lane*16.
__device__ __forceinline__ void gld16(void* lds, const void* g)
{
    __builtin_amdgcn_global_load_lds(
        (const __attribute__((address_space(1))) void*)g,
        (__attribute__((address_space(3))) void*)lds, 16, 0, 0);
}

// ---------------- split pass: out_hi/lo = bf16 split of (optionally mixed) f32 ----------------
__global__ void mixsplit(const float* __restrict__ in, const float* __restrict__ xxr,
                         unsigned short* __restrict__ hi, unsigned short* __restrict__ lo,
                         int T, int D, int total8, int domix)
{
    int i = blockIdx.x * 256 + threadIdx.x;
    if (i >= total8) return;
    const size_t e = (size_t)i * 8;
    float a[8];
    *(float4*)&a[0] = *(const float4*)(in + e);
    *(float4*)&a[4] = *(const float4*)(in + e + 4);
    if (domix) {
        const int m = (int)(e / D);
        const int d = (int)(e % D);
        const int t = m % T;
        float p[8] = {0.f,0.f,0.f,0.f,0.f,0.f,0.f,0.f};
        if (t > 0) {
            *(float4*)&p[0] = *(const float4*)(in + e - D);
            *(float4*)&p[4] = *(const float4*)(in + e - D + 4);
        }
        float xv[8];
        *(float4*)&xv[0] = *(const float4*)(xxr + d);
        *(float4*)&xv[4] = *(const float4*)(xxr + d + 4);
        #pragma unroll
        for (int j = 0; j < 8; ++j) a[j] += (p[j] - a[j]) * xv[j];
    }
    ushort8 h8, l8;
    #pragma unroll
    for (int j = 0; j < 8; ++j) {
        const unsigned short h = f2b(a[j]);
        h8[j] = h;
        l8[j] = f2b(a[j] - b2f(h));
    }
    *(ushort8*)(hi + e) = h8;
    *(ushort8*)(lo + e) = l8;
}

// ---------------- dual (hi+lo) bf16 MFMA GEMM: C[M,N] = A[M,K] @ W[N,K]^T, f32 out --------
#define GBM 128
#define GBN 128

__global__ __launch_bounds__(256) void gemm_dual(
    const unsigned short* __restrict__ Ahg, const unsigned short* __restrict__ Alg,
    const unsigned short* __restrict__ Bhg, const unsigned short* __restrict__ Blg,
    float* __restrict__ C, int M, int N, int K, int mode,
    const float* __restrict__ yv, const float* __restrict__ bias,
    const float* __restrict__ aux)
{
    __shared__ unsigned short Ah[GBM * 32], Al[GBM * 32];
    __shared__ unsigned short Bh[GBN * 32], Bl[GBN * 32];
    const int tid = threadIdx.x;
    const int m0 = blockIdx.x * GBM;
    const int n0 = blockIdx.y * GBN;
    const int wave = tid >> 6, lane = tid & 63;
    const int wr = (wave >> 1) * 64, wc = (wave & 1) * 64;
    const int fr = lane & 15, fq = lane >> 4;

    f32x4 acc[4][4];
    #pragma unroll
    for (int i = 0; i < 4; ++i)
        #pragma unroll
        for (int j = 0; j < 4; ++j)
            acc[i][j] = (f32x4){0.f, 0.f, 0.f, 0.f};

    const unsigned short* gsrc = (wave == 0) ? Ahg : (wave == 1) ? Alg : (wave == 2) ? Bhg : Blg;
    unsigned short* lbuf = (wave == 0) ? Ah : (wave == 1) ? Al : (wave == 2) ? Bh : Bl;
    const int tile0 = (wave < 2) ? m0 : n0;
    const unsigned short* gbase = gsrc + (size_t)(tile0 + (lane >> 2)) * K + ((lane & 3) << 3);

    for (int k0 = 0; k0 < K; k0 += 32) {
        #pragma unroll
        for (int j = 0; j < 8; ++j)
            gld16(lbuf + j * 16 * 32, gbase + (size_t)(j * 16) * K + k0);
        __syncthreads();

        bf16x8 fah[4], fal[4], fbh[4], fbl[4];
        #pragma unroll
        for (int m = 0; m < 4; ++m) {
            fah[m] = *(const bf16x8*)&Ah[(wr + m * 16 + fr) * 32 + fq * 8];
            fal[m] = *(const bf16x8*)&Al[(wr + m * 16 + fr) * 32 + fq * 8];
        }
        #pragma unroll
        for (int n = 0; n < 4; ++n) {
            fbh[n] = *(const bf16x8*)&Bh[(wc + n * 16 + fr) * 32 + fq * 8];
            fbl[n] = *(const bf16x8*)&Bl[(wc + n * 16 + fr) * 32 + fq * 8];
        }
        #pragma unroll
        for (int m = 0; m < 4; ++m)
            #pragma unroll
            for (int n = 0; n < 4; ++n) {
                acc[m][n] = __builtin_amdgcn_mfma_f32_16x16x32_bf16(fah[m], fbh[n], acc[m][n], 0, 0, 0);
                acc[m][n] = __builtin_amdgcn_mfma_f32_16x16x32_bf16(fah[m], fbl[n], acc[m][n], 0, 0, 0);
                acc[m][n] = __builtin_amdgcn_mfma_f32_16x16x32_bf16(fal[m], fbh[n], acc[m][n], 0, 0, 0);
            }
        __syncthreads();
    }

    #pragma unroll
    for (int m = 0; m < 4; ++m) {
        const int row = m0 + wr + m * 16 + fq * 4;
        #pragma unroll
        for (int n = 0; n < 4; ++n) {
            const int col = n0 + wc + n * 16 + fr;
            #pragma unroll
            for (int j = 0; j < 4; ++j) {
                const size_t idx = (size_t)(row + j) * N + col;
                float v = acc[m][n][j];
                if (mode == 2) {
                    const float sg = sigm(yv[idx] + bias[col]);
                    v = v + sg * (aux[idx] - v);
                }
                C[idx] = v;
            }
        }
    }
}

// ---------------- f32 SIMD GEMM (LoRA stage-2, g-gate) ----------------
#define BM 64
#define BN 64
#define BK 16
__global__ __launch_bounds__(256) void gemm_f32(
    const float* __restrict__ A, const float* __restrict__ xx,
    const float* __restrict__ W, float* __restrict__ C,
    int M, int N, int K, int T, int mode, const float* __restrict__ bias)
{
    __shared__ float As[BK][BM + 4];
    __shared__ float Bs[BK][BN + 4];
    const int tid = threadIdx.x;
    const int m0 = blockIdx.x * BM;
    const int n0 = blockIdx.y * BN;
    const int lr = tid >> 2;
    const int lk = (tid & 3) << 2;
    const int tx = tid & 15;
    const int ty = tid >> 4;
    const int mrow = m0 + lr;
    const int nrow = n0 + lr;
    float acc[4][4];
    #pragma unroll
    for (int i = 0; i < 4; ++i)
        #pragma unroll
        for (int j = 0; j < 4; ++j) acc[i][j] = 0.f;

    for (int k0 = 0; k0 < K; k0 += BK) {
        const float* ap = A + (size_t)mrow * K + k0 + lk;
        float4 av = *(const float4*)ap;
        if (xx) {
            const int t = mrow % T;
            float4 pv = make_float4(0.f, 0.f, 0.f, 0.f);
            if (t > 0) pv = *(const float4*)(ap - K);
            const float4 xv = *(const float4*)(xx + k0 + lk);
            av.x += (pv.x - av.x) * xv.x;
            av.y += (pv.y - av.y) * xv.y;
            av.z += (pv.z - av.z) * xv.z;
            av.w += (pv.w - av.w) * xv.w;
        }
        float4 bv = make_float4(0.f, 0.f, 0.f, 0.f);
        if (nrow < N) bv = *(const float4*)(W + (size_t)nrow * K + k0 + lk);

        As[lk + 0][lr] = av.x; As[lk + 1][lr] = av.y;
        As[lk + 2][lr] = av.z; As[lk + 3][lr] = av.w;
        Bs[lk + 0][lr] = bv.x; Bs[lk + 1][lr] = bv.y;
        Bs[lk + 2][lr] = bv.z; Bs[lk + 3][lr] = bv.w;
        __syncthreads();

        #pragma unroll
        for (int kk = 0; kk < BK; ++kk) {
            const float4 a4 = *(const float4*)&As[kk][ty << 2];
            const float4 b4 = *(const float4*)&Bs[kk][tx << 2];
            const float a[4] = {a4.x, a4.y, a4.z, a4.w};
            const float b[4] = {b4.x, b4.y, b4.z, b4.w};
            #pragma unroll
            for (int i = 0; i < 4; ++i)
                #pragma unroll
                for (int j = 0; j < 4; ++j)
                    acc[i][j] = fmaf(a[i], b[j], acc[i][j]);
        }
        __syncthreads();
    }
    #pragma unroll
    for (int i = 0; i < 4; ++i) {
        const int m = m0 + (ty << 2) + i;
        #pragma unroll
        for (int j = 0; j < 4; ++j) {
            const int n = n0 + (tx << 2) + j;
            if (n < N) {
                const size_t idx = (size_t)m * N + n;
                float v = acc[i][j];
                if (mode == 1) v = 0.6065306597126334f * sigm(v + bias[n]);
                C[idx] = v;
            }
        }
    }
}

// ---------------- fused LoRA stage-1: 4 GEMMs in one launch, act in epilogue ------------
__global__ __launch_bounds__(256) void lora1(
    const float* __restrict__ hid, const float* __restrict__ x_x,
    const float* __restrict__ wA, const float* __restrict__ vA,
    const float* __restrict__ aA, const float* __restrict__ gA,
    float* __restrict__ HW, float* __restrict__ HV,
    float* __restrict__ HA, float* __restrict__ HG,
    int M, int K, int T)
{
    __shared__ float As[BK][BM + 4];
    __shared__ float Bs[BK][BN + 4];
    const int y = blockIdx.y;
    const float* W; const float* xx; float* C; int NL, act, nofs, nvalid;
    if (y == 0)      { W = wA; xx = x_x + 1 * (size_t)K; C = HW; NL = 64;  act = 1; nofs = 0;  nvalid = 64; }
    else if (y == 1) { W = vA; xx = x_x + 3 * (size_t)K; C = HV; NL = 16;  act = 0; nofs = 0;  nvalid = 16; }
    else if (y == 2) { W = aA; xx = x_x + 4 * (size_t)K; C = HA; NL = 64;  act = 0; nofs = 0;  nvalid = 64; }
    else             { W = gA + (size_t)(y - 3) * 64 * K; xx = x_x + 5 * (size_t)K; C = HG; NL = 128; act = 2; nofs = (y - 3) * 64; nvalid = 64; }

    const int tid = threadIdx.x;
    const int m0 = blockIdx.x * BM;
    const int lr = tid >> 2;
    const int lk = (tid & 3) << 2;
    const int tx = tid & 15;
    const int ty = tid >> 4;
    const int mrow = m0 + lr;
    float acc[4][4];
    #pragma unroll
    for (int i = 0; i < 4; ++i)
        #pragma unroll
        for (int j = 0; j < 4; ++j) acc[i][j] = 0.f;

    for (int k0 = 0; k0 < K; k0 += BK) {
        const float* ap = hid + (size_t)mrow * K + k0 + lk;
        float4 av = *(const float4*)ap;
        {
            const int t = mrow % T;
            float4 pv = make_float4(0.f, 0.f, 0.f, 0.f);
            if (t > 0) pv = *(const float4*)(ap - K);
            const float4 xv = *(const float4*)(xx + k0 + lk);
            av.x += (pv.x - av.x) * xv.x;
            av.y += (pv.y - av.y) * xv.y;
            av.z += (pv.z - av.z) * xv.z;
            av.w += (pv.w - av.w) * xv.w;
        }
        float4 bv = make_float4(0.f, 0.f, 0.f, 0.f);
        if (lr < nvalid) bv = *(const float4*)(W + (size_t)lr * K + k0 + lk);

        As[lk + 0][lr] = av.x; As[lk + 1][lr] = av.y;
        As[lk + 2][lr] = av.z; As[lk + 3][lr] = av.w;
        Bs[lk + 0][lr] = bv.x; Bs[lk + 1][lr] = bv.y;
        Bs[lk + 2][lr] = bv.z; Bs[lk + 3][lr] = bv.w;
        __syncthreads();

        #pragma unroll
        for (int kk = 0; kk < BK; ++kk) {
            const float4 a4 = *(const float4*)&As[kk][ty << 2];
            const float4 b4 = *(const float4*)&Bs[kk][tx << 2];
            const float a[4] = {a4.x, a4.y, a4.z, a4.w};
            const float b[4] = {b4.x, b4.y, b4.z, b4.w};
            #pragma unroll
            for (int i = 0; i < 4; ++i)
                #pragma unroll
                for (int j = 0; j < 4; ++j)
                    acc[i][j] = fmaf(a[i], b[j], acc[i][j]);
        }
        __syncthreads();
    }
    #pragma unroll
    for (int i = 0; i < 4; ++i) {
        const int m = m0 + (ty << 2) + i;
        #pragma unroll
        for (int j = 0; j < 4; ++j) {
            const int n = (tx << 2) + j;
            if (n < nvalid) {
                float v = acc[i][j];
                if (act == 1) v = tanhf(v);
                else if (act == 2) v = sigm(v);
                C[(size_t)m * NL + nofs + n] = v;
            }
        }
    }
}

// per-(b,t,h) wave: a = sigmoid(ya+ab); kk = normalize(k0*k_k); bv = kk*a;
// kfinal = k0*(1+(a-1)*k_a)
__global__ __launch_bounds__(256) void ka_epi(
    float* __restrict__ Kf, float* __restrict__ A_BV, float* __restrict__ KKo,
    const float* __restrict__ k_k, const float* __restrict__ k_a,
    const float* __restrict__ ab, int total, int H)
{
    int wid = (blockIdx.x << 2) | (threadIdx.x >> 6);
    if (wid >= total) return;
    const int l = threadIdx.x & 63;
    const int h = wid % H;
    const int ch = h * 64 + l;
    const size_t base = (size_t)wid * 64;
    float k0 = Kf[base + l];
    float a = sigm(A_BV[base + l] + ab[ch]);
    float kkr = k0 * k_k[ch];
    float ss = kkr * kkr;
    #pragma unroll
    for (int off = 1; off < 64; off <<= 1) ss += __shfl_xor(ss, off, 64);
    float inv = 1.f / fmaxf(sqrtf(ss), 1e-12f);
    float kkn = kkr * inv;
    KKo[base + l] = kkn;
    A_BV[base + l] = kkn * a;
    Kf[base + l] = k0 * fmaf(a - 1.f, k_a[ch], 1.f);
}

// DPLR scan v5. ONE wave per block; grid = B*H*4 = 256 (1 block/CU).
#define SCH 16
__global__ __launch_bounds__(64) void rwkv_scan(
    const float* __restrict__ EW, const float* __restrict__ R,
    const float* __restrict__ Kf, const float* __restrict__ Vf,
    const float* __restrict__ KK, const float* __restrict__ BV,
    float* __restrict__ O, int T, int H)
{
    __shared__ float lds[2][5 * SCH * 64 + SCH * 16];

    const int blk = blockIdx.x;
    const int bh = blk & 63;
    const int slab = blk >> 6;
    const int b = bh >> 5, h = bh & 31;
    const int l = threadIdx.x;
    const int vc = l & 15;
    const int g  = l >> 4;
    const int kb = g << 4;
    const int vb0 = slab << 4;
    const size_t step = (size_t)H * 64;
    const size_t base0 = ((size_t)b * T * H + h) * 64;

    auto stage = [&](int c, int buf) {
        float* L = &lds[buf][0];
        const size_t t0 = (size_t)c * SCH;
        const float* gs[5] = {EW, R, Kf, KK, BV};
        #pragma unroll
        for (int s = 0; s < 5; ++s) {
            const float* gp = gs[s];
            #pragma unroll
            for (int j = 0; j < 4; ++j)
                gld16(L + s * SCH * 64 + j * 4 * 64,
                      gp + base0 + (t0 + j * 4 + (l >> 4)) * step + ((l & 15) << 2));
        }
        gld16(L + 5 * SCH * 64,
              Vf + base0 + (t0 + (l >> 2)) * step + vb0 + ((l & 3) << 2));
    };

    f32x2 s2[8];
    #pragma unroll
    for (int i = 0; i < 8; ++i) s2[i] = (f32x2){0.f, 0.f};

    struct P { f32x4 e[4], r[4], k[4], q[4], bb[4]; float vv; };
    P PA, PB;
    const int NCH = T / SCH;

    stage(0, 0);
    asm volatile("s_waitcnt vmcnt(0)" ::: "memory");
    __builtin_amdgcn_sched_barrier(0);

    for (int c = 0; c < NCH; ++c) {
        if (c + 1 < NCH) stage(c + 1, (c + 1) & 1);

        const float* L = &lds[c & 1][0];
        auto PRE = [&](P& pp, int tt) {
            const int o = tt * 64 + kb;
            #pragma unroll
            for (int j = 0; j < 4; ++j) {
                pp.e[j]  = *(const f32x4*)(L + 0 * SCH * 64 + o + j * 4);
                pp.r[j]  = *(const f32x4*)(L + 1 * SCH * 64 + o + j * 4);
                pp.k[j]  = *(const f32x4*)(L + 2 * SCH * 64 + o + j * 4);
                pp.q[j]  = *(const f32x4*)(L + 3 * SCH * 64 + o + j * 4);
                pp.bb[j] = *(const f32x4*)(L + 4 * SCH * 64 + o + j * 4);
            }
            pp.vv = L[5 * SCH * 64 + tt * 16 + vc];
        };
        auto COMP = [&](const P& pp, int tt) {
            f32x2 sa0 = (f32x2){0.f, 0.f}, sa1 = (f32x2){0.f, 0.f};
            #pragma unroll
            for (int j = 0; j < 4; ++j) {
                const f32x2 elo = __builtin_shufflevector(pp.e[j], pp.e[j], 0, 1);
                const f32x2 ehi = __builtin_shufflevector(pp.e[j], pp.e[j], 2, 3);
                const f32x2 qlo = __builtin_shufflevector(pp.q[j], pp.q[j], 0, 1);
                const f32x2 qhi = __builtin_shufflevector(pp.q[j], pp.q[j], 2, 3);
                s2[2*j]   *= elo;
                s2[2*j+1] *= ehi;
                sa0 += qlo * s2[2*j];
                sa1 += qhi * s2[2*j+1];
            }
            const f32x2 sas = sa0 + sa1;
            float p = -(sas.x + sas.y);
            p = red32(red16(p));
            const f32x2 p2 = (f32x2){p, p};
            const f32x2 v2 = (f32x2){pp.vv, pp.vv};
            f32x2 o0 = (f32x2){0.f, 0.f}, o1 = (f32x2){0.f, 0.f};
            #pragma unroll
            for (int j = 0; j < 4; ++j) {
                const f32x2 klo = __builtin_shufflevector(pp.k[j], pp.k[j], 0, 1);
                const f32x2 khi = __builtin_shufflevector(pp.k[j], pp.k[j], 2, 3);
                const f32x2 blo = __builtin_shufflevector(pp.bb[j], pp.bb[j], 0, 1);
                const f32x2 bhi = __builtin_shufflevector(pp.bb[j], pp.bb[j], 2, 3);
                const f32x2 rlo = __builtin_shufflevector(pp.r[j], pp.r[j], 0, 1);
                const f32x2 rhi = __builtin_shufflevector(pp.r[j], pp.r[j], 2, 3);
                s2[2*j]   = blo * p2 + (klo * v2 + s2[2*j]);
                s2[2*j+1] = bhi * p2 + (khi * v2 + s2[2*j+1]);
                o0 += rlo * s2[2*j];
                o1 += rhi * s2[2*j+1];
            }
            const f32x2 os = o0 + o1;
            float oo = os.x + os.y;
            oo = red32(red16(oo));
            if (g == 0)
                O[base0 + (size_t)(c * SCH + tt) * step + vb0 + vc] = oo;
        };

        PRE(PA, 0);
        PRE(PB, 1);
        #pragma unroll
        for (int tt = 0; tt < SCH - 2; tt += 2) {
            COMP(PA, tt);     PRE(PA, tt + 2);
            COMP(PB, tt + 1); PRE(PB, tt + 3);
        }
        COMP(PA, SCH - 2);
        COMP(PB, SCH - 1);

        asm volatile("s_waitcnt vmcnt(0)" ::: "memory");
        __builtin_amdgcn_sched_barrier(0);
    }
}

// GroupNorm + bonus + precomputed g-gate (coalesced). One wave per (b,t,h).
__global__ __launch_bounds__(256) void gn_bonus(
    const float* __restrict__ O, const float* __restrict__ R,
    const float* __restrict__ Kf, const float* __restrict__ Vf,
    const float* __restrict__ G, const float* __restrict__ r_k,
    const float* __restrict__ gn_w, const float* __restrict__ gn_b,
    float* __restrict__ ON, int total, int H, float eps)
{
    int wid = (blockIdx.x << 2) | (threadIdx.x >> 6);
    if (wid >= total) return;
    const int l = threadIdx.x & 63;
    const int h = wid % H;
    const int ch = h * 64 + l;
    const size_t base = (size_t)wid * 64;

    const float o = O[base + l];
    float sum = o;
    #pragma unroll
    for (int off = 1; off < 64; off <<= 1) sum += __shfl_xor(sum, off, 64);
    const float mu = sum * (1.f / 64.f);
    const float d = o - mu;
    float ss = d * d;
    #pragma unroll
    for (int off = 1; off < 64; off <<= 1) ss += __shfl_xor(ss, off, 64);
    const float inv = 1.f / sqrtf(ss * (1.f / 64.f) + eps);
    float on = d * inv * gn_w[ch] + gn_b[ch];

    const float r = R[base + l], k = Kf[base + l], vv = Vf[base + l];
    float p = r * k * r_k[ch];
    #pragma unroll
    for (int off = 1; off < 64; off <<= 1) p += __shfl_xor(p, off, 64);
    on = fmaf(p, vv, on);
    ON[base + l] = on * G[base + l];
}

extern "C" void kernel_launch(void* const* d_in, const int* in_sizes, int n_in,
                              void* d_out, int out_size, void* d_ws, size_t ws_size,
                              hipStream_t stream)
{
    const int B = 2, T = 2048, D = 2048, H = 32;
    const int M = B * T;

    const float* hid = (const float*)d_in[0];
    const float* vst = (const float*)d_in[1];
    const float* x_x = (const float*)d_in[2];
    const float* k_k = (const float*)d_in[3];
    const float* k_a = (const float*)d_in[4];
    const float* r_k = (const float*)d_in[5];
    const float* Wr  = (const float*)d_in[6];
    const float* Wk  = (const float*)d_in[7];
    const float* Wv  = (const float*)d_in[8];
    const float* Wo  = (const float*)d_in[9];
    const float* wA  = (const float*)d_in[10];
    const float* wB  = (const float*)d_in[11];
    const float* wb  = (const float*)d_in[12];
    const float* vA  = (const float*)d_in[13];
    const float* vB  = (const float*)d_in[14];
    const float* vb  = (const float*)d_in[15];
    const float* aA  = (const float*)d_in[16];
    const float* aB  = (const float*)d_in[17];
    const float* ab  = (const float*)d_in[18];
    const float* gA  = (const float*)d_in[19];
    const float* gB  = (const float*)d_in[20];
    const float* gnw = (const float*)d_in[21];
    const float* gnb = (const float*)d_in[22];
    float* out = (float*)d_out;

    const size_t NE = (size_t)M * D;   // 8,388,608
    const size_t DD = (size_t)D * D;   // 4,194,304
    const size_t need = (6 * NE + (size_t)M * 272) * sizeof(float);  // ~196 MiB (proven)
    if (ws_size < need) return;

    float* R_  = (float*)d_ws;
    float* EW  = R_  + NE;
    float* Kf  = EW  + NE;
    float* Vf  = Kf  + NE;
    float* KK  = Vf  + NE;
    float* ABV = KK  + NE;
    float* HW  = ABV + NE;
    float* HV  = HW + (size_t)M * 64;
    float* HA  = HV + (size_t)M * 16;
    float* HG  = HA + (size_t)M * 64;

    dim3 blk(256);
    dim3 gDual(M / GBM, D / GBN);
    const int nMix = (int)(NE / 8);
    const int nW   = (int)(DD / 8);
    const float* nf = nullptr;

    unsigned short* XHi = (unsigned short*)EW;
    unsigned short* XLo = XHi + NE;
    unsigned short* WHi = (unsigned short*)KK;
    unsigned short* WLo = WHi + DD;

    // ---- phase 1: fused LoRA stage-1 (acts in epilogue) ----
    hipLaunchKernelGGL(lora1, dim3(M / BM, 5), blk, 0, stream,
                       hid, x_x, wA, vA, aA, gA, HW, HV, HA, HG, M, D, T);

    // ---- phase 2: yv -> ABV ----
    hipLaunchKernelGGL(gemm_f32, dim3(M / BM, D / BN), blk, 0, stream, HV, nf, vB, ABV, M, D, 16, T, 0, nf);

    // ---- phase 3: R/K/V projections via split MFMA ----
    hipLaunchKernelGGL(mixsplit, dim3(nMix / 256), blk, 0, stream, hid, x_x + 0 * (size_t)D, XHi, XLo, T, D, nMix, 1);
    hipLaunchKernelGGL(mixsplit, dim3(nW / 256), blk, 0, stream, Wr, nf, WHi, WLo, T, D, nW, 0);
    hipLaunchKernelGGL(gemm_dual, gDual, blk, 0, stream, XHi, XLo, WHi, WLo, R_, M, D, D, 0, nf, nf, nf);

    hipLaunchKernelGGL(mixsplit, dim3(nMix / 256), blk, 0, stream, hid, x_x + 2 * (size_t)D, XHi, XLo, T, D, nMix, 1);
    hipLaunchKernelGGL(mixsplit, dim3(nW / 256), blk, 0, stream, Wk, nf, WHi, WLo, T, D, nW, 0);
    hipLaunchKernelGGL(gemm_dual, gDual, blk, 0, stream, XHi, XLo, WHi, WLo, Kf, M, D, D, 0, nf, nf, nf);

    hipLaunchKernelGGL(mixsplit, dim3(nMix / 256), blk, 0, stream, hid, x_x + 3 * (size_t)D, XHi, XLo, T, D, nMix, 1);
    hipLaunchKernelGGL(mixsplit, dim3(nW / 256), blk, 0, stream, Wv, nf, WHi, WLo, T, D, nW, 0);
    hipLaunchKernelGGL(gemm_dual, gDual, blk, 0, stream, XHi, XLo, WHi, WLo, Vf, M, D, D, 2, ABV, vb, vst);

    // ---- phase 4: LoRA stage-2 ----
    hipLaunchKernelGGL(gemm_f32, dim3(M / BM, D / BN), blk, 0, stream, HW, nf, wB, EW,  M, D, 64, T, 1, wb);
    hipLaunchKernelGGL(gemm_f32, dim3(M / BM, D / BN), blk, 0, stream, HA, nf, aB, ABV, M, D, 64, T, 0, nf);

    // ---- phase 5: ka epilogue ----
    const int totalW = M * H;
    hipLaunchKernelGGL(ka_epi, dim3(totalW / 4), blk, 0, stream, Kf, ABV, KK, k_k, k_a, ab, totalW, H);

    // ---- phase 6: scan -> d_out (256 single-wave blocks) ----
    hipLaunchKernelGGL(rwkv_scan, dim3(B * H * 4), dim3(64), 0, stream, EW, R_, Kf, Vf, KK, ABV, out, T, H);

    // ---- phase 7: g-gate GEMM (into dead KK window) + GroupNorm/bonus -> EW ----
    float* G_ = KK;   // kk consumed by scan; reused for G = HG @ gB^T
    hipLaunchKernelGGL(gemm_f32, dim3(M / BM, D / BN), blk, 0, stream, HG, nf, gB, G_, M, D, 128, T, 0, nf);
    hipLaunchKernelGGL(gn_bonus, dim3(totalW / 4), blk, 0, stream, out, R_, Kf, Vf, G_, r_k, gnw, gnb, EW, totalW, H, 64.f * 1e-5f);

    // ---- phase 8: Wo projection -> d_out ----
    unsigned short* XHi2 = (unsigned short*)KK;
    unsigned short* XLo2 = XHi2 + NE;
    unsigned short* WHi2 = (unsigned short*)ABV;
    unsigned short* WLo2 = WHi2 + DD;
    hipLaunchKernelGGL(mixsplit, dim3(nMix / 256), blk, 0, stream, EW, nf, XHi2, XLo2, T, D, nMix, 0);
    hipLaunchKernelGGL(mixsplit, dim3(nW / 256), blk, 0, stream, Wo, nf, WHi2, WLo2, T, D, nW, 0);
    hipLaunchKernelGGL(gemm_dual, gDual, blk, 0, stream, XHi2, XLo2, WHi2, WLo2, out, M, D, D, 0, nf, nf, nf);
}

// Round 12
// 1219.006 us; speedup vs baseline: 4.5556x; 1.0693x over previous
//
#include <hip/hip_runtime.h>
#include <hip/hip_bf16.h>
#include <math.h>

// RWKV7 attention, round 12:
//  - rwkv_scan: 8 v-slabs of 8 cols -> grid 512 (2 single-wave blocks/CU).
//    Lane owns 8 k (g=l>>3): 11 DS reads/step (was 21). Reduction = DPP
//    row_ror:8 (xor-8) + permlane16 + permlane32, all VALU (no DS wait on chain).
// Other kernels identical to round 11.

typedef __attribute__((ext_vector_type(8))) unsigned short ushort8;
typedef __attribute__((ext_vector_type(8))) short bf16x8;
typedef __attribute__((ext_vector_type(4))) float f32x4;
typedef __attribute__((ext_vector_type(2))) float f32x2;

__device__ inline float b2f(unsigned short u) {
    union { unsigned int u; float f; } x; x.u = ((unsigned int)u) << 16; return x.f;
}
__device__ inline unsigned short f2b(float f) {
    union { float f; unsigned int u; } x; x.f = f;
    return (unsigned short)((x.u + 0x7FFF + ((x.u >> 16) & 1)) >> 16);
}
__device__ inline float sigm(float x) { return 1.f / (1.f + expf(-x)); }

// VALU cross-lane reductions. permlane swaps need DISTINCT registers (r9 lesson:
// aliased operands -> swap(v0,v0) miscompile); DPP row_ror:8 gives lane^8 within
// each 16-lane row ((l+8) mod 16 == l^8).
__device__ __forceinline__ float red8(float x) {
    int xi = __builtin_bit_cast(int, x);
    int yi = __builtin_amdgcn_update_dpp(xi, xi, 0x128 /*row_ror:8*/, 0xf, 0xf, true);
    return x + __builtin_bit_cast(float, yi);
}
__device__ __forceinline__ float red16(float x) {
    float b = x;
    asm("" : "+v"(b));
    float a = x;
    asm("v_permlane16_swap_b32 %0, %1" : "+v"(a), "+v"(b));
    return a + b;
}
__device__ __forceinline__ float red32(float x) {
    float b = x;
    asm("" : "+v"(b));
    float a = x;
    asm("v_permlane32_swap_b32 %0, %1" : "+v"(a), "+v"(b));
    return a + b;
}

// async global -> LDS. LDS dest = uniform base + lane*size.
__device__ __forceinline__ void gld16(void* lds, const void* g)
{
    __builtin_amdgcn_global_load_lds(
        (const __attribute__((address_space(1))) void*)g,
        (__attribute__((address_space(3))) void*)lds, 16, 0, 0);
}
__device__ __forceinline__ void gld4(void* lds, const void* g)
{
    __builtin_amdgcn_global_load_lds(
        (const __attribute__((address_space(1))) void*)g,
        (__attribute__((address_space(3))) void*)lds, 4, 0, 0);
}

// ---------------- split pass: out_hi/lo = bf16 split of (optionally mixed) f32 ----------------
__global__ void mixsplit(const float* __restrict__ in, const float* __restrict__ xxr,
                         unsigned short* __restrict__ hi, unsigned short* __restrict__ lo,
                         int T, int D, int total8, int domix)
{
    int i = blockIdx.x * 256 + threadIdx.x;
    if (i >= total8) return;
    const size_t e = (size_t)i * 8;
    float a[8];
    *(float4*)&a[0] = *(const float4*)(in + e);
    *(float4*)&a[4] = *(const float4*)(in + e + 4);
    if (domix) {
        const int m = (int)(e / D);
        const int d = (int)(e % D);
        const int t = m % T;
        float p[8] = {0.f,0.f,0.f,0.f,0.f,0.f,0.f,0.f};
        if (t > 0) {
            *(float4*)&p[0] = *(const float4*)(in + e - D);
            *(float4*)&p[4] = *(const float4*)(in + e - D + 4);
        }
        float xv[8];
        *(float4*)&xv[0] = *(const float4*)(xxr + d);
        *(float4*)&xv[4] = *(const float4*)(xxr + d + 4);
        #pragma unroll
        for (int j = 0; j < 8; ++j) a[j] += (p[j] - a[j]) * xv[j];
    }
    ushort8 h8, l8;
    #pragma unroll
    for (int j = 0; j < 8; ++j) {
        const unsigned short h = f2b(a[j]);
        h8[j] = h;
        l8[j] = f2b(a[j] - b2f(h));
    }
    *(ushort8*)(hi + e) = h8;
    *(ushort8*)(lo + e) = l8;
}

// ---------------- dual (hi+lo) bf16 MFMA GEMM: C[M,N] = A[M,K] @ W[N,K]^T, f32 out --------
#define GBM 128
#define GBN 128

__global__ __launch_bounds__(256) void gemm_dual(
    const unsigned short* __restrict__ Ahg, const unsigned short* __restrict__ Alg,
    const unsigned short* __restrict__ Bhg, const unsigned short* __restrict__ Blg,
    float* __restrict__ C, int M, int N, int K, int mode,
    const float* __restrict__ yv, const float* __restrict__ bias,
    const float* __restrict__ aux)
{
    __shared__ unsigned short Ah[GBM * 32], Al[GBM * 32];
    __shared__ unsigned short Bh[GBN * 32], Bl[GBN * 32];
    const int tid = threadIdx.x;
    const int m0 = blockIdx.x * GBM;
    const int n0 = blockIdx.y * GBN;
    const int wave = tid >> 6, lane = tid & 63;
    const int wr = (wave >> 1) * 64, wc = (wave & 1) * 64;
    const int fr = lane & 15, fq = lane >> 4;

    f32x4 acc[4][4];
    #pragma unroll
    for (int i = 0; i < 4; ++i)
        #pragma unroll
        for (int j = 0; j < 4; ++j)
            acc[i][j] = (f32x4){0.f, 0.f, 0.f, 0.f};

    const unsigned short* gsrc = (wave == 0) ? Ahg : (wave == 1) ? Alg : (wave == 2) ? Bhg : Blg;
    unsigned short* lbuf = (wave == 0) ? Ah : (wave == 1) ? Al : (wave == 2) ? Bh : Bl;
    const int tile0 = (wave < 2) ? m0 : n0;
    const unsigned short* gbase = gsrc + (size_t)(tile0 + (lane >> 2)) * K + ((lane & 3) << 3);

    for (int k0 = 0; k0 < K; k0 += 32) {
        #pragma unroll
        for (int j = 0; j < 8; ++j)
            gld16(lbuf + j * 16 * 32, gbase + (size_t)(j * 16) * K + k0);
        __syncthreads();

        bf16x8 fah[4], fal[4], fbh[4], fbl[4];
        #pragma unroll
        for (int m = 0; m < 4; ++m) {
            fah[m] = *(const bf16x8*)&Ah[(wr + m * 16 + fr) * 32 + fq * 8];
            fal[m] = *(const bf16x8*)&Al[(wr + m * 16 + fr) * 32 + fq * 8];
        }
        #pragma unroll
        for (int n = 0; n < 4; ++n) {
            fbh[n] = *(const bf16x8*)&Bh[(wc + n * 16 + fr) * 32 + fq * 8];
            fbl[n] = *(const bf16x8*)&Bl[(wc + n * 16 + fr) * 32 + fq * 8];
        }
        #pragma unroll
        for (int m = 0; m < 4; ++m)
            #pragma unroll
            for (int n = 0; n < 4; ++n) {
                acc[m][n] = __builtin_amdgcn_mfma_f32_16x16x32_bf16(fah[m], fbh[n], acc[m][n], 0, 0, 0);
                acc[m][n] = __builtin_amdgcn_mfma_f32_16x16x32_bf16(fah[m], fbl[n], acc[m][n], 0, 0, 0);
                acc[m][n] = __builtin_amdgcn_mfma_f32_16x16x32_bf16(fal[m], fbh[n], acc[m][n], 0, 0, 0);
            }
        __syncthreads();
    }

    #pragma unroll
    for (int m = 0; m < 4; ++m) {
        const int row = m0 + wr + m * 16 + fq * 4;
        #pragma unroll
        for (int n = 0; n < 4; ++n) {
            const int col = n0 + wc + n * 16 + fr;
            #pragma unroll
            for (int j = 0; j < 4; ++j) {
                const size_t idx = (size_t)(row + j) * N + col;
                float v = acc[m][n][j];
                if (mode == 2) {
                    const float sg = sigm(yv[idx] + bias[col]);
                    v = v + sg * (aux[idx] - v);
                }
                C[idx] = v;
            }
        }
    }
}

// ---------------- f32 SIMD GEMM (LoRA stage-2, g-gate) ----------------
#define BM 64
#define BN 64
#define BK 16
__global__ __launch_bounds__(256) void gemm_f32(
    const float* __restrict__ A, const float* __restrict__ xx,
    const float* __restrict__ W, float* __restrict__ C,
    int M, int N, int K, int T, int mode, const float* __restrict__ bias)
{
    __shared__ float As[BK][BM + 4];
    __shared__ float Bs[BK][BN + 4];
    const int tid = threadIdx.x;
    const int m0 = blockIdx.x * BM;
    const int n0 = blockIdx.y * BN;
    const int lr = tid >> 2;
    const int lk = (tid & 3) << 2;
    const int tx = tid & 15;
    const int ty = tid >> 4;
    const int mrow = m0 + lr;
    const int nrow = n0 + lr;
    float acc[4][4];
    #pragma unroll
    for (int i = 0; i < 4; ++i)
        #pragma unroll
        for (int j = 0; j < 4; ++j) acc[i][j] = 0.f;

    for (int k0 = 0; k0 < K; k0 += BK) {
        const float* ap = A + (size_t)mrow * K + k0 + lk;
        float4 av = *(const float4*)ap;
        if (xx) {
            const int t = mrow % T;
            float4 pv = make_float4(0.f, 0.f, 0.f, 0.f);
            if (t > 0) pv = *(const float4*)(ap - K);
            const float4 xv = *(const float4*)(xx + k0 + lk);
            av.x += (pv.x - av.x) * xv.x;
            av.y += (pv.y - av.y) * xv.y;
            av.z += (pv.z - av.z) * xv.z;
            av.w += (pv.w - av.w) * xv.w;
        }
        float4 bv = make_float4(0.f, 0.f, 0.f, 0.f);
        if (nrow < N) bv = *(const float4*)(W + (size_t)nrow * K + k0 + lk);

        As[lk + 0][lr] = av.x; As[lk + 1][lr] = av.y;
        As[lk + 2][lr] = av.z; As[lk + 3][lr] = av.w;
        Bs[lk + 0][lr] = bv.x; Bs[lk + 1][lr] = bv.y;
        Bs[lk + 2][lr] = bv.z; Bs[lk + 3][lr] = bv.w;
        __syncthreads();

        #pragma unroll
        for (int kk = 0; kk < BK; ++kk) {
            const float4 a4 = *(const float4*)&As[kk][ty << 2];
            const float4 b4 = *(const float4*)&Bs[kk][tx << 2];
            const float a[4] = {a4.x, a4.y, a4.z, a4.w};
            const float b[4] = {b4.x, b4.y, b4.z, b4.w};
            #pragma unroll
            for (int i = 0; i < 4; ++i)
                #pragma unroll
                for (int j = 0; j < 4; ++j)
                    acc[i][j] = fmaf(a[i], b[j], acc[i][j]);
        }
        __syncthreads();
    }
    #pragma unroll
    for (int i = 0; i < 4; ++i) {
        const int m = m0 + (ty << 2) + i;
        #pragma unroll
        for (int j = 0; j < 4; ++j) {
            const int n = n0 + (tx << 2) + j;
            if (n < N) {
                const size_t idx = (size_t)m * N + n;
                float v = acc[i][j];
                if (mode == 1) v = 0.6065306597126334f * sigm(v + bias[n]);
                C[idx] = v;
            }
        }
    }
}

// ---------------- fused LoRA stage-1: 4 GEMMs in one launch, act in epilogue ------------
__global__ __launch_bounds__(256) void lora1(
    const float* __restrict__ hid, const float* __restrict__ x_x,
    const float* __restrict__ wA, const float* __restrict__ vA,
    const float* __restrict__ aA, const float* __restrict__ gA,
    float* __restrict__ HW, float* __restrict__ HV,
    float* __restrict__ HA, float* __restrict__ HG,
    int M, int K, int T)
{
    __shared__ float As[BK][BM + 4];
    __shared__ float Bs[BK][BN + 4];
    const int y = blockIdx.y;
    const float* W; const float* xx; float* C; int NL, act, nofs, nvalid;
    if (y == 0)      { W = wA; xx = x_x + 1 * (size_t)K; C = HW; NL = 64;  act = 1; nofs = 0;  nvalid = 64; }
    else if (y == 1) { W = vA; xx = x_x + 3 * (size_t)K; C = HV; NL = 16;  act = 0; nofs = 0;  nvalid = 16; }
    else if (y == 2) { W = aA; xx = x_x + 4 * (size_t)K; C = HA; NL = 64;  act = 0; nofs = 0;  nvalid = 64; }
    else             { W = gA + (size_t)(y - 3) * 64 * K; xx = x_x + 5 * (size_t)K; C = HG; NL = 128; act = 2; nofs = (y - 3) * 64; nvalid = 64; }

    const int tid = threadIdx.x;
    const int m0 = blockIdx.x * BM;
    const int lr = tid >> 2;
    const int lk = (tid & 3) << 2;
    const int tx = tid & 15;
    const int ty = tid >> 4;
    const int mrow = m0 + lr;
    float acc[4][4];
    #pragma unroll
    for (int i = 0; i < 4; ++i)
        #pragma unroll
        for (int j = 0; j < 4; ++j) acc[i][j] = 0.f;

    for (int k0 = 0; k0 < K; k0 += BK) {
        const float* ap = hid + (size_t)mrow * K + k0 + lk;
        float4 av = *(const float4*)ap;
        {
            const int t = mrow % T;
            float4 pv = make_float4(0.f, 0.f, 0.f, 0.f);
            if (t > 0) pv = *(const float4*)(ap - K);
            const float4 xv = *(const float4*)(xx + k0 + lk);
            av.x += (pv.x - av.x) * xv.x;
            av.y += (pv.y - av.y) * xv.y;
            av.z += (pv.z - av.z) * xv.z;
            av.w += (pv.w - av.w) * xv.w;
        }
        float4 bv = make_float4(0.f, 0.f, 0.f, 0.f);
        if (lr < nvalid) bv = *(const float4*)(W + (size_t)lr * K + k0 + lk);

        As[lk + 0][lr] = av.x; As[lk + 1][lr] = av.y;
        As[lk + 2][lr] = av.z; As[lk + 3][lr] = av.w;
        Bs[lk + 0][lr] = bv.x; Bs[lk + 1][lr] = bv.y;
        Bs[lk + 2][lr] = bv.z; Bs[lk + 3][lr] = bv.w;
        __syncthreads();

        #pragma unroll
        for (int kk = 0; kk < BK; ++kk) {
            const float4 a4 = *(const float4*)&As[kk][ty << 2];
            const float4 b4 = *(const float4*)&Bs[kk][tx << 2];
            const float a[4] = {a4.x, a4.y, a4.z, a4.w};
            const float b[4] = {b4.x, b4.y, b4.z, b4.w};
            #pragma unroll
            for (int i = 0; i < 4; ++i)
                #pragma unroll
                for (int j = 0; j < 4; ++j)
                    acc[i][j] = fmaf(a[i], b[j], acc[i][j]);
        }
        __syncthreads();
    }
    #pragma unroll
    for (int i = 0; i < 4; ++i) {
        const int m = m0 + (ty << 2) + i;
        #pragma unroll
        for (int j = 0; j < 4; ++j) {
            const int n = (tx << 2) + j;
            if (n < nvalid) {
                float v = acc[i][j];
                if (act == 1) v = tanhf(v);
                else if (act == 2) v = sigm(v);
                C[(size_t)m * NL + nofs + n] = v;
            }
        }
    }
}

// per-(b,t,h) wave: a = sigmoid(ya+ab); kk = normalize(k0*k_k); bv = kk*a;
// kfinal = k0*(1+(a-1)*k_a)
__global__ __launch_bounds__(256) void ka_epi(
    float* __restrict__ Kf, float* __restrict__ A_BV, float* __restrict__ KKo,
    const float* __restrict__ k_k, const float* __restrict__ k_a,
    const float* __restrict__ ab, int total, int H)
{
    int wid = (blockIdx.x << 2) | (threadIdx.x >> 6);
    if (wid >= total) return;
    const int l = threadIdx.x & 63;
    const int h = wid % H;
    const int ch = h * 64 + l;
    const size_t base = (size_t)wid * 64;
    float k0 = Kf[base + l];
    float a = sigm(A_BV[base + l] + ab[ch]);
    float kkr = k0 * k_k[ch];
    float ss = kkr * kkr;
    #pragma unroll
    for (int off = 1; off < 64; off <<= 1) ss += __shfl_xor(ss, off, 64);
    float inv = 1.f / fmaxf(sqrtf(ss), 1e-12f);
    float kkn = kkr * inv;
    KKo[base + l] = kkn;
    A_BV[base + l] = kkn * a;
    Kf[base + l] = k0 * fmaf(a - 1.f, k_a[ch], 1.f);
}

// DPLR scan v6. ONE wave per block; grid = B*H*8 = 512 (2 blocks/CU).
// Block (b,h,slab): 8 v-cols [slab*8, +8). Lane l: vc = l&7, g = l>>3,
// owns k in [g*8, +8) -> state s2[4] (f32x2). Chunks staged via global_load_lds.
// sa reduce = red8 (DPP ror8) + red16 + red32, all VALU.
#define SCH 16
__global__ __launch_bounds__(64) void rwkv_scan(
    const float* __restrict__ EW, const float* __restrict__ R,
    const float* __restrict__ Kf, const float* __restrict__ Vf,
    const float* __restrict__ KK, const float* __restrict__ BV,
    float* __restrict__ O, int T, int H)
{
    __shared__ float lds[2][5 * SCH * 64 + SCH * 8];

    const int blk = blockIdx.x;
    const int bh = blk & 63;               // slab-siblings 64 apart -> same XCD
    const int slab = blk >> 6;             // 0..7
    const int b = bh >> 5, h = bh & 31;
    const int l = threadIdx.x;
    const int vc = l & 7;
    const int g  = l >> 3;
    const int kb = g << 3;
    const int vb0 = slab << 3;
    const size_t step = (size_t)H * 64;
    const size_t base0 = ((size_t)b * T * H + h) * 64;

    auto stage = [&](int c, int buf) {
        float* L = &lds[buf][0];
        const size_t t0 = (size_t)c * SCH;
        const float* gs[5] = {EW, R, Kf, KK, BV};
        #pragma unroll
        for (int s = 0; s < 5; ++s) {
            const float* gp = gs[s];
            #pragma unroll
            for (int j = 0; j < 4; ++j)
                gld16(L + s * SCH * 64 + j * 4 * 64,
                      gp + base0 + (t0 + j * 4 + (l >> 4)) * step + ((l & 15) << 2));
        }
        // V slab: [SCH][8] floats = 128 = two size-4 waves
        gld4(L + 5 * SCH * 64,
             Vf + base0 + (t0 + (l >> 3)) * step + vb0 + (l & 7));
        gld4(L + 5 * SCH * 64 + 64,
             Vf + base0 + (t0 + 8 + (l >> 3)) * step + vb0 + (l & 7));
    };

    f32x2 s2[4];
    #pragma unroll
    for (int i = 0; i < 4; ++i) s2[i] = (f32x2){0.f, 0.f};

    struct P { f32x4 e[2], r[2], k[2], q[2], bb[2]; float vv; };
    P PA, PB;
    const int NCH = T / SCH;

    stage(0, 0);
    asm volatile("s_waitcnt vmcnt(0)" ::: "memory");
    __builtin_amdgcn_sched_barrier(0);

    for (int c = 0; c < NCH; ++c) {
        if (c + 1 < NCH) stage(c + 1, (c + 1) & 1);

        const float* L = &lds[c & 1][0];
        auto PRE = [&](P& pp, int tt) {
            const int o = tt * 64 + kb;
            #pragma unroll
            for (int j = 0; j < 2; ++j) {
                pp.e[j]  = *(const f32x4*)(L + 0 * SCH * 64 + o + j * 4);
                pp.r[j]  = *(const f32x4*)(L + 1 * SCH * 64 + o + j * 4);
                pp.k[j]  = *(const f32x4*)(L + 2 * SCH * 64 + o + j * 4);
                pp.q[j]  = *(const f32x4*)(L + 3 * SCH * 64 + o + j * 4);
                pp.bb[j] = *(const f32x4*)(L + 4 * SCH * 64 + o + j * 4);
            }
            pp.vv = L[5 * SCH * 64 + tt * 8 + vc];
        };
        auto COMP = [&](const P& pp, int tt) {
            f32x2 sa0 = (f32x2){0.f, 0.f}, sa1 = (f32x2){0.f, 0.f};
            #pragma unroll
            for (int j = 0; j < 2; ++j) {
                const f32x2 elo = __builtin_shufflevector(pp.e[j], pp.e[j], 0, 1);
                const f32x2 ehi = __builtin_shufflevector(pp.e[j], pp.e[j], 2, 3);
                const f32x2 qlo = __builtin_shufflevector(pp.q[j], pp.q[j], 0, 1);
                const f32x2 qhi = __builtin_shufflevector(pp.q[j], pp.q[j], 2, 3);
                s2[2*j]   *= elo;
                s2[2*j+1] *= ehi;
                sa0 += qlo * s2[2*j];
                sa1 += qhi * s2[2*j+1];
            }
            const f32x2 sas = sa0 + sa1;
            float p = -(sas.x + sas.y);
            p = red32(red16(red8(p)));              // VALU-only reduction
            const f32x2 p2 = (f32x2){p, p};
            const f32x2 v2 = (f32x2){pp.vv, pp.vv};
            f32x2 o0 = (f32x2){0.f, 0.f}, o1 = (f32x2){0.f, 0.f};
            #pragma unroll
            for (int j = 0; j < 2; ++j) {
                const f32x2 klo = __builtin_shufflevector(pp.k[j], pp.k[j], 0, 1);
                const f32x2 khi = __builtin_shufflevector(pp.k[j], pp.k[j], 2, 3);
                const f32x2 blo = __builtin_shufflevector(pp.bb[j], pp.bb[j], 0, 1);
                const f32x2 bhi = __builtin_shufflevector(pp.bb[j], pp.bb[j], 2, 3);
                const f32x2 rlo = __builtin_shufflevector(pp.r[j], pp.r[j], 0, 1);
                const f32x2 rhi = __builtin_shufflevector(pp.r[j], pp.r[j], 2, 3);
                s2[2*j]   = blo * p2 + (klo * v2 + s2[2*j]);
                s2[2*j+1] = bhi * p2 + (khi * v2 + s2[2*j+1]);
                o0 += rlo * s2[2*j];
                o1 += rhi * s2[2*j+1];
            }
            const f32x2 os = o0 + o1;
            float oo = os.x + os.y;
            oo = red32(red16(red8(oo)));
            if (g == 0)
                O[base0 + (size_t)(c * SCH + tt) * step + vb0 + vc] = oo;
        };

        PRE(PA, 0);
        PRE(PB, 1);
        #pragma unroll
        for (int tt = 0; tt < SCH - 2; tt += 2) {
            COMP(PA, tt);     PRE(PA, tt + 2);
            COMP(PB, tt + 1); PRE(PB, tt + 3);
        }
        COMP(PA, SCH - 2);
        COMP(PB, SCH - 1);

        asm volatile("s_waitcnt vmcnt(0)" ::: "memory");
        __builtin_amdgcn_sched_barrier(0);
    }
}

// GroupNorm + bonus + precomputed g-gate (coalesced). One wave per (b,t,h).
__global__ __launch_bounds__(256) void gn_bonus(
    const float* __restrict__ O, const float* __restrict__ R,
    const float* __restrict__ Kf, const float* __restrict__ Vf,
    const float* __restrict__ G, const float* __restrict__ r_k,
    const float* __restrict__ gn_w, const float* __restrict__ gn_b,
    float* __restrict__ ON, int total, int H, float eps)
{
    int wid = (blockIdx.x << 2) | (threadIdx.x >> 6);
    if (wid >= total) return;
    const int l = threadIdx.x & 63;
    const int h = wid % H;
    const int ch = h * 64 + l;
    const size_t base = (size_t)wid * 64;

    const float o = O[base + l];
    float sum = o;
    #pragma unroll
    for (int off = 1; off < 64; off <<= 1) sum += __shfl_xor(sum, off, 64);
    const float mu = sum * (1.f / 64.f);
    const float d = o - mu;
    float ss = d * d;
    #pragma unroll
    for (int off = 1; off < 64; off <<= 1) ss += __shfl_xor(ss, off, 64);
    const float inv = 1.f / sqrtf(ss * (1.f / 64.f) + eps);
    float on = d * inv * gn_w[ch] + gn_b[ch];

    const float r = R[base + l], k = Kf[base + l], vv = Vf[base + l];
    float p = r * k * r_k[ch];
    #pragma unroll
    for (int off = 1; off < 64; off <<= 1) p += __shfl_xor(p, off, 64);
    on = fmaf(p, vv, on);
    ON[base + l] = on * G[base + l];
}

extern "C" void kernel_launch(void* const* d_in, const int* in_sizes, int n_in,
                              void* d_out, int out_size, void* d_ws, size_t ws_size,
                              hipStream_t stream)
{
    const int B = 2, T = 2048, D = 2048, H = 32;
    const int M = B * T;

    const float* hid = (const float*)d_in[0];
    const float* vst = (const float*)d_in[1];
    const float* x_x = (const float*)d_in[2];
    const float* k_k = (const float*)d_in[3];
    const float* k_a = (const float*)d_in[4];
    const float* r_k = (const float*)d_in[5];
    const float* Wr  = (const float*)d_in[6];
    const float* Wk  = (const float*)d_in[7];
    const float* Wv  = (const float*)d_in[8];
    const float* Wo  = (const float*)d_in[9];
    const float* wA  = (const float*)d_in[10];
    const float* wB  = (const float*)d_in[11];
    const float* wb  = (const float*)d_in[12];
    const float* vA  = (const float*)d_in[13];
    const float* vB  = (const float*)d_in[14];
    const float* vb  = (const float*)d_in[15];
    const float* aA  = (const float*)d_in[16];
    const float* aB  = (const float*)d_in[17];
    const float* ab  = (const float*)d_in[18];
    const float* gA  = (const float*)d_in[19];
    const float* gB  = (const float*)d_in[20];
    const float* gnw = (const float*)d_in[21];
    const float* gnb = (const float*)d_in[22];
    float* out = (float*)d_out;

    const size_t NE = (size_t)M * D;   // 8,388,608
    const size_t DD = (size_t)D * D;   // 4,194,304
    const size_t need = (6 * NE + (size_t)M * 272) * sizeof(float);  // ~196 MiB (proven)
    if (ws_size < need) return;

    float* R_  = (float*)d_ws;
    float* EW  = R_  + NE;
    float* Kf  = EW  + NE;
    float* Vf  = Kf  + NE;
    float* KK  = Vf  + NE;
    float* ABV = KK  + NE;
    float* HW  = ABV + NE;
    float* HV  = HW + (size_t)M * 64;
    float* HA  = HV + (size_t)M * 16;
    float* HG  = HA + (size_t)M * 64;

    dim3 blk(256);
    dim3 gDual(M / GBM, D / GBN);
    const int nMix = (int)(NE / 8);
    const int nW   = (int)(DD / 8);
    const float* nf = nullptr;

    unsigned short* XHi = (unsigned short*)EW;
    unsigned short* XLo = XHi + NE;
    unsigned short* WHi = (unsigned short*)KK;
    unsigned short* WLo = WHi + DD;

    // ---- phase 1: fused LoRA stage-1 (acts in epilogue) ----
    hipLaunchKernelGGL(lora1, dim3(M / BM, 5), blk, 0, stream,
                       hid, x_x, wA, vA, aA, gA, HW, HV, HA, HG, M, D, T);

    // ---- phase 2: yv -> ABV ----
    hipLaunchKernelGGL(gemm_f32, dim3(M / BM, D / BN), blk, 0, stream, HV, nf, vB, ABV, M, D, 16, T, 0, nf);

    // ---- phase 3: R/K/V projections via split MFMA ----
    hipLaunchKernelGGL(mixsplit, dim3(nMix / 256), blk, 0, stream, hid, x_x + 0 * (size_t)D, XHi, XLo, T, D, nMix, 1);
    hipLaunchKernelGGL(mixsplit, dim3(nW / 256), blk, 0, stream, Wr, nf, WHi, WLo, T, D, nW, 0);
    hipLaunchKernelGGL(gemm_dual, gDual, blk, 0, stream, XHi, XLo, WHi, WLo, R_, M, D, D, 0, nf, nf, nf);

    hipLaunchKernelGGL(mixsplit, dim3(nMix / 256), blk, 0, stream, hid, x_x + 2 * (size_t)D, XHi, XLo, T, D, nMix, 1);
    hipLaunchKernelGGL(mixsplit, dim3(nW / 256), blk, 0, stream, Wk, nf, WHi, WLo, T, D, nW, 0);
    hipLaunchKernelGGL(gemm_dual, gDual, blk, 0, stream, XHi, XLo, WHi, WLo, Kf, M, D, D, 0, nf, nf, nf);

    hipLaunchKernelGGL(mixsplit, dim3(nMix / 256), blk, 0, stream, hid, x_x + 3 * (size_t)D, XHi, XLo, T, D, nMix, 1);
    hipLaunchKernelGGL(mixsplit, dim3(nW / 256), blk, 0, stream, Wv, nf, WHi, WLo, T, D, nW, 0);
    hipLaunchKernelGGL(gemm_dual, gDual, blk, 0, stream, XHi, XLo, WHi, WLo, Vf, M, D, D, 2, ABV, vb, vst);

    // ---- phase 4: LoRA stage-2 ----
    hipLaunchKernelGGL(gemm_f32, dim3(M / BM, D / BN), blk, 0, stream, HW, nf, wB, EW,  M, D, 64, T, 1, wb);
    hipLaunchKernelGGL(gemm_f32, dim3(M / BM, D / BN), blk, 0, stream, HA, nf, aB, ABV, M, D, 64, T, 0, nf);

    // ---- phase 5: ka epilogue ----
    const int totalW = M * H;
    hipLaunchKernelGGL(ka_epi, dim3(totalW / 4), blk, 0, stream, Kf, ABV, KK, k_k, k_a, ab, totalW, H);

    // ---- phase 6: scan -> d_out (512 single-wave blocks, 2/CU) ----
    hipLaunchKernelGGL(rwkv_scan, dim3(B * H * 8), dim3(64), 0, stream, EW, R_, Kf, Vf, KK, ABV, out, T, H);

    // ---- phase 7: g-gate GEMM (into dead KK window) + GroupNorm/bonus -> EW ----
    float* G_ = KK;
    hipLaunchKernelGGL(gemm_f32, dim3(M / BM, D / BN), blk, 0, stream, HG, nf, gB, G_, M, D, 128, T, 0, nf);
    hipLaunchKernelGGL(gn_bonus, dim3(totalW / 4), blk, 0, stream, out, R_, Kf, Vf, G_, r_k, gnw, gnb, EW, totalW, H, 64.f * 1e-5f);

    // ---- phase 8: Wo projection -> d_out ----
    unsigned short* XHi2 = (unsigned short*)KK;
    unsigned short* XLo2 = XHi2 + NE;
    unsigned short* WHi2 = (unsigned short*)ABV;
    unsigned short* WLo2 = WHi2 + DD;
    hipLaunchKernelGGL(mixsplit, dim3(nMix / 256), blk, 0, stream, EW, nf, XHi2, XLo2, T, D, nMix, 0);
    hipLaunchKernelGGL(mixsplit, dim3(nW / 256), blk, 0, stream, Wo, nf, WHi2, WLo2, T, D, nW, 0);
    hipLaunchKernelGGL(gemm_dual, gDual, blk, 0, stream, XHi2, XLo2, WHi2, WLo2, out, M, D, D, 0, nf, nf, nf);
}

// Round 13
// 1129.148 us; speedup vs baseline: 4.9181x; 1.0796x over previous
//
#include <hip/hip_runtime.h>
#include <hip/hip_bf16.h>
#include <math.h>

// RWKV7 attention, round 13:
//  - gemm_h2: fp16 2-term GEMM (A single fp16, B split hi/lo fp16; C = A*Bh + A*Bl).
//    2 MFMAs per fragment pair (was 3 bf16), A staging halved.
//  - rwkv_scan v7: SCH=8, 16 v-slabs of 4 cols, grid 1024 (4 blocks/CU),
//    reductions = DPP ror4 + ror8 + permlane16 + permlane32 (all VALU).
// Other kernels identical to round 12.

typedef __attribute__((ext_vector_type(8))) unsigned short ushort8;
typedef __attribute__((ext_vector_type(8))) _Float16 f16x8;
typedef __attribute__((ext_vector_type(4))) float f32x4;
typedef __attribute__((ext_vector_type(2))) float f32x2;

__device__ inline unsigned short f2h(float f) {
    _Float16 h = (_Float16)f;
    return __builtin_bit_cast(unsigned short, h);
}
__device__ inline float h2f(unsigned short u) {
    return (float)__builtin_bit_cast(_Float16, u);
}
__device__ inline float sigm(float x) { return 1.f / (1.f + expf(-x)); }

// VALU cross-lane reductions. permlane swaps need DISTINCT registers (r9 lesson).
// DPP row_ror:N rotates within each 16-lane row.
__device__ __forceinline__ float red4(float x) {
    int xi = __builtin_bit_cast(int, x);
    int yi = __builtin_amdgcn_update_dpp(xi, xi, 0x124 /*row_ror:4*/, 0xf, 0xf, true);
    return x + __builtin_bit_cast(float, yi);
}
__device__ __forceinline__ float red8(float x) {
    int xi = __builtin_bit_cast(int, x);
    int yi = __builtin_amdgcn_update_dpp(xi, xi, 0x128 /*row_ror:8*/, 0xf, 0xf, true);
    return x + __builtin_bit_cast(float, yi);
}
__device__ __forceinline__ float red16(float x) {
    float b = x;
    asm("" : "+v"(b));
    float a = x;
    asm("v_permlane16_swap_b32 %0, %1" : "+v"(a), "+v"(b));
    return a + b;
}
__device__ __forceinline__ float red32(float x) {
    float b = x;
    asm("" : "+v"(b));
    float a = x;
    asm("v_permlane32_swap_b32 %0, %1" : "+v"(a), "+v"(b));
    return a + b;
}

// async global -> LDS. LDS dest = uniform base + lane*size.
__device__ __forceinline__ void gld16(void* lds, const void* g)
{
    __builtin_amdgcn_global_load_lds(
        (const __attribute__((address_space(1))) void*)g,
        (__attribute__((address_space(3))) void*)lds, 16, 0, 0);
}
__device__ __forceinline__ void gld4(void* lds, const void* g)
{
    __builtin_amdgcn_global_load_lds(
        (const __attribute__((address_space(1))) void*)g,
        (__attribute__((address_space(3))) void*)lds, 4, 0, 0);
}

// ---------------- mix (optional) + convert to single fp16 ----------------
__global__ void mixcvt_h(const float* __restrict__ in, const float* __restrict__ xxr,
                         unsigned short* __restrict__ o16, int T, int D, int total8, int domix)
{
    int i = blockIdx.x * 256 + threadIdx.x;
    if (i >= total8) return;
    const size_t e = (size_t)i * 8;
    float a[8];
    *(float4*)&a[0] = *(const float4*)(in + e);
    *(float4*)&a[4] = *(const float4*)(in + e + 4);
    if (domix) {
        const int m = (int)(e / D);
        const int d = (int)(e % D);
        const int t = m % T;
        float p[8] = {0.f,0.f,0.f,0.f,0.f,0.f,0.f,0.f};
        if (t > 0) {
            *(float4*)&p[0] = *(const float4*)(in + e - D);
            *(float4*)&p[4] = *(const float4*)(in + e - D + 4);
        }
        float xv[8];
        *(float4*)&xv[0] = *(const float4*)(xxr + d);
        *(float4*)&xv[4] = *(const float4*)(xxr + d + 4);
        #pragma unroll
        for (int j = 0; j < 8; ++j) a[j] += (p[j] - a[j]) * xv[j];
    }
    ushort8 o;
    #pragma unroll
    for (int j = 0; j < 8; ++j) o[j] = f2h(a[j]);
    *(ushort8*)(o16 + e) = o;
}

// ---------------- weight split: hi = fp16(w), lo = fp16(w - hi) ----------------
__global__ void wsplit_h(const float* __restrict__ in,
                         unsigned short* __restrict__ hi, unsigned short* __restrict__ lo,
                         int total8)
{
    int i = blockIdx.x * 256 + threadIdx.x;
    if (i >= total8) return;
    const size_t e = (size_t)i * 8;
    float a[8];
    *(float4*)&a[0] = *(const float4*)(in + e);
    *(float4*)&a[4] = *(const float4*)(in + e + 4);
    ushort8 h8, l8;
    #pragma unroll
    for (int j = 0; j < 8; ++j) {
        const unsigned short h = f2h(a[j]);
        h8[j] = h;
        l8[j] = f2h(a[j] - h2f(h));
    }
    *(ushort8*)(hi + e) = h8;
    *(ushort8*)(lo + e) = l8;
}

// ---------------- fp16 2-term MFMA GEMM: C[M,N] = A[M,K] @ W[N,K]^T, f32 out ----------
// A: single fp16. W: hi/lo fp16. C = A*Wh + A*Wl (2 MFMAs per fragment pair).
// mode 0: C = acc ; mode 2: C = lerp(acc, aux, sigmoid(yv + bias[col]))
#define GBM 128
#define GBN 128

__global__ __launch_bounds__(256) void gemm_h2(
    const unsigned short* __restrict__ Ag,
    const unsigned short* __restrict__ Bhg, const unsigned short* __restrict__ Blg,
    float* __restrict__ C, int M, int N, int K, int mode,
    const float* __restrict__ yv, const float* __restrict__ bias,
    const float* __restrict__ aux)
{
    __shared__ unsigned short As[GBM * 32];
    __shared__ unsigned short Bhs[GBN * 32], Bls[GBN * 32];
    const int tid = threadIdx.x;
    const int m0 = blockIdx.x * GBM;
    const int n0 = blockIdx.y * GBN;
    const int wave = tid >> 6, lane = tid & 63;
    const int wr = (wave >> 1) * 64, wc = (wave & 1) * 64;
    const int fr = lane & 15, fq = lane >> 4;

    f32x4 acc[4][4];
    #pragma unroll
    for (int i = 0; i < 4; ++i)
        #pragma unroll
        for (int j = 0; j < 4; ++j)
            acc[i][j] = (f32x4){0.f, 0.f, 0.f, 0.f};

    // staging: wave0 -> A rows 0-63, wave1 -> A rows 64-127, wave2 -> Bh, wave3 -> Bl
    const unsigned short* gsrc;
    unsigned short* lbuf;
    int rofs, nld;
    if (wave == 0)      { gsrc = Ag;  lbuf = As;           rofs = m0;      nld = 4; }
    else if (wave == 1) { gsrc = Ag;  lbuf = As + 64 * 32; rofs = m0 + 64; nld = 4; }
    else if (wave == 2) { gsrc = Bhg; lbuf = Bhs;          rofs = n0;      nld = 8; }
    else                { gsrc = Blg; lbuf = Bls;          rofs = n0;      nld = 8; }
    const unsigned short* gbase = gsrc + (size_t)(rofs + (lane >> 2)) * K + ((lane & 3) << 3);

    for (int k0 = 0; k0 < K; k0 += 32) {
        #pragma unroll
        for (int j = 0; j < 8; ++j)
            if (j < nld)
                gld16(lbuf + j * 16 * 32, gbase + (size_t)(j * 16) * K + k0);
        __syncthreads();

        f16x8 fa[4], fbh[4], fbl[4];
        #pragma unroll
        for (int m = 0; m < 4; ++m)
            fa[m] = *(const f16x8*)&As[(wr + m * 16 + fr) * 32 + fq * 8];
        #pragma unroll
        for (int n = 0; n < 4; ++n) {
            fbh[n] = *(const f16x8*)&Bhs[(wc + n * 16 + fr) * 32 + fq * 8];
            fbl[n] = *(const f16x8*)&Bls[(wc + n * 16 + fr) * 32 + fq * 8];
        }
        #pragma unroll
        for (int m = 0; m < 4; ++m)
            #pragma unroll
            for (int n = 0; n < 4; ++n) {
                acc[m][n] = __builtin_amdgcn_mfma_f32_16x16x32_f16(fa[m], fbh[n], acc[m][n], 0, 0, 0);
                acc[m][n] = __builtin_amdgcn_mfma_f32_16x16x32_f16(fa[m], fbl[n], acc[m][n], 0, 0, 0);
            }
        __syncthreads();
    }

    #pragma unroll
    for (int m = 0; m < 4; ++m) {
        const int row = m0 + wr + m * 16 + fq * 4;
        #pragma unroll
        for (int n = 0; n < 4; ++n) {
            const int col = n0 + wc + n * 16 + fr;
            #pragma unroll
            for (int j = 0; j < 4; ++j) {
                const size_t idx = (size_t)(row + j) * N + col;
                float v = acc[m][n][j];
                if (mode == 2) {
                    const float sg = sigm(yv[idx] + bias[col]);
                    v = v + sg * (aux[idx] - v);
                }
                C[idx] = v;
            }
        }
    }
}

// ---------------- f32 SIMD GEMM (LoRA stage-2, g-gate) ----------------
#define BM 64
#define BN 64
#define BK 16
__global__ __launch_bounds__(256) void gemm_f32(
    const float* __restrict__ A, const float* __restrict__ xx,
    const float* __restrict__ W, float* __restrict__ C,
    int M, int N, int K, int T, int mode, const float* __restrict__ bias)
{
    __shared__ float As[BK][BM + 4];
    __shared__ float Bs[BK][BN + 4];
    const int tid = threadIdx.x;
    const int m0 = blockIdx.x * BM;
    const int n0 = blockIdx.y * BN;
    const int lr = tid >> 2;
    const int lk = (tid & 3) << 2;
    const int tx = tid & 15;
    const int ty = tid >> 4;
    const int mrow = m0 + lr;
    const int nrow = n0 + lr;
    float acc[4][4];
    #pragma unroll
    for (int i = 0; i < 4; ++i)
        #pragma unroll
        for (int j = 0; j < 4; ++j) acc[i][j] = 0.f;

    for (int k0 = 0; k0 < K; k0 += BK) {
        const float* ap = A + (size_t)mrow * K + k0 + lk;
        float4 av = *(const float4*)ap;
        if (xx) {
            const int t = mrow % T;
            float4 pv = make_float4(0.f, 0.f, 0.f, 0.f);
            if (t > 0) pv = *(const float4*)(ap - K);
            const float4 xv = *(const float4*)(xx + k0 + lk);
            av.x += (pv.x - av.x) * xv.x;
            av.y += (pv.y - av.y) * xv.y;
            av.z += (pv.z - av.z) * xv.z;
            av.w += (pv.w - av.w) * xv.w;
        }
        float4 bv = make_float4(0.f, 0.f, 0.f, 0.f);
        if (nrow < N) bv = *(const float4*)(W + (size_t)nrow * K + k0 + lk);

        As[lk + 0][lr] = av.x; As[lk + 1][lr] = av.y;
        As[lk + 2][lr] = av.z; As[lk + 3][lr] = av.w;
        Bs[lk + 0][lr] = bv.x; Bs[lk + 1][lr] = bv.y;
        Bs[lk + 2][lr] = bv.z; Bs[lk + 3][lr] = bv.w;
        __syncthreads();

        #pragma unroll
        for (int kk = 0; kk < BK; ++kk) {
            const float4 a4 = *(const float4*)&As[kk][ty << 2];
            const float4 b4 = *(const float4*)&Bs[kk][tx << 2];
            const float a[4] = {a4.x, a4.y, a4.z, a4.w};
            const float b[4] = {b4.x, b4.y, b4.z, b4.w};
            #pragma unroll
            for (int i = 0; i < 4; ++i)
                #pragma unroll
                for (int j = 0; j < 4; ++j)
                    acc[i][j] = fmaf(a[i], b[j], acc[i][j]);
        }
        __syncthreads();
    }
    #pragma unroll
    for (int i = 0; i < 4; ++i) {
        const int m = m0 + (ty << 2) + i;
        #pragma unroll
        for (int j = 0; j < 4; ++j) {
            const int n = n0 + (tx << 2) + j;
            if (n < N) {
                const size_t idx = (size_t)m * N + n;
                float v = acc[i][j];
                if (mode == 1) v = 0.6065306597126334f * sigm(v + bias[n]);
                C[idx] = v;
            }
        }
    }
}

// ---------------- fused LoRA stage-1: 4 GEMMs in one launch, act in epilogue ------------
__global__ __launch_bounds__(256) void lora1(
    const float* __restrict__ hid, const float* __restrict__ x_x,
    const float* __restrict__ wA, const float* __restrict__ vA,
    const float* __restrict__ aA, const float* __restrict__ gA,
    float* __restrict__ HW, float* __restrict__ HV,
    float* __restrict__ HA, float* __restrict__ HG,
    int M, int K, int T)
{
    __shared__ float As[BK][BM + 4];
    __shared__ float Bs[BK][BN + 4];
    const int y = blockIdx.y;
    const float* W; const float* xx; float* C; int NL, act, nofs, nvalid;
    if (y == 0)      { W = wA; xx = x_x + 1 * (size_t)K; C = HW; NL = 64;  act = 1; nofs = 0;  nvalid = 64; }
    else if (y == 1) { W = vA; xx = x_x + 3 * (size_t)K; C = HV; NL = 16;  act = 0; nofs = 0;  nvalid = 16; }
    else if (y == 2) { W = aA; xx = x_x + 4 * (size_t)K; C = HA; NL = 64;  act = 0; nofs = 0;  nvalid = 64; }
    else             { W = gA + (size_t)(y - 3) * 64 * K; xx = x_x + 5 * (size_t)K; C = HG; NL = 128; act = 2; nofs = (y - 3) * 64; nvalid = 64; }

    const int tid = threadIdx.x;
    const int m0 = blockIdx.x * BM;
    const int lr = tid >> 2;
    const int lk = (tid & 3) << 2;
    const int tx = tid & 15;
    const int ty = tid >> 4;
    const int mrow = m0 + lr;
    float acc[4][4];
    #pragma unroll
    for (int i = 0; i < 4; ++i)
        #pragma unroll
        for (int j = 0; j < 4; ++j) acc[i][j] = 0.f;

    for (int k0 = 0; k0 < K; k0 += BK) {
        const float* ap = hid + (size_t)mrow * K + k0 + lk;
        float4 av = *(const float4*)ap;
        {
            const int t = mrow % T;
            float4 pv = make_float4(0.f, 0.f, 0.f, 0.f);
            if (t > 0) pv = *(const float4*)(ap - K);
            const float4 xv = *(const float4*)(xx + k0 + lk);
            av.x += (pv.x - av.x) * xv.x;
            av.y += (pv.y - av.y) * xv.y;
            av.z += (pv.z - av.z) * xv.z;
            av.w += (pv.w - av.w) * xv.w;
        }
        float4 bv = make_float4(0.f, 0.f, 0.f, 0.f);
        if (lr < nvalid) bv = *(const float4*)(W + (size_t)lr * K + k0 + lk);

        As[lk + 0][lr] = av.x; As[lk + 1][lr] = av.y;
        As[lk + 2][lr] = av.z; As[lk + 3][lr] = av.w;
        Bs[lk + 0][lr] = bv.x; Bs[lk + 1][lr] = bv.y;
        Bs[lk + 2][lr] = bv.z; Bs[lk + 3][lr] = bv.w;
        __syncthreads();

        #pragma unroll
        for (int kk = 0; kk < BK; ++kk) {
            const float4 a4 = *(const float4*)&As[kk][ty << 2];
            const float4 b4 = *(const float4*)&Bs[kk][tx << 2];
            const float a[4] = {a4.x, a4.y, a4.z, a4.w};
            const float b[4] = {b4.x, b4.y, b4.z, b4.w};
            #pragma unroll
            for (int i = 0; i < 4; ++i)
                #pragma unroll
                for (int j = 0; j < 4; ++j)
                    acc[i][j] = fmaf(a[i], b[j], acc[i][j]);
        }
        __syncthreads();
    }
    #pragma unroll
    for (int i = 0; i < 4; ++i) {
        const int m = m0 + (ty << 2) + i;
        #pragma unroll
        for (int j = 0; j < 4; ++j) {
            const int n = (tx << 2) + j;
            if (n < nvalid) {
                float v = acc[i][j];
                if (act == 1) v = tanhf(v);
                else if (act == 2) v = sigm(v);
                C[(size_t)m * NL + nofs + n] = v;
            }
        }
    }
}

// per-(b,t,h) wave: a = sigmoid(ya+ab); kk = normalize(k0*k_k); bv = kk*a;
// kfinal = k0*(1+(a-1)*k_a)
__global__ __launch_bounds__(256) void ka_epi(
    float* __restrict__ Kf, float* __restrict__ A_BV, float* __restrict__ KKo,
    const float* __restrict__ k_k, const float* __restrict__ k_a,
    const float* __restrict__ ab, int total, int H)
{
    int wid = (blockIdx.x << 2) | (threadIdx.x >> 6);
    if (wid >= total) return;
    const int l = threadIdx.x & 63;
    const int h = wid % H;
    const int ch = h * 64 + l;
    const size_t base = (size_t)wid * 64;
    float k0 = Kf[base + l];
    float a = sigm(A_BV[base + l] + ab[ch]);
    float kkr = k0 * k_k[ch];
    float ss = kkr * kkr;
    #pragma unroll
    for (int off = 1; off < 64; off <<= 1) ss += __shfl_xor(ss, off, 64);
    float inv = 1.f / fmaxf(sqrtf(ss), 1e-12f);
    float kkn = kkr * inv;
    KKo[base + l] = kkn;
    A_BV[base + l] = kkn * a;
    Kf[base + l] = k0 * fmaf(a - 1.f, k_a[ch], 1.f);
}

// DPLR scan v7. ONE wave per block; grid = B*H*16 = 1024 (4 blocks/CU).
// Block (b,h,slab): 4 v-cols. Lane l: vc = l&3, g = l>>2, owns k in [g*4,+4).
// Chunks (SCH=8) staged via global_load_lds; reductions = ror4+ror8+permlane.
#define SCH 8
__global__ __launch_bounds__(64) void rwkv_scan(
    const float* __restrict__ EW, const float* __restrict__ R,
    const float* __restrict__ Kf, const float* __restrict__ Vf,
    const float* __restrict__ KK, const float* __restrict__ BV,
    float* __restrict__ O, int T, int H)
{
    __shared__ float lds[2][5 * SCH * 64 + SCH * 4];

    const int blk = blockIdx.x;
    const int bh = blk & 63;               // slab-siblings 64 apart -> same XCD
    const int slab = blk >> 6;             // 0..15
    const int b = bh >> 5, h = bh & 31;
    const int l = threadIdx.x;
    const int vc = l & 3;
    const int g  = l >> 2;
    const int kb = g << 2;
    const int vb0 = slab << 2;
    const size_t step = (size_t)H * 64;
    const size_t base0 = ((size_t)b * T * H + h) * 64;

    auto stage = [&](int c, int buf) {
        float* L = &lds[buf][0];
        const size_t t0 = (size_t)c * SCH;
        const float* gs[5] = {EW, R, Kf, KK, BV};
        #pragma unroll
        for (int s = 0; s < 5; ++s) {
            const float* gp = gs[s];
            #pragma unroll
            for (int j = 0; j < 2; ++j)
                gld16(L + s * SCH * 64 + j * 4 * 64,
                      gp + base0 + (t0 + j * 4 + (l >> 4)) * step + ((l & 15) << 2));
        }
        // V slab: [SCH][4] floats = 32 -> one gld4 with 32 active lanes
        if (l < 32)
            gld4(L + 5 * SCH * 64,
                 Vf + base0 + (t0 + (l >> 2)) * step + vb0 + (l & 3));
    };

    f32x2 s2[2];
    s2[0] = (f32x2){0.f, 0.f};
    s2[1] = (f32x2){0.f, 0.f};

    struct P { f32x4 e, r, k, q, bb; float vv; };
    P PA, PB;
    const int NCH = T / SCH;

    stage(0, 0);
    asm volatile("s_waitcnt vmcnt(0)" ::: "memory");
    __builtin_amdgcn_sched_barrier(0);

    for (int c = 0; c < NCH; ++c) {
        if (c + 1 < NCH) stage(c + 1, (c + 1) & 1);

        const float* L = &lds[c & 1][0];
        auto PRE = [&](P& pp, int tt) {
            const int o = tt * 64 + kb;
            pp.e  = *(const f32x4*)(L + 0 * SCH * 64 + o);
            pp.r  = *(const f32x4*)(L + 1 * SCH * 64 + o);
            pp.k  = *(const f32x4*)(L + 2 * SCH * 64 + o);
            pp.q  = *(const f32x4*)(L + 3 * SCH * 64 + o);
            pp.bb = *(const f32x4*)(L + 4 * SCH * 64 + o);
            pp.vv = L[5 * SCH * 64 + tt * 4 + vc];
        };
        auto COMP = [&](const P& pp, int tt) {
            const f32x2 elo = __builtin_shufflevector(pp.e, pp.e, 0, 1);
            const f32x2 ehi = __builtin_shufflevector(pp.e, pp.e, 2, 3);
            const f32x2 qlo = __builtin_shufflevector(pp.q, pp.q, 0, 1);
            const f32x2 qhi = __builtin_shufflevector(pp.q, pp.q, 2, 3);
            s2[0] *= elo;
            s2[1] *= ehi;
            const f32x2 sa2 = qlo * s2[0] + qhi * s2[1];
            float p = -(sa2.x + sa2.y);
            p = red32(red16(red8(red4(p))));        // VALU-only reduction
            const f32x2 p2 = (f32x2){p, p};
            const f32x2 v2 = (f32x2){pp.vv, pp.vv};
            const f32x2 klo = __builtin_shufflevector(pp.k, pp.k, 0, 1);
            const f32x2 khi = __builtin_shufflevector(pp.k, pp.k, 2, 3);
            const f32x2 blo = __builtin_shufflevector(pp.bb, pp.bb, 0, 1);
            const f32x2 bhi = __builtin_shufflevector(pp.bb, pp.bb, 2, 3);
            const f32x2 rlo = __builtin_shufflevector(pp.r, pp.r, 0, 1);
            const f32x2 rhi = __builtin_shufflevector(pp.r, pp.r, 2, 3);
            s2[0] = blo * p2 + (klo * v2 + s2[0]);
            s2[1] = bhi * p2 + (khi * v2 + s2[1]);
            const f32x2 oo2 = rlo * s2[0] + rhi * s2[1];
            float oo = oo2.x + oo2.y;
            oo = red32(red16(red8(red4(oo))));
            if (g == 0)
                O[base0 + (size_t)(c * SCH + tt) * step + vb0 + vc] = oo;
        };

        PRE(PA, 0);
        PRE(PB, 1);
        #pragma unroll
        for (int tt = 0; tt < SCH - 2; tt += 2) {
            COMP(PA, tt);     PRE(PA, tt + 2);
            COMP(PB, tt + 1); PRE(PB, tt + 3);
        }
        COMP(PA, SCH - 2);
        COMP(PB, SCH - 1);

        asm volatile("s_waitcnt vmcnt(0)" ::: "memory");
        __builtin_amdgcn_sched_barrier(0);
    }
}

// GroupNorm + bonus + precomputed g-gate (coalesced). One wave per (b,t,h).
__global__ __launch_bounds__(256) void gn_bonus(
    const float* __restrict__ O, const float* __restrict__ R,
    const float* __restrict__ Kf, const float* __restrict__ Vf,
    const float* __restrict__ G, const float* __restrict__ r_k,
    const float* __restrict__ gn_w, const float* __restrict__ gn_b,
    float* __restrict__ ON, int total, int H, float eps)
{
    int wid = (blockIdx.x << 2) | (threadIdx.x >> 6);
    if (wid >= total) return;
    const int l = threadIdx.x & 63;
    const int h = wid % H;
    const int ch = h * 64 + l;
    const size_t base = (size_t)wid * 64;

    const float o = O[base + l];
    float sum = o;
    #pragma unroll
    for (int off = 1; off < 64; off <<= 1) sum += __shfl_xor(sum, off, 64);
    const float mu = sum * (1.f / 64.f);
    const float d = o - mu;
    float ss = d * d;
    #pragma unroll
    for (int off = 1; off < 64; off <<= 1) ss += __shfl_xor(ss, off, 64);
    const float inv = 1.f / sqrtf(ss * (1.f / 64.f) + eps);
    float on = d * inv * gn_w[ch] + gn_b[ch];

    const float r = R[base + l], k = Kf[base + l], vv = Vf[base + l];
    float p = r * k * r_k[ch];
    #pragma unroll
    for (int off = 1; off < 64; off <<= 1) p += __shfl_xor(p, off, 64);
    on = fmaf(p, vv, on);
    ON[base + l] = on * G[base + l];
}

extern "C" void kernel_launch(void* const* d_in, const int* in_sizes, int n_in,
                              void* d_out, int out_size, void* d_ws, size_t ws_size,
                              hipStream_t stream)
{
    const int B = 2, T = 2048, D = 2048, H = 32;
    const int M = B * T;

    const float* hid = (const float*)d_in[0];
    const float* vst = (const float*)d_in[1];
    const float* x_x = (const float*)d_in[2];
    const float* k_k = (const float*)d_in[3];
    const float* k_a = (const float*)d_in[4];
    const float* r_k = (const float*)d_in[5];
    const float* Wr  = (const float*)d_in[6];
    const float* Wk  = (const float*)d_in[7];
    const float* Wv  = (const float*)d_in[8];
    const float* Wo  = (const float*)d_in[9];
    const float* wA  = (const float*)d_in[10];
    const float* wB  = (const float*)d_in[11];
    const float* wb  = (const float*)d_in[12];
    const float* vA  = (const float*)d_in[13];
    const float* vB  = (const float*)d_in[14];
    const float* vb  = (const float*)d_in[15];
    const float* aA  = (const float*)d_in[16];
    const float* aB  = (const float*)d_in[17];
    const float* ab  = (const float*)d_in[18];
    const float* gA  = (const float*)d_in[19];
    const float* gB  = (const float*)d_in[20];
    const float* gnw = (const float*)d_in[21];
    const float* gnb = (const float*)d_in[22];
    float* out = (float*)d_out;

    const size_t NE = (size_t)M * D;   // 8,388,608
    const size_t DD = (size_t)D * D;   // 4,194,304
    const size_t need = (6 * NE + (size_t)M * 272) * sizeof(float);  // ~196 MiB (proven)
    if (ws_size < need) return;

    float* R_  = (float*)d_ws;
    float* EW  = R_  + NE;
    float* Kf  = EW  + NE;
    float* Vf  = Kf  + NE;
    float* KK  = Vf  + NE;
    float* ABV = KK  + NE;
    float* HW  = ABV + NE;
    float* HV  = HW + (size_t)M * 64;
    float* HA  = HV + (size_t)M * 16;
    float* HG  = HA + (size_t)M * 64;

    dim3 blk(256);
    dim3 gH2(M / GBM, D / GBN);
    const int nMix = (int)(NE / 8);
    const int nW   = (int)(DD / 8);
    const float* nf = nullptr;

    unsigned short* X16 = (unsigned short*)EW;   // NE shorts (half the EW window)
    unsigned short* WHi = (unsigned short*)KK;   // DD shorts
    unsigned short* WLo = WHi + DD;

    // ---- phase 1: fused LoRA stage-1 (acts in epilogue) ----
    hipLaunchKernelGGL(lora1, dim3(M / BM, 5), blk, 0, stream,
                       hid, x_x, wA, vA, aA, gA, HW, HV, HA, HG, M, D, T);

    // ---- phase 2: yv -> ABV ----
    hipLaunchKernelGGL(gemm_f32, dim3(M / BM, D / BN), blk, 0, stream, HV, nf, vB, ABV, M, D, 16, T, 0, nf);

    // ---- phase 3: R/K/V projections via fp16 2-term MFMA ----
    hipLaunchKernelGGL(mixcvt_h, dim3(nMix / 256), blk, 0, stream, hid, x_x + 0 * (size_t)D, X16, T, D, nMix, 1);
    hipLaunchKernelGGL(wsplit_h, dim3(nW / 256), blk, 0, stream, Wr, WHi, WLo, nW);
    hipLaunchKernelGGL(gemm_h2, gH2, blk, 0, stream, X16, WHi, WLo, R_, M, D, D, 0, nf, nf, nf);

    hipLaunchKernelGGL(mixcvt_h, dim3(nMix / 256), blk, 0, stream, hid, x_x + 2 * (size_t)D, X16, T, D, nMix, 1);
    hipLaunchKernelGGL(wsplit_h, dim3(nW / 256), blk, 0, stream, Wk, WHi, WLo, nW);
    hipLaunchKernelGGL(gemm_h2, gH2, blk, 0, stream, X16, WHi, WLo, Kf, M, D, D, 0, nf, nf, nf);

    hipLaunchKernelGGL(mixcvt_h, dim3(nMix / 256), blk, 0, stream, hid, x_x + 3 * (size_t)D, X16, T, D, nMix, 1);
    hipLaunchKernelGGL(wsplit_h, dim3(nW / 256), blk, 0, stream, Wv, WHi, WLo, nW);
    hipLaunchKernelGGL(gemm_h2, gH2, blk, 0, stream, X16, WHi, WLo, Vf, M, D, D, 2, ABV, vb, vst);

    // ---- phase 4: LoRA stage-2 ----
    hipLaunchKernelGGL(gemm_f32, dim3(M / BM, D / BN), blk, 0, stream, HW, nf, wB, EW,  M, D, 64, T, 1, wb);
    hipLaunchKernelGGL(gemm_f32, dim3(M / BM, D / BN), blk, 0, stream, HA, nf, aB, ABV, M, D, 64, T, 0, nf);

    // ---- phase 5: ka epilogue ----
    const int totalW = M * H;
    hipLaunchKernelGGL(ka_epi, dim3(totalW / 4), blk, 0, stream, Kf, ABV, KK, k_k, k_a, ab, totalW, H);

    // ---- phase 6: scan -> d_out (1024 single-wave blocks, 4/CU) ----
    hipLaunchKernelGGL(rwkv_scan, dim3(B * H * 16), dim3(64), 0, stream, EW, R_, Kf, Vf, KK, ABV, out, T, H);

    // ---- phase 7: g-gate GEMM (into dead KK window) + GroupNorm/bonus -> EW ----
    float* G_ = KK;
    hipLaunchKernelGGL(gemm_f32, dim3(M / BM, D / BN), blk, 0, stream, HG, nf, gB, G_, M, D, 128, T, 0, nf);
    hipLaunchKernelGGL(gn_bonus, dim3(totalW / 4), blk, 0, stream, out, R_, Kf, Vf, G_, r_k, gnw, gnb, EW, totalW, H, 64.f * 1e-5f);

    // ---- phase 8: Wo projection -> d_out ----
    unsigned short* ON16 = (unsigned short*)KK;        // overwrites G after gn_bonus
    unsigned short* WoHi = (unsigned short*)ABV;       // bv dead after scan
    unsigned short* WoLo = WoHi + DD;
    hipLaunchKernelGGL(mixcvt_h, dim3(nMix / 256), blk, 0, stream, EW, nf, ON16, T, D, nMix, 0);
    hipLaunchKernelGGL(wsplit_h, dim3(nW / 256), blk, 0, stream, Wo, WoHi, WoLo, nW);
    hipLaunchKernelGGL(gemm_h2, gH2, blk, 0, stream, ON16, WoHi, WoLo, out, M, D, D, 0, nf, nf, nf);
}

// Round 15
// 1090.296 us; speedup vs baseline: 5.0934x; 1.0356x over previous
//
#include <hip/hip_runtime.h>
#include <hip/hip_bf16.h>
#include <math.h>

// RWKV7 attention, round 15 (= round 14 with the DPP-ctrl compile fix):
//  - rwkv_scan reverted to round-12 config (8 slabs, SCH=16, grid 512) - proven 404us.
//  - mixcvt2_h: R+K mixes fused (hid read once); gemm_h2 batched via grid.z (R,K in one dispatch).
//  - g-gate GEMM via fp16 2-term MFMA (K=128).
//  - ka_epi / gn_bonus reductions moved off the DS pipe (DPP rotates + permlane swaps).
// gemm_h2 math identical to round 13 (absmax-proven).

typedef __attribute__((ext_vector_type(8))) unsigned short ushort8;
typedef __attribute__((ext_vector_type(8))) _Float16 f16x8;
typedef __attribute__((ext_vector_type(4))) float f32x4;
typedef __attribute__((ext_vector_type(2))) float f32x2;

__device__ inline unsigned short f2h(float f) {
    _Float16 h = (_Float16)f;
    return __builtin_bit_cast(unsigned short, h);
}
__device__ inline float h2f(unsigned short u) {
    return (float)__builtin_bit_cast(_Float16, u);
}
__device__ inline float sigm(float x) { return 1.f / (1.f + expf(-x)); }

// ---- VALU cross-lane reductions (DPP rotates + permlane swaps; distinct-reg rule from r9) ----
template <int CTRL>
__device__ __forceinline__ float rrot(float x) {
    int xi = __builtin_bit_cast(int, x);
    int yi = __builtin_amdgcn_update_dpp(xi, xi, CTRL, 0xf, 0xf, true);
    return x + __builtin_bit_cast(float, yi);
}
__device__ __forceinline__ float red8(float x)  { return rrot<0x128>(x); }
__device__ __forceinline__ float red16(float x) {
    float b = x;
    asm("" : "+v"(b));
    float a = x;
    asm("v_permlane16_swap_b32 %0, %1" : "+v"(a), "+v"(b));
    return a + b;
}
__device__ __forceinline__ float red32(float x) {
    float b = x;
    asm("" : "+v"(b));
    float a = x;
    asm("v_permlane32_swap_b32 %0, %1" : "+v"(a), "+v"(b));
    return a + b;
}
// full 64-lane sum, result in every lane (per-lane rounding may differ by ~1ulp)
__device__ __forceinline__ float full64(float x) {
    x = rrot<0x121>(x);   // ror:1
    x = rrot<0x122>(x);   // ror:2
    x = rrot<0x124>(x);   // ror:4
    x = rrot<0x128>(x);   // ror:8  -> 16-lane row sums
    return red32(red16(x));
}

// async global -> LDS. LDS dest = uniform base + lane*size.
__device__ __forceinline__ void gld16(void* lds, const void* g)
{
    __builtin_amdgcn_global_load_lds(
        (const __attribute__((address_space(1))) void*)g,
        (__attribute__((address_space(3))) void*)lds, 16, 0, 0);
}
__device__ __forceinline__ void gld4(void* lds, const void* g)
{
    __builtin_amdgcn_global_load_lds(
        (const __attribute__((address_space(1))) void*)g,
        (__attribute__((address_space(3))) void*)lds, 4, 0, 0);
}

// ---------------- mix (optional) + convert to single fp16 ----------------
__global__ void mixcvt_h(const float* __restrict__ in, const float* __restrict__ xxr,
                         unsigned short* __restrict__ o16, int T, int D, int total8, int domix)
{
    int i = blockIdx.x * 256 + threadIdx.x;
    if (i >= total8) return;
    const size_t e = (size_t)i * 8;
    float a[8];
    *(float4*)&a[0] = *(const float4*)(in + e);
    *(float4*)&a[4] = *(const float4*)(in + e + 4);
    if (domix) {
        const int m = (int)(e / D);
        const int d = (int)(e % D);
        const int t = m % T;
        float p[8] = {0.f,0.f,0.f,0.f,0.f,0.f,0.f,0.f};
        if (t > 0) {
            *(float4*)&p[0] = *(const float4*)(in + e - D);
            *(float4*)&p[4] = *(const float4*)(in + e - D + 4);
        }
        float xv[8];
        *(float4*)&xv[0] = *(const float4*)(xxr + d);
        *(float4*)&xv[4] = *(const float4*)(xxr + d + 4);
        #pragma unroll
        for (int j = 0; j < 8; ++j) a[j] += (p[j] - a[j]) * xv[j];
    }
    ushort8 o;
    #pragma unroll
    for (int j = 0; j < 8; ++j) o[j] = f2h(a[j]);
    *(ushort8*)(o16 + e) = o;
}

// two mixes in one pass (hid/prev read once)
__global__ void mixcvt2_h(const float* __restrict__ in,
                          const float* __restrict__ xx0, const float* __restrict__ xx1,
                          unsigned short* __restrict__ o0, unsigned short* __restrict__ o1,
                          int T, int D, int total8)
{
    int i = blockIdx.x * 256 + threadIdx.x;
    if (i >= total8) return;
    const size_t e = (size_t)i * 8;
    float a[8];
    *(float4*)&a[0] = *(const float4*)(in + e);
    *(float4*)&a[4] = *(const float4*)(in + e + 4);
    const int m = (int)(e / D);
    const int d = (int)(e % D);
    const int t = m % T;
    float p[8] = {0.f,0.f,0.f,0.f,0.f,0.f,0.f,0.f};
    if (t > 0) {
        *(float4*)&p[0] = *(const float4*)(in + e - D);
        *(float4*)&p[4] = *(const float4*)(in + e - D + 4);
    }
    float x0[8], x1[8];
    *(float4*)&x0[0] = *(const float4*)(xx0 + d);
    *(float4*)&x0[4] = *(const float4*)(xx0 + d + 4);
    *(float4*)&x1[0] = *(const float4*)(xx1 + d);
    *(float4*)&x1[4] = *(const float4*)(xx1 + d + 4);
    ushort8 r0, r1;
    #pragma unroll
    for (int j = 0; j < 8; ++j) {
        r0[j] = f2h(a[j] + (p[j] - a[j]) * x0[j]);
        r1[j] = f2h(a[j] + (p[j] - a[j]) * x1[j]);
    }
    *(ushort8*)(o0 + e) = r0;
    *(ushort8*)(o1 + e) = r1;
}

// ---------------- weight split: hi = fp16(w), lo = fp16(w - hi) ----------------
__global__ void wsplit_h(const float* __restrict__ in,
                         unsigned short* __restrict__ hi, unsigned short* __restrict__ lo,
                         int total8)
{
    int i = blockIdx.x * 256 + threadIdx.x;
    if (i >= total8) return;
    const size_t e = (size_t)i * 8;
    float a[8];
    *(float4*)&a[0] = *(const float4*)(in + e);
    *(float4*)&a[4] = *(const float4*)(in + e + 4);
    ushort8 h8, l8;
    #pragma unroll
    for (int j = 0; j < 8; ++j) {
        const unsigned short h = f2h(a[j]);
        h8[j] = h;
        l8[j] = f2h(a[j] - h2f(h));
    }
    *(ushort8*)(hi + e) = h8;
    *(ushort8*)(lo + e) = l8;
}

// ---------------- fp16 2-term MFMA GEMM: C[M,N] = A[M,K] @ W[N,K]^T, f32 out ----------
// A: single fp16. W: hi/lo fp16. C = A*Wh + A*Wl. blockIdx.z strides A/B/C by sA/sB/sC.
#define GBM 128
#define GBN 128

__global__ __launch_bounds__(256) void gemm_h2(
    const unsigned short* __restrict__ Ag,
    const unsigned short* __restrict__ Bhg, const unsigned short* __restrict__ Blg,
    float* __restrict__ C, int M, int N, int K, int mode,
    const float* __restrict__ yv, const float* __restrict__ bias,
    const float* __restrict__ aux,
    size_t sA, size_t sB, size_t sC)
{
    __shared__ unsigned short As[GBM * 32];
    __shared__ unsigned short Bhs[GBN * 32], Bls[GBN * 32];
    const int z = blockIdx.z;
    Ag  += (size_t)z * sA;
    Bhg += (size_t)z * sB;
    Blg += (size_t)z * sB;
    C   += (size_t)z * sC;
    const int tid = threadIdx.x;
    const int m0 = blockIdx.x * GBM;
    const int n0 = blockIdx.y * GBN;
    const int wave = tid >> 6, lane = tid & 63;
    const int wr = (wave >> 1) * 64, wc = (wave & 1) * 64;
    const int fr = lane & 15, fq = lane >> 4;

    f32x4 acc[4][4];
    #pragma unroll
    for (int i = 0; i < 4; ++i)
        #pragma unroll
        for (int j = 0; j < 4; ++j)
            acc[i][j] = (f32x4){0.f, 0.f, 0.f, 0.f};

    // staging: wave0 -> A rows 0-63, wave1 -> A rows 64-127, wave2 -> Bh, wave3 -> Bl
    const unsigned short* gsrc;
    unsigned short* lbuf;
    int rofs, nld;
    if (wave == 0)      { gsrc = Ag;  lbuf = As;           rofs = m0;      nld = 4; }
    else if (wave == 1) { gsrc = Ag;  lbuf = As + 64 * 32; rofs = m0 + 64; nld = 4; }
    else if (wave == 2) { gsrc = Bhg; lbuf = Bhs;          rofs = n0;      nld = 8; }
    else                { gsrc = Blg; lbuf = Bls;          rofs = n0;      nld = 8; }
    const unsigned short* gbase = gsrc + (size_t)(rofs + (lane >> 2)) * K + ((lane & 3) << 3);

    for (int k0 = 0; k0 < K; k0 += 32) {
        #pragma unroll
        for (int j = 0; j < 8; ++j)
            if (j < nld)
                gld16(lbuf + j * 16 * 32, gbase + (size_t)(j * 16) * K + k0);
        __syncthreads();

        f16x8 fa[4], fbh[4], fbl[4];
        #pragma unroll
        for (int m = 0; m < 4; ++m)
            fa[m] = *(const f16x8*)&As[(wr + m * 16 + fr) * 32 + fq * 8];
        #pragma unroll
        for (int n = 0; n < 4; ++n) {
            fbh[n] = *(const f16x8*)&Bhs[(wc + n * 16 + fr) * 32 + fq * 8];
            fbl[n] = *(const f16x8*)&Bls[(wc + n * 16 + fr) * 32 + fq * 8];
        }
        #pragma unroll
        for (int m = 0; m < 4; ++m)
            #pragma unroll
            for (int n = 0; n < 4; ++n) {
                acc[m][n] = __builtin_amdgcn_mfma_f32_16x16x32_f16(fa[m], fbh[n], acc[m][n], 0, 0, 0);
                acc[m][n] = __builtin_amdgcn_mfma_f32_16x16x32_f16(fa[m], fbl[n], acc[m][n], 0, 0, 0);
            }
        __syncthreads();
    }

    #pragma unroll
    for (int m = 0; m < 4; ++m) {
        const int row = m0 + wr + m * 16 + fq * 4;
        #pragma unroll
        for (int n = 0; n < 4; ++n) {
            const int col = n0 + wc + n * 16 + fr;
            #pragma unroll
            for (int j = 0; j < 4; ++j) {
                const size_t idx = (size_t)(row + j) * N + col;
                float v = acc[m][n][j];
                if (mode == 2) {
                    const float sg = sigm(yv[idx] + bias[col]);
                    v = v + sg * (aux[idx] - v);
                }
                C[idx] = v;
            }
        }
    }
}

// ---------------- f32 SIMD GEMM (LoRA stage-2, yv) ----------------
#define BM 64
#define BN 64
#define BK 16
__global__ __launch_bounds__(256) void gemm_f32(
    const float* __restrict__ A, const float* __restrict__ xx,
    const float* __restrict__ W, float* __restrict__ C,
    int M, int N, int K, int T, int mode, const float* __restrict__ bias)
{
    __shared__ float As[BK][BM + 4];
    __shared__ float Bs[BK][BN + 4];
    const int tid = threadIdx.x;
    const int m0 = blockIdx.x * BM;
    const int n0 = blockIdx.y * BN;
    const int lr = tid >> 2;
    const int lk = (tid & 3) << 2;
    const int tx = tid & 15;
    const int ty = tid >> 4;
    const int mrow = m0 + lr;
    const int nrow = n0 + lr;
    float acc[4][4];
    #pragma unroll
    for (int i = 0; i < 4; ++i)
        #pragma unroll
        for (int j = 0; j < 4; ++j) acc[i][j] = 0.f;

    for (int k0 = 0; k0 < K; k0 += BK) {
        const float* ap = A + (size_t)mrow * K + k0 + lk;
        float4 av = *(const float4*)ap;
        if (xx) {
            const int t = mrow % T;
            float4 pv = make_float4(0.f, 0.f, 0.f, 0.f);
            if (t > 0) pv = *(const float4*)(ap - K);
            const float4 xv = *(const float4*)(xx + k0 + lk);
            av.x += (pv.x - av.x) * xv.x;
            av.y += (pv.y - av.y) * xv.y;
            av.z += (pv.z - av.z) * xv.z;
            av.w += (pv.w - av.w) * xv.w;
        }
        float4 bv = make_float4(0.f, 0.f, 0.f, 0.f);
        if (nrow < N) bv = *(const float4*)(W + (size_t)nrow * K + k0 + lk);

        As[lk + 0][lr] = av.x; As[lk + 1][lr] = av.y;
        As[lk + 2][lr] = av.z; As[lk + 3][lr] = av.w;
        Bs[lk + 0][lr] = bv.x; Bs[lk + 1][lr] = bv.y;
        Bs[lk + 2][lr] = bv.z; Bs[lk + 3][lr] = bv.w;
        __syncthreads();

        #pragma unroll
        for (int kk = 0; kk < BK; ++kk) {
            const float4 a4 = *(const float4*)&As[kk][ty << 2];
            const float4 b4 = *(const float4*)&Bs[kk][tx << 2];
            const float a[4] = {a4.x, a4.y, a4.z, a4.w};
            const float b[4] = {b4.x, b4.y, b4.z, b4.w};
            #pragma unroll
            for (int i = 0; i < 4; ++i)
                #pragma unroll
                for (int j = 0; j < 4; ++j)
                    acc[i][j] = fmaf(a[i], b[j], acc[i][j]);
        }
        __syncthreads();
    }
    #pragma unroll
    for (int i = 0; i < 4; ++i) {
        const int m = m0 + (ty << 2) + i;
        #pragma unroll
        for (int j = 0; j < 4; ++j) {
            const int n = n0 + (tx << 2) + j;
            if (n < N) {
                const size_t idx = (size_t)m * N + n;
                float v = acc[i][j];
                if (mode == 1) v = 0.6065306597126334f * sigm(v + bias[n]);
                C[idx] = v;
            }
        }
    }
}

// ---------------- fused LoRA stage-1: 4 GEMMs in one launch, act in epilogue ------------
__global__ __launch_bounds__(256) void lora1(
    const float* __restrict__ hid, const float* __restrict__ x_x,
    const float* __restrict__ wA, const float* __restrict__ vA,
    const float* __restrict__ aA, const float* __restrict__ gA,
    float* __restrict__ HW, float* __restrict__ HV,
    float* __restrict__ HA, float* __restrict__ HG,
    int M, int K, int T)
{
    __shared__ float As[BK][BM + 4];
    __shared__ float Bs[BK][BN + 4];
    const int y = blockIdx.y;
    const float* W; const float* xx; float* C; int NL, act, nofs, nvalid;
    if (y == 0)      { W = wA; xx = x_x + 1 * (size_t)K; C = HW; NL = 64;  act = 1; nofs = 0;  nvalid = 64; }
    else if (y == 1) { W = vA; xx = x_x + 3 * (size_t)K; C = HV; NL = 16;  act = 0; nofs = 0;  nvalid = 16; }
    else if (y == 2) { W = aA; xx = x_x + 4 * (size_t)K; C = HA; NL = 64;  act = 0; nofs = 0;  nvalid = 64; }
    else             { W = gA + (size_t)(y - 3) * 64 * K; xx = x_x + 5 * (size_t)K; C = HG; NL = 128; act = 2; nofs = (y - 3) * 64; nvalid = 64; }

    const int tid = threadIdx.x;
    const int m0 = blockIdx.x * BM;
    const int lr = tid >> 2;
    const int lk = (tid & 3) << 2;
    const int tx = tid & 15;
    const int ty = tid >> 4;
    const int mrow = m0 + lr;
    float acc[4][4];
    #pragma unroll
    for (int i = 0; i < 4; ++i)
        #pragma unroll
        for (int j = 0; j < 4; ++j) acc[i][j] = 0.f;

    for (int k0 = 0; k0 < K; k0 += BK) {
        const float* ap = hid + (size_t)mrow * K + k0 + lk;
        float4 av = *(const float4*)ap;
        {
            const int t = mrow % T;
            float4 pv = make_float4(0.f, 0.f, 0.f, 0.f);
            if (t > 0) pv = *(const float4*)(ap - K);
            const float4 xv = *(const float4*)(xx + k0 + lk);
            av.x += (pv.x - av.x) * xv.x;
            av.y += (pv.y - av.y) * xv.y;
            av.z += (pv.z - av.z) * xv.z;
            av.w += (pv.w - av.w) * xv.w;
        }
        float4 bv = make_float4(0.f, 0.f, 0.f, 0.f);
        if (lr < nvalid) bv = *(const float4*)(W + (size_t)lr * K + k0 + lk);

        As[lk + 0][lr] = av.x; As[lk + 1][lr] = av.y;
        As[lk + 2][lr] = av.z; As[lk + 3][lr] = av.w;
        Bs[lk + 0][lr] = bv.x; Bs[lk + 1][lr] = bv.y;
        Bs[lk + 2][lr] = bv.z; Bs[lk + 3][lr] = bv.w;
        __syncthreads();

        #pragma unroll
        for (int kk = 0; kk < BK; ++kk) {
            const float4 a4 = *(const float4*)&As[kk][ty << 2];
            const float4 b4 = *(const float4*)&Bs[kk][tx << 2];
            const float a[4] = {a4.x, a4.y, a4.z, a4.w};
            const float b[4] = {b4.x, b4.y, b4.z, b4.w};
            #pragma unroll
            for (int i = 0; i < 4; ++i)
                #pragma unroll
                for (int j = 0; j < 4; ++j)
                    acc[i][j] = fmaf(a[i], b[j], acc[i][j]);
        }
        __syncthreads();
    }
    #pragma unroll
    for (int i = 0; i < 4; ++i) {
        const int m = m0 + (ty << 2) + i;
        #pragma unroll
        for (int j = 0; j < 4; ++j) {
            const int n = (tx << 2) + j;
            if (n < nvalid) {
                float v = acc[i][j];
                if (act == 1) v = tanhf(v);
                else if (act == 2) v = sigm(v);
                C[(size_t)m * NL + nofs + n] = v;
            }
        }
    }
}

// per-(b,t,h) wave: a = sigmoid(ya+ab); kk = normalize(k0*k_k); bv = kk*a;
// kfinal = k0*(1+(a-1)*k_a).  Reduction on VALU (no DS).
__global__ __launch_bounds__(256) void ka_epi(
    float* __restrict__ Kf, float* __restrict__ A_BV, float* __restrict__ KKo,
    const float* __restrict__ k_k, const float* __restrict__ k_a,
    const float* __restrict__ ab, int total, int H)
{
    int wid = (blockIdx.x << 2) | (threadIdx.x >> 6);
    if (wid >= total) return;
    const int l = threadIdx.x & 63;
    const int h = wid % H;
    const int ch = h * 64 + l;
    const size_t base = (size_t)wid * 64;
    float k0 = Kf[base + l];
    float a = sigm(A_BV[base + l] + ab[ch]);
    float kkr = k0 * k_k[ch];
    float ss = full64(kkr * kkr);
    float inv = 1.f / fmaxf(sqrtf(ss), 1e-12f);
    float kkn = kkr * inv;
    KKo[base + l] = kkn;
    A_BV[base + l] = kkn * a;
    Kf[base + l] = k0 * fmaf(a - 1.f, k_a[ch], 1.f);
}

// DPLR scan (round-12 proven config). ONE wave per block; grid = B*H*8 = 512.
// Block (b,h,slab): 8 v-cols. Lane l: vc = l&7, g = l>>3, owns k in [g*8,+8).
// Chunks (SCH=16) staged via global_load_lds; reductions red8+red16+red32 (VALU).
#define SCH 16
__global__ __launch_bounds__(64) void rwkv_scan(
    const float* __restrict__ EW, const float* __restrict__ R,
    const float* __restrict__ Kf, const float* __restrict__ Vf,
    const float* __restrict__ KK, const float* __restrict__ BV,
    float* __restrict__ O, int T, int H)
{
    __shared__ float lds[2][5 * SCH * 64 + SCH * 8];

    const int blk = blockIdx.x;
    const int bh = blk & 63;               // slab-siblings 64 apart -> same XCD
    const int slab = blk >> 6;             // 0..7
    const int b = bh >> 5, h = bh & 31;
    const int l = threadIdx.x;
    const int vc = l & 7;
    const int g  = l >> 3;
    const int kb = g << 3;
    const int vb0 = slab << 3;
    const size_t step = (size_t)H * 64;
    const size_t base0 = ((size_t)b * T * H + h) * 64;

    auto stage = [&](int c, int buf) {
        float* L = &lds[buf][0];
        const size_t t0 = (size_t)c * SCH;
        const float* gs[5] = {EW, R, Kf, KK, BV};
        #pragma unroll
        for (int s = 0; s < 5; ++s) {
            const float* gp = gs[s];
            #pragma unroll
            for (int j = 0; j < 4; ++j)
                gld16(L + s * SCH * 64 + j * 4 * 64,
                      gp + base0 + (t0 + j * 4 + (l >> 4)) * step + ((l & 15) << 2));
        }
        gld4(L + 5 * SCH * 64,
             Vf + base0 + (t0 + (l >> 3)) * step + vb0 + (l & 7));
        gld4(L + 5 * SCH * 64 + 64,
             Vf + base0 + (t0 + 8 + (l >> 3)) * step + vb0 + (l & 7));
    };

    f32x2 s2[4];
    #pragma unroll
    for (int i = 0; i < 4; ++i) s2[i] = (f32x2){0.f, 0.f};

    struct P { f32x4 e[2], r[2], k[2], q[2], bb[2]; float vv; };
    P PA, PB;
    const int NCH = T / SCH;

    stage(0, 0);
    asm volatile("s_waitcnt vmcnt(0)" ::: "memory");
    __builtin_amdgcn_sched_barrier(0);

    for (int c = 0; c < NCH; ++c) {
        if (c + 1 < NCH) stage(c + 1, (c + 1) & 1);

        const float* L = &lds[c & 1][0];
        auto PRE = [&](P& pp, int tt) {
            const int o = tt * 64 + kb;
            #pragma unroll
            for (int j = 0; j < 2; ++j) {
                pp.e[j]  = *(const f32x4*)(L + 0 * SCH * 64 + o + j * 4);
                pp.r[j]  = *(const f32x4*)(L + 1 * SCH * 64 + o + j * 4);
                pp.k[j]  = *(const f32x4*)(L + 2 * SCH * 64 + o + j * 4);
                pp.q[j]  = *(const f32x4*)(L + 3 * SCH * 64 + o + j * 4);
                pp.bb[j] = *(const f32x4*)(L + 4 * SCH * 64 + o + j * 4);
            }
            pp.vv = L[5 * SCH * 64 + tt * 8 + vc];
        };
        auto COMP = [&](const P& pp, int tt) {
            f32x2 sa0 = (f32x2){0.f, 0.f}, sa1 = (f32x2){0.f, 0.f};
            #pragma unroll
            for (int j = 0; j < 2; ++j) {
                const f32x2 elo = __builtin_shufflevector(pp.e[j], pp.e[j], 0, 1);
                const f32x2 ehi = __builtin_shufflevector(pp.e[j], pp.e[j], 2, 3);
                const f32x2 qlo = __builtin_shufflevector(pp.q[j], pp.q[j], 0, 1);
                const f32x2 qhi = __builtin_shufflevector(pp.q[j], pp.q[j], 2, 3);
                s2[2*j]   *= elo;
                s2[2*j+1] *= ehi;
                sa0 += qlo * s2[2*j];
                sa1 += qhi * s2[2*j+1];
            }
            const f32x2 sas = sa0 + sa1;
            float p = -(sas.x + sas.y);
            p = red32(red16(red8(p)));
            const f32x2 p2 = (f32x2){p, p};
            const f32x2 v2 = (f32x2){pp.vv, pp.vv};
            f32x2 o0 = (f32x2){0.f, 0.f}, o1 = (f32x2){0.f, 0.f};
            #pragma unroll
            for (int j = 0; j < 2; ++j) {
                const f32x2 klo = __builtin_shufflevector(pp.k[j], pp.k[j], 0, 1);
                const f32x2 khi = __builtin_shufflevector(pp.k[j], pp.k[j], 2, 3);
                const f32x2 blo = __builtin_shufflevector(pp.bb[j], pp.bb[j], 0, 1);
                const f32x2 bhi = __builtin_shufflevector(pp.bb[j], pp.bb[j], 2, 3);
                const f32x2 rlo = __builtin_shufflevector(pp.r[j], pp.r[j], 0, 1);
                const f32x2 rhi = __builtin_shufflevector(pp.r[j], pp.r[j], 2, 3);
                s2[2*j]   = blo * p2 + (klo * v2 + s2[2*j]);
                s2[2*j+1] = bhi * p2 + (khi * v2 + s2[2*j+1]);
                o0 += rlo * s2[2*j];
                o1 += rhi * s2[2*j+1];
            }
            const f32x2 os = o0 + o1;
            float oo = os.x + os.y;
            oo = red32(red16(red8(oo)));
            if (g == 0)
                O[base0 + (size_t)(c * SCH + tt) * step + vb0 + vc] = oo;
        };

        PRE(PA, 0);
        PRE(PB, 1);
        #pragma unroll
        for (int tt = 0; tt < SCH - 2; tt += 2) {
            COMP(PA, tt);     PRE(PA, tt + 2);
            COMP(PB, tt + 1); PRE(PB, tt + 3);
        }
        COMP(PA, SCH - 2);
        COMP(PB, SCH - 1);

        asm volatile("s_waitcnt vmcnt(0)" ::: "memory");
        __builtin_amdgcn_sched_barrier(0);
    }
}

// GroupNorm + bonus + precomputed g-gate. Reductions on VALU (no DS).
__global__ __launch_bounds__(256) void gn_bonus(
    const float* __restrict__ O, const float* __restrict__ R,
    const float* __restrict__ Kf, const float* __restrict__ Vf,
    const float* __restrict__ G, const float* __restrict__ r_k,
    const float* __restrict__ gn_w, const float* __restrict__ gn_b,
    float* __restrict__ ON, int total, int H, float eps)
{
    int wid = (blockIdx.x << 2) | (threadIdx.x >> 6);
    if (wid >= total) return;
    const int l = threadIdx.x & 63;
    const int h = wid % H;
    const int ch = h * 64 + l;
    const size_t base = (size_t)wid * 64;

    const float o = O[base + l];
    const float mu = full64(o) * (1.f / 64.f);
    const float d = o - mu;
    const float ss = full64(d * d);
    const float inv = 1.f / sqrtf(ss * (1.f / 64.f) + eps);
    float on = d * inv * gn_w[ch] + gn_b[ch];

    const float r = R[base + l], k = Kf[base + l], vv = Vf[base + l];
    const float p = full64(r * k * r_k[ch]);
    on = fmaf(p, vv, on);
    ON[base + l] = on * G[base + l];
}

extern "C" void kernel_launch(void* const* d_in, const int* in_sizes, int n_in,
                              void* d_out, int out_size, void* d_ws, size_t ws_size,
                              hipStream_t stream)
{
    const int B = 2, T = 2048, D = 2048, H = 32;
    const int M = B * T;

    const float* hid = (const float*)d_in[0];
    const float* vst = (const float*)d_in[1];
    const float* x_x = (const float*)d_in[2];
    const float* k_k = (const float*)d_in[3];
    const float* k_a = (const float*)d_in[4];
    const float* r_k = (const float*)d_in[5];
    const float* Wr  = (const float*)d_in[6];
    const float* Wk  = (const float*)d_in[7];
    const float* Wv  = (const float*)d_in[8];
    const float* Wo  = (const float*)d_in[9];
    const float* wA  = (const float*)d_in[10];
    const float* wB  = (const float*)d_in[11];
    const float* wb  = (const float*)d_in[12];
    const float* vA  = (const float*)d_in[13];
    const float* vB  = (const float*)d_in[14];
    const float* vb  = (const float*)d_in[15];
    const float* aA  = (const float*)d_in[16];
    const float* aB  = (const float*)d_in[17];
    const float* ab  = (const float*)d_in[18];
    const float* gA  = (const float*)d_in[19];
    const float* gB  = (const float*)d_in[20];
    const float* gnw = (const float*)d_in[21];
    const float* gnb = (const float*)d_in[22];
    float* out = (float*)d_out;

    const size_t NE = (size_t)M * D;   // 8,388,608
    const size_t DD = (size_t)D * D;   // 4,194,304
    const size_t need = (6 * NE + (size_t)M * 272) * sizeof(float);  // ~196 MiB (proven)
    if (ws_size < need) return;

    float* R_  = (float*)d_ws;
    float* EW  = R_  + NE;
    float* Kf  = EW  + NE;
    float* Vf  = Kf  + NE;
    float* KK  = Vf  + NE;
    float* ABV = KK  + NE;
    float* HW  = ABV + NE;
    float* HV  = HW + (size_t)M * 64;
    float* HA  = HV + (size_t)M * 16;
    float* HG  = HA + (size_t)M * 64;

    dim3 blk(256);
    const int nMix = (int)(NE / 8);
    const int nW   = (int)(DD / 8);
    const float* nf = nullptr;

    // ---- phase 1: fused LoRA stage-1 (acts in epilogue) ----
    hipLaunchKernelGGL(lora1, dim3(M / BM, 5), blk, 0, stream,
                       hid, x_x, wA, vA, aA, gA, HW, HV, HA, HG, M, D, T);

    // ---- phase 2: yv -> ABV ----
    hipLaunchKernelGGL(gemm_f32, dim3(M / BM, D / BN), blk, 0, stream, HV, nf, vB, ABV, M, D, 16, T, 0, nf);

    // ---- phase 3a: R+K batched (fused mixcvt; one grid.z=2 GEMM dispatch) ----
    unsigned short* X2  = (unsigned short*)EW;   // [2][NE] fp16
    unsigned short* W2  = (unsigned short*)KK;   // [hiR, loR, hiK, loK] each DD
    hipLaunchKernelGGL(mixcvt2_h, dim3(nMix / 256), blk, 0, stream,
                       hid, x_x + 0 * (size_t)D, x_x + 2 * (size_t)D, X2, X2 + NE, T, D, nMix);
    hipLaunchKernelGGL(wsplit_h, dim3(nW / 256), blk, 0, stream, Wr, W2, W2 + DD, nW);
    hipLaunchKernelGGL(wsplit_h, dim3(nW / 256), blk, 0, stream, Wk, W2 + 2 * DD, W2 + 3 * DD, nW);
    hipLaunchKernelGGL(gemm_h2, dim3(M / GBM, D / GBN, 2), blk, 0, stream,
                       X2, W2, W2 + DD, R_, M, D, D, 0, nf, nf, nf,
                       NE, 2 * DD, 2 * NE);   // C: z0 -> R_, z1 -> R_ + 2NE = Kf

    // ---- phase 3b: V (fused lerp epilogue) ----
    hipLaunchKernelGGL(mixcvt_h, dim3(nMix / 256), blk, 0, stream, hid, x_x + 3 * (size_t)D, X2, T, D, nMix, 1);
    hipLaunchKernelGGL(wsplit_h, dim3(nW / 256), blk, 0, stream, Wv, W2, W2 + DD, nW);
    hipLaunchKernelGGL(gemm_h2, dim3(M / GBM, D / GBN, 1), blk, 0, stream,
                       X2, W2, W2 + DD, Vf, M, D, D, 2, ABV, vb, vst, 0, 0, 0);

    // ---- phase 4: LoRA stage-2 ----
    hipLaunchKernelGGL(gemm_f32, dim3(M / BM, D / BN), blk, 0, stream, HW, nf, wB, EW,  M, D, 64, T, 1, wb);
    hipLaunchKernelGGL(gemm_f32, dim3(M / BM, D / BN), blk, 0, stream, HA, nf, aB, ABV, M, D, 64, T, 0, nf);

    // ---- phase 5: ka epilogue ----
    const int totalW = M * H;
    hipLaunchKernelGGL(ka_epi, dim3(totalW / 4), blk, 0, stream, Kf, ABV, KK, k_k, k_a, ab, totalW, H);

    // ---- phase 6: scan -> d_out (512 single-wave blocks, 2/CU) ----
    hipLaunchKernelGGL(rwkv_scan, dim3(B * H * 8), dim3(64), 0, stream, EW, R_, Kf, Vf, KK, ABV, out, T, H);

    // ---- phase 7: g-gate via fp16 GEMM (inputs in dead ABV window, G in KK) + gn_bonus ----
    unsigned short* HG16 = (unsigned short*)ABV;              // M*128 shorts
    unsigned short* gbHi = HG16 + (size_t)M * 128;            // D*128 shorts
    unsigned short* gbLo = gbHi + (size_t)D * 128;
    float* G_ = KK;
    hipLaunchKernelGGL(mixcvt_h, dim3((M * 128 / 8) / 256), blk, 0, stream, HG, nf, HG16, T, D, M * 128 / 8, 0);
    hipLaunchKernelGGL(wsplit_h, dim3((D * 128 / 8) / 256), blk, 0, stream, gB, gbHi, gbLo, D * 128 / 8);
    hipLaunchKernelGGL(gemm_h2, dim3(M / GBM, D / GBN, 1), blk, 0, stream,
                       HG16, gbHi, gbLo, G_, M, D, 128, 0, nf, nf, nf, 0, 0, 0);
    hipLaunchKernelGGL(gn_bonus, dim3(totalW / 4), blk, 0, stream, out, R_, Kf, Vf, G_, r_k, gnw, gnb, EW, totalW, H, 64.f * 1e-5f);

    // ---- phase 8: Wo projection -> d_out ----
    unsigned short* ON16 = (unsigned short*)KK;        // overwrites G after gn_bonus
    unsigned short* WoHi = (unsigned short*)ABV;       // overwrites HG16/gb (dead)
    unsigned short* WoLo = WoHi + DD;
    hipLaunchKernelGGL(mixcvt_h, dim3(nMix / 256), blk, 0, stream, EW, nf, ON16, T, D, nMix, 0);
    hipLaunchKernelGGL(wsplit_h, dim3(nW / 256), blk, 0, stream, Wo, WoHi, WoLo, nW);
    hipLaunchKernelGGL(gemm_h2, dim3(M / GBM, D / GBN, 1), blk, 0, stream,
                       ON16, WoHi, WoLo, out, M, D, D, 0, nf, nf, nf, 0, 0, 0);
}